// Round 1
// baseline (773.554 us; speedup 1.0000x reference)
//
#include <hip/hip_runtime.h>
#include <math.h>

#define BATCH  8192
#define NNODES 500000
#define DIM    128
#define TDIM   64
#define KNB    32
#define KSEL   16

__device__ __forceinline__ float sigmoidf_(float x) { return 1.f / (1.f + expf(-x)); }
__device__ __forceinline__ float dot4(float4 a, float4 b) {
    return a.x * b.x + a.y * b.y + a.z * b.z + a.w * b.w;
}

// ---------------------------------------------------------------------------
// K_winner: last-write-wins scatter resolution. winner[v] = max row index i in
// nodes=[src;dst] with nodes[i]==v (numpy a[idx]=val semantics: last wins).
// ---------------------------------------------------------------------------
__global__ __launch_bounds__(256) void k_winner(const int* __restrict__ src,
                                                const int* __restrict__ dst,
                                                int* __restrict__ winner) {
    int i = blockIdx.x * 256 + threadIdx.x;
    if (i < 2 * BATCH) {
        int v = (i < BATCH) ? src[i] : dst[i - BATCH];
        atomicMax(&winner[v], i);
    }
}

// ---------------------------------------------------------------------------
// K1: message MLP + GRU for all 2B endpoint rows. 16 rows per 256-thread block.
// ---------------------------------------------------------------------------
__global__ __launch_bounds__(256) void k1_msg_gru(
    const int* __restrict__ src, const int* __restrict__ dst, const float* __restrict__ ts,
    const float* __restrict__ memory, const float* __restrict__ last_update,
    const float* __restrict__ w_t, const float* __restrict__ b_t,
    const float* __restrict__ W1, const float* __restrict__ b1,
    const float* __restrict__ W2, const float* __restrict__ b2,
    const float* __restrict__ Wih, const float* __restrict__ bih,
    const float* __restrict__ Whh, const float* __restrict__ bhh,
    float* __restrict__ new_mem)
{
    __shared__ float sx[16][320];    // [self(128) | other(128) | te(64)]
    __shared__ float sh1[16][128];
    __shared__ float smsg[16][128];
    __shared__ int   s_node[16];
    __shared__ int   s_oth[16];
    __shared__ float s_dt[16];

    const int tid  = threadIdx.x;
    const int base = blockIdx.x * 16;

    if (tid < 16) {
        int gi = base + tid;
        int node, oth; float t;
        if (gi < BATCH) { node = src[gi];         oth = dst[gi];         t = ts[gi]; }
        else            { node = dst[gi - BATCH]; oth = src[gi - BATCH]; t = ts[gi - BATCH]; }
        s_node[tid] = node;
        s_oth[tid]  = oth;
        s_dt[tid]   = t - last_update[node];
    }
    __syncthreads();

    // stage self_mem, oth_mem (float4)
    for (int idx = tid; idx < 16 * 32; idx += 256) {
        int r = idx >> 5, c4 = (idx & 31) << 2;
        float4 vs = *(const float4*)&memory[(size_t)s_node[r] * DIM + c4];
        float4 vo = *(const float4*)&memory[(size_t)s_oth[r]  * DIM + c4];
        *(float4*)&sx[r][c4]       = vs;
        *(float4*)&sx[r][128 + c4] = vo;
    }
    // time encoding: even->sin, odd->cos
    for (int idx = tid; idx < 16 * TDIM; idx += 256) {
        int r = idx >> 6, c = idx & 63;
        float f = s_dt[r] * w_t[c] + b_t[c];
        sx[r][256 + c] = (c & 1) ? cosf(f) : sinf(f);
    }
    __syncthreads();

    const int d  = tid & 127;
    const int rg = tid >> 7;   // 0/1 -> rows rg*8 .. rg*8+7

    // h1 = relu(x @ W1.T + b1)   (W1: [128][320])
    {
        float acc[8];
        float bb = b1[d];
        #pragma unroll
        for (int r = 0; r < 8; ++r) acc[r] = bb;
        const float* wrow = W1 + (size_t)d * 320;
        for (int k = 0; k < 320; k += 4) {
            float4 w4 = *(const float4*)&wrow[k];
            #pragma unroll
            for (int r = 0; r < 8; ++r) {
                float4 x4 = *(const float4*)&sx[rg * 8 + r][k];
                acc[r] += dot4(w4, x4);
            }
        }
        #pragma unroll
        for (int r = 0; r < 8; ++r) sh1[rg * 8 + r][d] = fmaxf(acc[r], 0.f);
    }
    __syncthreads();

    // msg = h1 @ W2.T + b2   (W2: [128][128])
    {
        float acc[8];
        float bb = b2[d];
        #pragma unroll
        for (int r = 0; r < 8; ++r) acc[r] = bb;
        const float* wrow = W2 + (size_t)d * 128;
        for (int k = 0; k < 128; k += 4) {
            float4 w4 = *(const float4*)&wrow[k];
            #pragma unroll
            for (int r = 0; r < 8; ++r) {
                float4 x4 = *(const float4*)&sh1[rg * 8 + r][k];
                acc[r] += dot4(w4, x4);
            }
        }
        #pragma unroll
        for (int r = 0; r < 8; ++r) smsg[rg * 8 + r][d] = acc[r];
    }
    __syncthreads();

    // GRU: gi = msg@Wih.T + bih ; gh = self@Whh.T + bhh
    {
        float aR[8], aZ[8], aG[8], hR[8], hZ[8], hG[8];
        #pragma unroll
        for (int r = 0; r < 8; ++r) { aR[r]=aZ[r]=aG[r]=hR[r]=hZ[r]=hG[r]=0.f; }
        const float* wir = Wih + (size_t)d * 128;
        const float* wiz = Wih + (size_t)(128 + d) * 128;
        const float* wig = Wih + (size_t)(256 + d) * 128;
        const float* whr = Whh + (size_t)d * 128;
        const float* whz = Whh + (size_t)(128 + d) * 128;
        const float* whg = Whh + (size_t)(256 + d) * 128;
        for (int k = 0; k < 128; k += 4) {
            float4 w_ir = *(const float4*)&wir[k];
            float4 w_iz = *(const float4*)&wiz[k];
            float4 w_ig = *(const float4*)&wig[k];
            float4 w_hr = *(const float4*)&whr[k];
            float4 w_hz = *(const float4*)&whz[k];
            float4 w_hg = *(const float4*)&whg[k];
            #pragma unroll
            for (int r = 0; r < 8; ++r) {
                float4 m4 = *(const float4*)&smsg[rg * 8 + r][k];
                float4 s4 = *(const float4*)&sx[rg * 8 + r][k];
                aR[r] += dot4(w_ir, m4); aZ[r] += dot4(w_iz, m4); aG[r] += dot4(w_ig, m4);
                hR[r] += dot4(w_hr, s4); hZ[r] += dot4(w_hz, s4); hG[r] += dot4(w_hg, s4);
            }
        }
        float bir = bih[d], biz = bih[128 + d], big = bih[256 + d];
        float bhr = bhh[d], bhz = bhh[128 + d], bhg = bhh[256 + d];
        #pragma unroll
        for (int r = 0; r < 8; ++r) {
            float rr = sigmoidf_(aR[r] + bir + hR[r] + bhr);
            float zz = sigmoidf_(aZ[r] + biz + hZ[r] + bhz);
            float gg = tanhf(aG[r] + big + rr * (hG[r] + bhg));
            float selfv = sx[rg * 8 + r][d];
            new_mem[(size_t)(base + rg * 8 + r) * DIM + d] = (1.f - zz) * gg + zz * selfv;
        }
    }
}

// ---------------------------------------------------------------------------
// K2: temporal top-16-of-32 per src row. One thread per row; register arrays,
// compile-time indexing only (picked bitmask; best value/id tracked in scan).
// Tie-break: ascending scan with strict '>' == stable top_k (smaller idx wins).
// Selection ORDER doesn't affect the final output (softmax perm-invariant).
// ---------------------------------------------------------------------------
__global__ __launch_bounds__(256) void k2_topk(
    const int* __restrict__ src, const float* __restrict__ ts,
    const int* __restrict__ nbr_ids, const float* __restrict__ nbr_ts,
    int* __restrict__ sel_id, float* __restrict__ sel_td, int* __restrict__ sel_mk)
{
    int b = blockIdx.x * 256 + threadIdx.x;
    if (b >= BATCH) return;
    int   s = src[b];
    float t = ts[b];
    const int*   ip = nbr_ids + (size_t)s * KNB;
    const float* tp = nbr_ts  + (size_t)s * KNB;
    float kt[KNB]; int kid[KNB];
    #pragma unroll
    for (int j = 0; j < KNB; ++j) {
        int id = ip[j]; float nt = tp[j];
        bool valid = (id >= 0) && (nt < t + 1e-6f);
        kt[j]  = valid ? nt : -1e30f;
        kid[j] = id;
    }
    unsigned picked = 0u;
    for (int sI = 0; sI < KSEL; ++sI) {
        float bv = -3.4e38f; int bj = 0; int bid = 0;
        #pragma unroll
        for (int j = 0; j < KNB; ++j) {
            bool avail = !((picked >> j) & 1u);
            if (avail && kt[j] > bv) { bv = kt[j]; bj = j; bid = kid[j]; }
        }
        picked |= (1u << bj);
        bool mk = bv > -1e29f;
        int id = mk ? (bid < 0 ? 0 : (bid > NNODES - 1 ? NNODES - 1 : bid)) : 0;
        sel_id[b * KSEL + sI] = id;
        sel_td[b * KSEL + sI] = mk ? (t - bv) : 0.f;
        sel_mk[b * KSEL + sI] = mk ? 1 : 0;
    }
}

// ---------------------------------------------------------------------------
// K3: temporal attention + merge MLP + LayerNorm. One wave per query row,
// 4 waves/block. Math restructure (KS=16 < hd=64):
//   scores[h,n] = (Wk_h^T Q_h) . kv[n] + Q_h.bk_h
//   out_h      = Wv_h @ (sum_n attn[h,n] kv[n]) + (sum attn) * bv_h
// ---------------------------------------------------------------------------
__global__ __launch_bounds__(256) void k3_attn(
    const int* __restrict__ src,
    const float* __restrict__ memory, const float* __restrict__ new_mem,
    const int* __restrict__ winner,
    const int* __restrict__ sel_id, const float* __restrict__ sel_td,
    const int* __restrict__ sel_mk,
    const float* __restrict__ w_ta, const float* __restrict__ b_ta,
    const float* __restrict__ Wq, const float* __restrict__ bq,
    const float* __restrict__ Wk, const float* __restrict__ bk,
    const float* __restrict__ Wv, const float* __restrict__ bv,
    const float* __restrict__ Wo, const float* __restrict__ bo,
    const float* __restrict__ Wm1, const float* __restrict__ bm1,
    const float* __restrict__ Wm2, const float* __restrict__ bm2,
    const float* __restrict__ ln_g, const float* __restrict__ ln_b,
    float* __restrict__ out)
{
    const int lane = threadIdx.x & 63;
    const int w    = threadIdx.x >> 6;
    const int b    = blockIdx.x * 4 + w;

    __shared__ float s_nf [4][128];
    __shared__ float s_q  [4][128];
    __shared__ float s_u  [4][2][192];
    __shared__ float s_attn[4][2][16];
    __shared__ float s_satt[4][2];
    __shared__ float s_kvb[4][2][192];
    __shared__ float s_te [4][16][68];   // padded stride vs bank aliasing
    __shared__ float s_o  [4][128];
    __shared__ float s_ao [4][128];
    __shared__ float s_h1 [4][128];
    __shared__ const float* s_nptr[4][16];

    // --- stage per-row state -------------------------------------------------
    if (lane < 16) {
        int id = sel_id[b * KSEL + lane];
        int wi = winner[id];
        s_nptr[w][lane] = (wi >= 0) ? (new_mem + (size_t)wi * DIM)
                                    : (memory  + (size_t)id * DIM);
    }
    {
        int v  = src[b];
        int wv = winner[v];
        const float* nodep = (wv >= 0) ? (new_mem + (size_t)wv * DIM)
                                       : (memory  + (size_t)v  * DIM);
        s_nf[w][lane]      = nodep[lane];
        s_nf[w][64 + lane] = nodep[64 + lane];
    }
    {
        float wt = w_ta[lane], bt = b_ta[lane];
        for (int n = 0; n < 16; ++n) {
            float td = sel_td[b * KSEL + n];
            float f  = td * wt + bt;
            s_te[w][n][lane] = (lane & 1) ? cosf(f) : sinf(f);
        }
    }
    __syncthreads();

    // --- Q = node_feat @ Wq.T + bq ------------------------------------------
    #pragma unroll
    for (int j = 0; j < 2; ++j) {
        int dd = j * 64 + lane;
        float acc = bq[dd];
        const float* wrow = Wq + (size_t)dd * 128;
        for (int k = 0; k < 128; k += 4)
            acc += dot4(*(const float4*)&wrow[k], *(const float4*)&s_nf[w][k]);
        s_q[w][dd] = acc;
    }
    __syncthreads();

    // qb_h = Q_h . bk_h  (bias term folded into scores)
    float qb0, qb1;
    {
        float p0 = s_q[w][lane]      * bk[lane];
        float p1 = s_q[w][64 + lane] * bk[64 + lane];
        #pragma unroll
        for (int m = 1; m < 64; m <<= 1) { p0 += __shfl_xor(p0, m); p1 += __shfl_xor(p1, m); }
        qb0 = p0; qb1 = p1;
    }

    // --- u_h = Wk_h^T Q_h  (2 x 192) ----------------------------------------
    #pragma unroll
    for (int h = 0; h < 2; ++h) {
        const float* wkh = Wk + (size_t)h * 64 * 192;
        #pragma unroll
        for (int i = 0; i < 3; ++i) {
            int c = i * 64 + lane;
            float acc = 0.f;
            #pragma unroll 4
            for (int dh = 0; dh < 64; ++dh)
                acc += wkh[(size_t)dh * 192 + c] * s_q[w][h * 64 + dh];
            s_u[w][h][c] = acc;
        }
    }
    __syncthreads();

    // --- scores + masked softmax (lanes 0..31: h = lane>>4, n = lane&15) ----
    if (lane < 32) {
        int h = lane >> 4, n = lane & 15;
        int mk = sel_mk[b * KSEL + n];
        float s = -INFINITY;
        if (mk) {
            const float* fp = s_nptr[w][n];
            float acc = (h == 0) ? qb0 : qb1;
            for (int k = 0; k < 128; k += 4)
                acc += dot4(*(const float4*)&fp[k], *(const float4*)&s_u[w][h][k]);
            for (int k = 0; k < 64; k += 4)
                acc += dot4(*(const float4*)&s_te[w][n][k], *(const float4*)&s_u[w][h][128 + k]);
            s = acc * 0.125f;   // 1/sqrt(64)
        }
        float mx = s;
        #pragma unroll
        for (int m = 1; m < 16; m <<= 1) mx = fmaxf(mx, __shfl_xor(mx, m));
        float p = (mk && mx > -1e37f) ? expf(s - mx) : 0.f;
        float den = p;
        #pragma unroll
        for (int m = 1; m < 16; m <<= 1) den += __shfl_xor(den, m);
        float a = (den > 0.f) ? (p / den) : 0.f;
        s_attn[w][h][n] = a;
        if (n == 0) s_satt[w][h] = (den > 0.f) ? 1.f : 0.f;
    }
    __syncthreads();

    // --- kvbar_h = sum_n attn[h,n] * kv[n]  (2 x 192) ------------------------
    {
        float kb00 = 0.f, kb01 = 0.f, kb10 = 0.f, kb11 = 0.f, kb20 = 0.f, kb21 = 0.f;
        for (int n = 0; n < 16; ++n) {
            float a0 = s_attn[w][0][n], a1 = s_attn[w][1][n];
            if (a0 == 0.f && a1 == 0.f) continue;   // wave-uniform skip
            const float* fp = s_nptr[w][n];
            float v0 = fp[lane];
            float v1 = fp[64 + lane];
            float v2 = s_te[w][n][lane];
            kb00 += a0 * v0; kb01 += a1 * v0;
            kb10 += a0 * v1; kb11 += a1 * v1;
            kb20 += a0 * v2; kb21 += a1 * v2;
        }
        s_kvb[w][0][lane]       = kb00; s_kvb[w][1][lane]       = kb01;
        s_kvb[w][0][64 + lane]  = kb10; s_kvb[w][1][64 + lane]  = kb11;
        s_kvb[w][0][128 + lane] = kb20; s_kvb[w][1][128 + lane] = kb21;
    }
    __syncthreads();

    // --- out = Wv_h @ kvbar_h + satt_h * bv ----------------------------------
    #pragma unroll
    for (int j = 0; j < 2; ++j) {
        int dd = j * 64 + lane; int h = j;
        float acc = s_satt[w][h] * bv[dd];
        const float* wrow = Wv + (size_t)dd * 192;
        for (int k = 0; k < 192; k += 4)
            acc += dot4(*(const float4*)&wrow[k], *(const float4*)&s_kvb[w][h][k]);
        s_o[w][dd] = acc;
    }
    __syncthreads();

    // --- attn_out = out @ Wo.T + bo -----------------------------------------
    #pragma unroll
    for (int j = 0; j < 2; ++j) {
        int dd = j * 64 + lane;
        float acc = bo[dd];
        const float* wrow = Wo + (size_t)dd * 128;
        for (int k = 0; k < 128; k += 4)
            acc += dot4(*(const float4*)&wrow[k], *(const float4*)&s_o[w][k]);
        s_ao[w][dd] = acc;
    }
    __syncthreads();

    // --- h1 = relu([attn_out, node_feat] @ Wm1.T + bm1) ----------------------
    #pragma unroll
    for (int j = 0; j < 2; ++j) {
        int dd = j * 64 + lane;
        float acc = bm1[dd];
        const float* wrow = Wm1 + (size_t)dd * 256;
        for (int k = 0; k < 128; k += 4)
            acc += dot4(*(const float4*)&wrow[k], *(const float4*)&s_ao[w][k]);
        for (int k = 0; k < 128; k += 4)
            acc += dot4(*(const float4*)&wrow[128 + k], *(const float4*)&s_nf[w][k]);
        s_h1[w][dd] = fmaxf(acc, 0.f);
    }
    __syncthreads();

    // --- h2 = h1 @ Wm2.T + bm2, then LayerNorm -------------------------------
    float v0, v1;
    {
        int dd = lane;
        float acc = bm2[dd];
        const float* wrow = Wm2 + (size_t)dd * 128;
        for (int k = 0; k < 128; k += 4)
            acc += dot4(*(const float4*)&wrow[k], *(const float4*)&s_h1[w][k]);
        v0 = acc;
    }
    {
        int dd = 64 + lane;
        float acc = bm2[dd];
        const float* wrow = Wm2 + (size_t)dd * 128;
        for (int k = 0; k < 128; k += 4)
            acc += dot4(*(const float4*)&wrow[k], *(const float4*)&s_h1[w][k]);
        v1 = acc;
    }
    float sum = v0 + v1;
    #pragma unroll
    for (int m = 1; m < 64; m <<= 1) sum += __shfl_xor(sum, m);
    float mean = sum * (1.f / 128.f);
    float e0 = v0 - mean, e1 = v1 - mean;
    float sq = e0 * e0 + e1 * e1;
    #pragma unroll
    for (int m = 1; m < 64; m <<= 1) sq += __shfl_xor(sq, m);
    float var = sq * (1.f / 128.f);
    float inv = rsqrtf(var + 1e-5f);
    out[(size_t)b * DIM + lane]      = e0 * inv * ln_g[lane]      + ln_b[lane];
    out[(size_t)b * DIM + 64 + lane] = e1 * inv * ln_g[64 + lane] + ln_b[64 + lane];
}

// ---------------------------------------------------------------------------
extern "C" void kernel_launch(void* const* d_in, const int* in_sizes, int n_in,
                              void* d_out, int out_size, void* d_ws, size_t ws_size,
                              hipStream_t stream) {
    const int*   src         = (const int*)  d_in[0];
    const int*   dst         = (const int*)  d_in[1];
    const float* ts          = (const float*)d_in[2];
    const int*   nbr_ids     = (const int*)  d_in[3];
    const float* nbr_ts      = (const float*)d_in[4];
    const float* memory      = (const float*)d_in[5];
    const float* last_update = (const float*)d_in[6];
    const float* w_t_msg     = (const float*)d_in[7];
    const float* b_t_msg     = (const float*)d_in[8];
    const float* W_msg1      = (const float*)d_in[9];
    const float* b_msg1      = (const float*)d_in[10];
    const float* W_msg2      = (const float*)d_in[11];
    const float* b_msg2      = (const float*)d_in[12];
    const float* W_ih        = (const float*)d_in[13];
    const float* b_ih        = (const float*)d_in[14];
    const float* W_hh        = (const float*)d_in[15];
    const float* b_hh        = (const float*)d_in[16];
    const float* w_t_att     = (const float*)d_in[17];
    const float* b_t_att     = (const float*)d_in[18];
    const float* Wq          = (const float*)d_in[19];
    const float* bq          = (const float*)d_in[20];
    const float* Wk          = (const float*)d_in[21];
    const float* bk          = (const float*)d_in[22];
    const float* Wv          = (const float*)d_in[23];
    const float* bv          = (const float*)d_in[24];
    const float* Wo          = (const float*)d_in[25];
    const float* bo          = (const float*)d_in[26];
    const float* Wm1         = (const float*)d_in[27];
    const float* bm1         = (const float*)d_in[28];
    const float* Wm2         = (const float*)d_in[29];
    const float* bm2         = (const float*)d_in[30];
    const float* ln_g        = (const float*)d_in[31];
    const float* ln_b        = (const float*)d_in[32];
    float* out = (float*)d_out;

    char* ws = (char*)d_ws;
    float* new_mem = (float*)ws;                               // 2B*128*4 = 8 MiB
    int*   winner  = (int*)(ws + 8388608);                     // N*4 ~ 2 MB (pad to 2 MiB+)
    int*   sel_id  = (int*)(ws + 8388608 + 2097152);           // B*16*4
    float* sel_td  = (float*)(ws + 8388608 + 2097152 + 524288);
    int*   sel_mk  = (int*)(ws + 8388608 + 2097152 + 2 * 524288);

    hipMemsetAsync(winner, 0xFF, NNODES * sizeof(int), stream);   // -1
    k_winner<<<(2 * BATCH + 255) / 256, 256, 0, stream>>>(src, dst, winner);
    k1_msg_gru<<<(2 * BATCH) / 16, 256, 0, stream>>>(
        src, dst, ts, memory, last_update,
        w_t_msg, b_t_msg, W_msg1, b_msg1, W_msg2, b_msg2,
        W_ih, b_ih, W_hh, b_hh, new_mem);
    k2_topk<<<(BATCH + 255) / 256, 256, 0, stream>>>(
        src, ts, nbr_ids, nbr_ts, sel_id, sel_td, sel_mk);
    k3_attn<<<BATCH / 4, 256, 0, stream>>>(
        src, memory, new_mem, winner, sel_id, sel_td, sel_mk,
        w_t_att, b_t_att, Wq, bq, Wk, bk, Wv, bv, Wo, bo,
        Wm1, bm1, Wm2, bm2, ln_g, ln_b, out);
}

// Round 2
// 396.004 us; speedup vs baseline: 1.9534x; 1.9534x over previous
//
#include <hip/hip_runtime.h>
#include <math.h>

#define BATCH  8192
#define NNODES 500000
#define DIM    128
#define TDIM   64
#define KNB    32
#define KSEL   16

__device__ __forceinline__ float sigmoidf_(float x) { return 1.f / (1.f + expf(-x)); }
__device__ __forceinline__ float dot4(float4 a, float4 b) {
    return a.x * b.x + a.y * b.y + a.z * b.z + a.w * b.w;
}

// ---------------------------------------------------------------------------
// K_winner: last-write-wins scatter resolution.
// ---------------------------------------------------------------------------
__global__ __launch_bounds__(256) void k_winner(const int* __restrict__ src,
                                                const int* __restrict__ dst,
                                                int* __restrict__ winner) {
    int i = blockIdx.x * 256 + threadIdx.x;
    if (i < 2 * BATCH) {
        int v = (i < BATCH) ? src[i] : dst[i - BATCH];
        atomicMax(&winner[v], i);
    }
}

// ---------------------------------------------------------------------------
// K1: message MLP + GRU for all 2B endpoint rows. 16 rows per 256-thread block.
// ---------------------------------------------------------------------------
__global__ __launch_bounds__(256) void k1_msg_gru(
    const int* __restrict__ src, const int* __restrict__ dst, const float* __restrict__ ts,
    const float* __restrict__ memory, const float* __restrict__ last_update,
    const float* __restrict__ w_t, const float* __restrict__ b_t,
    const float* __restrict__ W1, const float* __restrict__ b1,
    const float* __restrict__ W2, const float* __restrict__ b2,
    const float* __restrict__ Wih, const float* __restrict__ bih,
    const float* __restrict__ Whh, const float* __restrict__ bhh,
    float* __restrict__ new_mem)
{
    __shared__ float sx[16][320];
    __shared__ float sh1[16][128];
    __shared__ float smsg[16][128];
    __shared__ int   s_node[16];
    __shared__ int   s_oth[16];
    __shared__ float s_dt[16];

    const int tid  = threadIdx.x;
    const int base = blockIdx.x * 16;

    if (tid < 16) {
        int gi = base + tid;
        int node, oth; float t;
        if (gi < BATCH) { node = src[gi];         oth = dst[gi];         t = ts[gi]; }
        else            { node = dst[gi - BATCH]; oth = src[gi - BATCH]; t = ts[gi - BATCH]; }
        s_node[tid] = node;
        s_oth[tid]  = oth;
        s_dt[tid]   = t - last_update[node];
    }
    __syncthreads();

    for (int idx = tid; idx < 16 * 32; idx += 256) {
        int r = idx >> 5, c4 = (idx & 31) << 2;
        float4 vs = *(const float4*)&memory[(size_t)s_node[r] * DIM + c4];
        float4 vo = *(const float4*)&memory[(size_t)s_oth[r]  * DIM + c4];
        *(float4*)&sx[r][c4]       = vs;
        *(float4*)&sx[r][128 + c4] = vo;
    }
    for (int idx = tid; idx < 16 * TDIM; idx += 256) {
        int r = idx >> 6, c = idx & 63;
        float f = s_dt[r] * w_t[c] + b_t[c];
        sx[r][256 + c] = (c & 1) ? cosf(f) : sinf(f);
    }
    __syncthreads();

    const int d  = tid & 127;
    const int rg = tid >> 7;

    {
        float acc[8];
        float bb = b1[d];
        #pragma unroll
        for (int r = 0; r < 8; ++r) acc[r] = bb;
        const float* wrow = W1 + (size_t)d * 320;
        for (int k = 0; k < 320; k += 4) {
            float4 w4 = *(const float4*)&wrow[k];
            #pragma unroll
            for (int r = 0; r < 8; ++r)
                acc[r] += dot4(w4, *(const float4*)&sx[rg * 8 + r][k]);
        }
        #pragma unroll
        for (int r = 0; r < 8; ++r) sh1[rg * 8 + r][d] = fmaxf(acc[r], 0.f);
    }
    __syncthreads();

    {
        float acc[8];
        float bb = b2[d];
        #pragma unroll
        for (int r = 0; r < 8; ++r) acc[r] = bb;
        const float* wrow = W2 + (size_t)d * 128;
        for (int k = 0; k < 128; k += 4) {
            float4 w4 = *(const float4*)&wrow[k];
            #pragma unroll
            for (int r = 0; r < 8; ++r)
                acc[r] += dot4(w4, *(const float4*)&sh1[rg * 8 + r][k]);
        }
        #pragma unroll
        for (int r = 0; r < 8; ++r) smsg[rg * 8 + r][d] = acc[r];
    }
    __syncthreads();

    {
        float aR[8], aZ[8], aG[8], hR[8], hZ[8], hG[8];
        #pragma unroll
        for (int r = 0; r < 8; ++r) { aR[r]=aZ[r]=aG[r]=hR[r]=hZ[r]=hG[r]=0.f; }
        const float* wir = Wih + (size_t)d * 128;
        const float* wiz = Wih + (size_t)(128 + d) * 128;
        const float* wig = Wih + (size_t)(256 + d) * 128;
        const float* whr = Whh + (size_t)d * 128;
        const float* whz = Whh + (size_t)(128 + d) * 128;
        const float* whg = Whh + (size_t)(256 + d) * 128;
        for (int k = 0; k < 128; k += 4) {
            float4 w_ir = *(const float4*)&wir[k];
            float4 w_iz = *(const float4*)&wiz[k];
            float4 w_ig = *(const float4*)&wig[k];
            float4 w_hr = *(const float4*)&whr[k];
            float4 w_hz = *(const float4*)&whz[k];
            float4 w_hg = *(const float4*)&whg[k];
            #pragma unroll
            for (int r = 0; r < 8; ++r) {
                float4 m4 = *(const float4*)&smsg[rg * 8 + r][k];
                float4 s4 = *(const float4*)&sx[rg * 8 + r][k];
                aR[r] += dot4(w_ir, m4); aZ[r] += dot4(w_iz, m4); aG[r] += dot4(w_ig, m4);
                hR[r] += dot4(w_hr, s4); hZ[r] += dot4(w_hz, s4); hG[r] += dot4(w_hg, s4);
            }
        }
        float bir = bih[d], biz = bih[128 + d], big = bih[256 + d];
        float bhr = bhh[d], bhz = bhh[128 + d], bhg = bhh[256 + d];
        #pragma unroll
        for (int r = 0; r < 8; ++r) {
            float rr = sigmoidf_(aR[r] + bir + hR[r] + bhr);
            float zz = sigmoidf_(aZ[r] + biz + hZ[r] + bhz);
            float gg = tanhf(aG[r] + big + rr * (hG[r] + bhg));
            float selfv = sx[rg * 8 + r][d];
            new_mem[(size_t)(base + rg * 8 + r) * DIM + d] = (1.f - zz) * gg + zz * selfv;
        }
    }
}

// ---------------------------------------------------------------------------
// K2: temporal top-16-of-32 per src row.
// ---------------------------------------------------------------------------
__global__ __launch_bounds__(256) void k2_topk(
    const int* __restrict__ src, const float* __restrict__ ts,
    const int* __restrict__ nbr_ids, const float* __restrict__ nbr_ts,
    int* __restrict__ sel_id, float* __restrict__ sel_td, int* __restrict__ sel_mk)
{
    int b = blockIdx.x * 256 + threadIdx.x;
    if (b >= BATCH) return;
    int   s = src[b];
    float t = ts[b];
    const int*   ip = nbr_ids + (size_t)s * KNB;
    const float* tp = nbr_ts  + (size_t)s * KNB;
    float kt[KNB]; int kid[KNB];
    #pragma unroll
    for (int j = 0; j < KNB; ++j) {
        int id = ip[j]; float nt = tp[j];
        bool valid = (id >= 0) && (nt < t + 1e-6f);
        kt[j]  = valid ? nt : -1e30f;
        kid[j] = id;
    }
    unsigned picked = 0u;
    for (int sI = 0; sI < KSEL; ++sI) {
        float bv = -3.4e38f; int bj = 0; int bid = 0;
        #pragma unroll
        for (int j = 0; j < KNB; ++j) {
            bool avail = !((picked >> j) & 1u);
            if (avail && kt[j] > bv) { bv = kt[j]; bj = j; bid = kid[j]; }
        }
        picked |= (1u << bj);
        bool mk = bv > -1e29f;
        int id = mk ? (bid < 0 ? 0 : (bid > NNODES - 1 ? NNODES - 1 : bid)) : 0;
        sel_id[b * KSEL + sI] = id;
        sel_td[b * KSEL + sI] = mk ? (t - bv) : 0.f;
        sel_mk[b * KSEL + sI] = mk ? 1 : 0;
    }
}

// ---------------------------------------------------------------------------
// K3a: node_feat gather + Q proj + qb = Q.bk + u = Wk_h^T Q_h.
// ---------------------------------------------------------------------------
__global__ __launch_bounds__(256) void k3a_qu(
    const int* __restrict__ src,
    const float* __restrict__ memory, const float* __restrict__ new_mem,
    const int* __restrict__ winner,
    const float* __restrict__ Wq, const float* __restrict__ bq,
    const float* __restrict__ Wk, const float* __restrict__ bk,
    float* __restrict__ nf_ws, float* __restrict__ u_ws, float* __restrict__ qb_ws)
{
    __shared__ float s_nf[16][128];
    __shared__ float s_q [16][128];
    __shared__ const float* s_ptr[16];

    const int tid = threadIdx.x;
    const int base = blockIdx.x * 16;

    if (tid < 16) {
        int v = src[base + tid];
        int wv = winner[v];
        s_ptr[tid] = (wv >= 0) ? (new_mem + (size_t)wv * DIM)
                               : (memory  + (size_t)v  * DIM);
    }
    __syncthreads();

    for (int idx = tid; idx < 16 * 32; idx += 256) {
        int r = idx >> 5, c4 = (idx & 31) << 2;
        float4 v = *(const float4*)&s_ptr[r][c4];
        *(float4*)&s_nf[r][c4] = v;
        *(float4*)&nf_ws[(size_t)(base + r) * DIM + c4] = v;
    }
    __syncthreads();

    const int d  = tid & 127;
    const int rg = tid >> 7;

    {
        float acc[8];
        float bb = bq[d];
        #pragma unroll
        for (int r = 0; r < 8; ++r) acc[r] = bb;
        const float* wrow = Wq + (size_t)d * 128;
        for (int k = 0; k < 128; k += 4) {
            float4 w4 = *(const float4*)&wrow[k];
            #pragma unroll
            for (int r = 0; r < 8; ++r)
                acc[r] += dot4(w4, *(const float4*)&s_nf[rg * 8 + r][k]);
        }
        #pragma unroll
        for (int r = 0; r < 8; ++r) s_q[rg * 8 + r][d] = acc[r];
    }
    __syncthreads();

    {
        int r = tid >> 4, rem = tid & 15, h = rem >> 3, p = rem & 7;
        float part = 0.f;
        #pragma unroll
        for (int j = 0; j < 8; ++j) {
            int dd = h * 64 + p * 8 + j;
            part += s_q[r][dd] * bk[dd];
        }
        part += __shfl_xor(part, 1);
        part += __shfl_xor(part, 2);
        part += __shfl_xor(part, 4);
        if (p == 0) qb_ws[(base + r) * 2 + h] = part;
    }

    {
        const int lane_c = tid & 63;
        const int sel = tid >> 6;
        const int rg2 = sel & 1;
        const int h   = sel >> 1;
        float acc0[8], acc1[8], acc2[8];
        #pragma unroll
        for (int r = 0; r < 8; ++r) { acc0[r] = 0.f; acc1[r] = 0.f; acc2[r] = 0.f; }
        for (int dh = 0; dh < 64; ++dh) {
            float qv[8];
            #pragma unroll
            for (int r = 0; r < 8; ++r) qv[r] = s_q[rg2 * 8 + r][h * 64 + dh];
            const float* wp = Wk + (size_t)(h * 64 + dh) * 192 + lane_c;
            float w0 = wp[0], w1 = wp[64], w2 = wp[128];
            #pragma unroll
            for (int r = 0; r < 8; ++r) {
                acc0[r] += w0 * qv[r];
                acc1[r] += w1 * qv[r];
                acc2[r] += w2 * qv[r];
            }
        }
        #pragma unroll
        for (int r = 0; r < 8; ++r) {
            size_t rowb = (size_t)(base + rg2 * 8 + r) * 384 + h * 192 + lane_c;
            u_ws[rowb]       = acc0[r];
            u_ws[rowb + 64]  = acc1[r];
            u_ws[rowb + 128] = acc2[r];
        }
    }
}

// ---------------------------------------------------------------------------
// K3b: neighbor gather + scores + softmax + kvbar. One wave per row.
// ---------------------------------------------------------------------------
__global__ __launch_bounds__(256) void k3b_score(
    const float* __restrict__ memory, const float* __restrict__ new_mem,
    const int* __restrict__ winner,
    const int* __restrict__ sel_id, const float* __restrict__ sel_td,
    const int* __restrict__ sel_mk,
    const float* __restrict__ w_ta, const float* __restrict__ b_ta,
    const float* __restrict__ u_ws, const float* __restrict__ qb_ws,
    float* __restrict__ kvb_ws, float* __restrict__ satt_ws)
{
    const int lane = threadIdx.x & 63;
    const int w    = threadIdx.x >> 6;
    const int b    = blockIdx.x * 4 + w;

    __shared__ float s_kv  [4][16][196];
    __shared__ float s_u   [4][384];
    __shared__ float s_attn[4][2][16];
    __shared__ float s_td  [4][16];
    __shared__ int   s_mk  [4][16];
    __shared__ const float* s_ptr[4][16];

    if (lane < 16) {
        int id = sel_id[b * KSEL + lane];
        int wi = winner[id];
        s_ptr[w][lane] = (wi >= 0) ? (new_mem + (size_t)wi * DIM)
                                   : (memory  + (size_t)id * DIM);
        s_td[w][lane] = sel_td[b * KSEL + lane];
        s_mk[w][lane] = sel_mk[b * KSEL + lane];
    }
    #pragma unroll
    for (int i = 0; i < 6; ++i)
        s_u[w][i * 64 + lane] = u_ws[(size_t)b * 384 + i * 64 + lane];
    __syncthreads();

    {
        #pragma unroll
        for (int it = 0; it < 8; ++it) {
            int n  = it * 2 + (lane >> 5);
            int c4 = (lane & 31) << 2;
            *(float4*)&s_kv[w][n][c4] = *(const float4*)&s_ptr[w][n][c4];
        }
        float wt = w_ta[lane], bt = b_ta[lane];
        #pragma unroll
        for (int n = 0; n < 16; ++n) {
            float f = s_td[w][n] * wt + bt;
            s_kv[w][n][128 + lane] = (lane & 1) ? cosf(f) : sinf(f);
        }
    }
    __syncthreads();

    {
        int h = (lane >> 4) & 1, n = lane & 15, half = lane >> 5;
        float acc = (half == 0) ? qb_ws[b * 2 + h] : 0.f;
        const float* kvrow = &s_kv[w][n][half * 96];
        const float* urow  = &s_u[w][h * 192 + half * 96];
        #pragma unroll
        for (int k = 0; k < 96; k += 4)
            acc += dot4(*(const float4*)&kvrow[k], *(const float4*)&urow[k]);
        acc += __shfl_xor(acc, 32);
        int mk = s_mk[w][n];
        float s = mk ? acc * 0.125f : -INFINITY;
        float mx = s;
        #pragma unroll
        for (int m = 1; m < 16; m <<= 1) mx = fmaxf(mx, __shfl_xor(mx, m));
        float p = (mk && mx > -1e37f) ? expf(s - mx) : 0.f;
        float den = p;
        #pragma unroll
        for (int m = 1; m < 16; m <<= 1) den += __shfl_xor(den, m);
        float a = (den > 0.f) ? (p / den) : 0.f;
        if (lane < 32) s_attn[w][h][n] = a;
        if (lane == 0 || lane == 16) satt_ws[b * 2 + h] = (den > 0.f) ? 1.f : 0.f;
    }
    __syncthreads();

    #pragma unroll
    for (int i = 0; i < 3; ++i) {
        int c = i * 64 + lane;
        float k0 = 0.f, k1 = 0.f;
        #pragma unroll
        for (int n = 0; n < 16; ++n) {
            float v = s_kv[w][n][c];
            k0 += s_attn[w][0][n] * v;
            k1 += s_attn[w][1][n] * v;
        }
        kvb_ws[(size_t)b * 384 + c]       = k0;
        kvb_ws[(size_t)b * 384 + 192 + c] = k1;
    }
}

// ---------------------------------------------------------------------------
// K3c: dense back-end + LayerNorm. 16 rows/block, 8-row ILP.
// ---------------------------------------------------------------------------
__global__ __launch_bounds__(256) void k3c_mlp(
    const float* __restrict__ kvb_ws, const float* __restrict__ satt_ws,
    const float* __restrict__ nf_ws,
    const float* __restrict__ Wv, const float* __restrict__ bv,
    const float* __restrict__ Wo, const float* __restrict__ bo,
    const float* __restrict__ Wm1, const float* __restrict__ bm1,
    const float* __restrict__ Wm2, const float* __restrict__ bm2,
    const float* __restrict__ ln_g, const float* __restrict__ ln_b,
    float* __restrict__ out)
{
    __shared__ float s_pool[16 * 384];
    __shared__ float s_nf[16][128];
    __shared__ float s_o [16][128];
    __shared__ float s_satt[16][2];

    float (*s_kvb)[384] = (float(*)[384])s_pool;
    float (*s_ao)[128]  = (float(*)[128])s_pool;
    float (*s_h1)[128]  = (float(*)[128])(s_pool + 16 * 128);
    float (*s_h2)[128]  = (float(*)[128])(s_pool + 32 * 128);

    const int tid = threadIdx.x;
    const int base = blockIdx.x * 16;

    for (int idx = tid; idx < 16 * 96; idx += 256) {
        int r = idx / 96, j = (idx % 96) << 2;
        *(float4*)&s_kvb[r][j] = *(const float4*)&kvb_ws[(size_t)(base + r) * 384 + j];
    }
    for (int idx = tid; idx < 16 * 32; idx += 256) {
        int r = idx >> 5, j = (idx & 31) << 2;
        *(float4*)&s_nf[r][j] = *(const float4*)&nf_ws[(size_t)(base + r) * DIM + j];
    }
    if (tid < 32) s_satt[tid >> 1][tid & 1] = satt_ws[(base + (tid >> 1)) * 2 + (tid & 1)];
    __syncthreads();

    const int d  = tid & 127;
    const int rg = tid >> 7;

    {
        float acc[8];
        int h = d >> 6;
        float bb = bv[d];
        #pragma unroll
        for (int r = 0; r < 8; ++r) acc[r] = s_satt[rg * 8 + r][h] * bb;
        const float* wrow = Wv + (size_t)d * 192;
        for (int k = 0; k < 192; k += 4) {
            float4 w4 = *(const float4*)&wrow[k];
            #pragma unroll
            for (int r = 0; r < 8; ++r)
                acc[r] += dot4(w4, *(const float4*)&s_kvb[rg * 8 + r][h * 192 + k]);
        }
        __syncthreads();
        #pragma unroll
        for (int r = 0; r < 8; ++r) s_o[rg * 8 + r][d] = acc[r];
    }
    __syncthreads();

    {
        float acc[8];
        float bb = bo[d];
        #pragma unroll
        for (int r = 0; r < 8; ++r) acc[r] = bb;
        const float* wrow = Wo + (size_t)d * 128;
        for (int k = 0; k < 128; k += 4) {
            float4 w4 = *(const float4*)&wrow[k];
            #pragma unroll
            for (int r = 0; r < 8; ++r)
                acc[r] += dot4(w4, *(const float4*)&s_o[rg * 8 + r][k]);
        }
        #pragma unroll
        for (int r = 0; r < 8; ++r) s_ao[rg * 8 + r][d] = acc[r];
    }
    __syncthreads();

    {
        float acc[8];
        float bb = bm1[d];
        #pragma unroll
        for (int r = 0; r < 8; ++r) acc[r] = bb;
        const float* wrow = Wm1 + (size_t)d * 256;
        for (int k = 0; k < 128; k += 4) {
            float4 w4  = *(const float4*)&wrow[k];
            float4 w42 = *(const float4*)&wrow[128 + k];
            #pragma unroll
            for (int r = 0; r < 8; ++r) {
                acc[r] += dot4(w4,  *(const float4*)&s_ao[rg * 8 + r][k]);
                acc[r] += dot4(w42, *(const float4*)&s_nf[rg * 8 + r][k]);
            }
        }
        #pragma unroll
        for (int r = 0; r < 8; ++r) s_h1[rg * 8 + r][d] = fmaxf(acc[r], 0.f);
    }
    __syncthreads();

    {
        float acc[8];
        float bb = bm2[d];
        #pragma unroll
        for (int r = 0; r < 8; ++r) acc[r] = bb;
        const float* wrow = Wm2 + (size_t)d * 128;
        for (int k = 0; k < 128; k += 4) {
            float4 w4 = *(const float4*)&wrow[k];
            #pragma unroll
            for (int r = 0; r < 8; ++r)
                acc[r] += dot4(w4, *(const float4*)&s_h1[rg * 8 + r][k]);
        }
        #pragma unroll
        for (int r = 0; r < 8; ++r) s_h2[rg * 8 + r][d] = acc[r];
    }
    __syncthreads();

    {
        const int wv = tid >> 6, lane = tid & 63;
        float lg0 = ln_g[lane], lg1 = ln_g[64 + lane];
        float lb0 = ln_b[lane], lb1 = ln_b[64 + lane];
        #pragma unroll
        for (int rr = 0; rr < 4; ++rr) {
            int r = wv * 4 + rr;
            float v0 = s_h2[r][lane], v1 = s_h2[r][64 + lane];
            float sum = v0 + v1;
            #pragma unroll
            for (int m = 1; m < 64; m <<= 1) sum += __shfl_xor(sum, m);
            float mean = sum * (1.f / 128.f);
            float e0 = v0 - mean, e1 = v1 - mean;
            float sq = e0 * e0 + e1 * e1;
            #pragma unroll
            for (int m = 1; m < 64; m <<= 1) sq += __shfl_xor(sq, m);
            float inv = rsqrtf(sq * (1.f / 128.f) + 1e-5f);
            out[(size_t)(base + r) * DIM + lane]      = e0 * inv * lg0 + lb0;
            out[(size_t)(base + r) * DIM + 64 + lane] = e1 * inv * lg1 + lb1;
        }
    }
}

// ---------------------------------------------------------------------------
extern "C" void kernel_launch(void* const* d_in, const int* in_sizes, int n_in,
                              void* d_out, int out_size, void* d_ws, size_t ws_size,
                              hipStream_t stream) {
    const int*   src         = (const int*)  d_in[0];
    const int*   dst         = (const int*)  d_in[1];
    const float* ts          = (const float*)d_in[2];
    const int*   nbr_ids     = (const int*)  d_in[3];
    const float* nbr_ts      = (const float*)d_in[4];
    const float* memory      = (const float*)d_in[5];
    const float* last_update = (const float*)d_in[6];
    const float* w_t_msg     = (const float*)d_in[7];
    const float* b_t_msg     = (const float*)d_in[8];
    const float* W_msg1      = (const float*)d_in[9];
    const float* b_msg1      = (const float*)d_in[10];
    const float* W_msg2      = (const float*)d_in[11];
    const float* b_msg2      = (const float*)d_in[12];
    const float* W_ih        = (const float*)d_in[13];
    const float* b_ih        = (const float*)d_in[14];
    const float* W_hh        = (const float*)d_in[15];
    const float* b_hh        = (const float*)d_in[16];
    const float* w_t_att     = (const float*)d_in[17];
    const float* b_t_att     = (const float*)d_in[18];
    const float* Wq          = (const float*)d_in[19];
    const float* bq          = (const float*)d_in[20];
    const float* Wk          = (const float*)d_in[21];
    const float* bk          = (const float*)d_in[22];
    const float* Wv          = (const float*)d_in[23];
    const float* bv          = (const float*)d_in[24];
    const float* Wo          = (const float*)d_in[25];
    const float* bo          = (const float*)d_in[26];
    const float* Wm1         = (const float*)d_in[27];
    const float* bm1         = (const float*)d_in[28];
    const float* Wm2         = (const float*)d_in[29];
    const float* bm2         = (const float*)d_in[30];
    const float* ln_g        = (const float*)d_in[31];
    const float* ln_b        = (const float*)d_in[32];
    float* out = (float*)d_out;

    char* ws = (char*)d_ws;
    size_t off = 0;
    float* new_mem = (float*)(ws + off); off += (size_t)2 * BATCH * DIM * 4;
    int*   winner  = (int*)  (ws + off); off += 2097152;
    int*   sel_id  = (int*)  (ws + off); off += (size_t)BATCH * KSEL * 4;
    float* sel_td  = (float*)(ws + off); off += (size_t)BATCH * KSEL * 4;
    int*   sel_mk  = (int*)  (ws + off); off += (size_t)BATCH * KSEL * 4;
    float* nf_ws   = (float*)(ws + off); off += (size_t)BATCH * DIM * 4;
    float* u_ws    = (float*)(ws + off); off += (size_t)BATCH * 384 * 4;
    float* qb_ws   = (float*)(ws + off); off += (size_t)BATCH * 2 * 4;
    float* kvb_ws  = (float*)(ws + off); off += (size_t)BATCH * 384 * 4;
    float* satt_ws = (float*)(ws + off); off += (size_t)BATCH * 2 * 4;

    hipMemsetAsync(winner, 0xFF, NNODES * sizeof(int), stream);
    k_winner<<<(2 * BATCH + 255) / 256, 256, 0, stream>>>(src, dst, winner);
    k1_msg_gru<<<(2 * BATCH) / 16, 256, 0, stream>>>(
        src, dst, ts, memory, last_update,
        w_t_msg, b_t_msg, W_msg1, b_msg1, W_msg2, b_msg2,
        W_ih, b_ih, W_hh, b_hh, new_mem);
    k2_topk<<<(BATCH + 255) / 256, 256, 0, stream>>>(
        src, ts, nbr_ids, nbr_ts, sel_id, sel_td, sel_mk);
    k3a_qu<<<BATCH / 16, 256, 0, stream>>>(
        src, memory, new_mem, winner, Wq, bq, Wk, bk, nf_ws, u_ws, qb_ws);
    k3b_score<<<BATCH / 4, 256, 0, stream>>>(
        memory, new_mem, winner, sel_id, sel_td, sel_mk,
        w_t_att, b_t_att, u_ws, qb_ws, kvb_ws, satt_ws);
    k3c_mlp<<<BATCH / 16, 256, 0, stream>>>(
        kvb_ws, satt_ws, nf_ws, Wv, bv, Wo, bo, Wm1, bm1, Wm2, bm2,
        ln_g, ln_b, out);
}

// Round 3
// 177.507 us; speedup vs baseline: 4.3579x; 2.2309x over previous
//
#include <hip/hip_runtime.h>
#include <math.h>

#define BATCH  8192
#define NNODES 500000
#define DIM    128
#define TDIM   64
#define KNB    32
#define KSEL   16

typedef float  f32x4  __attribute__((ext_vector_type(4)));
typedef __bf16 bf16x8 __attribute__((ext_vector_type(8)));
typedef short  s16x8  __attribute__((ext_vector_type(8)));

#define MFMA(a,b,c) __builtin_amdgcn_mfma_f32_16x16x32_bf16(a,b,c,0,0,0)

__device__ __forceinline__ float sigmoidf_(float x) { return 1.f / (1.f + expf(-x)); }
__device__ __forceinline__ float dot4(float4 a, float4 b) {
    return a.x * b.x + a.y * b.y + a.z * b.z + a.w * b.w;
}
__device__ __forceinline__ unsigned short f2bf(float x) {
    unsigned u = __builtin_bit_cast(unsigned, x);
    unsigned r = (u + 0x7FFFu + ((u >> 16) & 1u)) >> 16;
    return (unsigned short)r;
}
__device__ __forceinline__ float bf2f(unsigned short u) {
    unsigned v = ((unsigned)u) << 16;
    return __builtin_bit_cast(float, v);
}
__device__ __forceinline__ bf16x8 ldfrag(const unsigned short* p) {
    s16x8 v = *(const s16x8*)p;
    return __builtin_bit_cast(bf16x8, v);
}

// ---------------------------------------------------------------------------
// K0: convert the 4 k1 weight matrices to bf16 (same [nout][k] layout).
// ---------------------------------------------------------------------------
__global__ __launch_bounds__(256) void k0_cvt4(
    const float* __restrict__ s0, const float* __restrict__ s1,
    const float* __restrict__ s2, const float* __restrict__ s3,
    unsigned short* __restrict__ d0, unsigned short* __restrict__ d1,
    unsigned short* __restrict__ d2, unsigned short* __restrict__ d3)
{
    int i = blockIdx.x * 256 + threadIdx.x;
    if (i < 40960) { d0[i] = f2bf(s0[i]); }
    else if (i < 57344)  { int j = i - 40960;  d1[j] = f2bf(s1[j]); }
    else if (i < 106496) { int j = i - 57344;  d2[j] = f2bf(s2[j]); }
    else if (i < 155648) { int j = i - 106496; d3[j] = f2bf(s3[j]); }
}

// ---------------------------------------------------------------------------
// K_winner: last-write-wins scatter resolution.
// ---------------------------------------------------------------------------
__global__ __launch_bounds__(256) void k_winner(const int* __restrict__ src,
                                                const int* __restrict__ dst,
                                                int* __restrict__ winner) {
    int i = blockIdx.x * 256 + threadIdx.x;
    if (i < 2 * BATCH) {
        int v = (i < BATCH) ? src[i] : dst[i - BATCH];
        atomicMax(&winner[v], i);
    }
}

// ---------------------------------------------------------------------------
// K1 (MFMA): message MLP + GRU for all 2B rows. 16 rows/block, 4 waves.
// Wave w owns output cols [w*32, w*32+32) of every GEMM stage.
// A-frag: lane l reads 8 contiguous bf16 at row (l&15), k-off (l>>4)*8 (LDS).
// B-frag: lane l reads 8 contiguous bf16 from weight row (n_tile*16 + (l&15)).
// D: col = lane&15 (n), row = (lane>>4)*4 + reg (m).   [m89/m92-verified maps]
// ---------------------------------------------------------------------------
__global__ __launch_bounds__(256) void k1_mfma(
    const int* __restrict__ src, const int* __restrict__ dst, const float* __restrict__ ts,
    const float* __restrict__ memory, const float* __restrict__ last_update,
    const float* __restrict__ w_t, const float* __restrict__ b_t,
    const unsigned short* __restrict__ W1b, const float* __restrict__ b1,
    const unsigned short* __restrict__ W2b, const float* __restrict__ b2,
    const unsigned short* __restrict__ Wihb, const float* __restrict__ bih,
    const unsigned short* __restrict__ Whhb, const float* __restrict__ bhh,
    float* __restrict__ new_mem)
{
    __shared__ unsigned short sxb[16][328];   // [self 0:128 | oth 128:256 | te 256:320], +8 pad
    __shared__ unsigned short hb [16][136];   // h1, then msg (bf16), +8 pad
    __shared__ int   s_node[16];
    __shared__ int   s_oth [16];
    __shared__ float s_dt  [16];

    const int tid  = threadIdx.x;
    const int base = blockIdx.x * 16;

    if (tid < 16) {
        int gi = base + tid;
        int node, oth; float t;
        if (gi < BATCH) { node = src[gi];         oth = dst[gi];         t = ts[gi]; }
        else            { node = dst[gi - BATCH]; oth = src[gi - BATCH]; t = ts[gi - BATCH]; }
        s_node[tid] = node;
        s_oth[tid]  = oth;
        s_dt[tid]   = t - last_update[node];
    }
    __syncthreads();

    // stage x = [self | oth | te] as bf16
    for (int idx = tid; idx < 16 * 32; idx += 256) {
        int r = idx >> 5, c4 = (idx & 31) << 2;
        float4 vs = *(const float4*)&memory[(size_t)s_node[r] * DIM + c4];
        float4 vo = *(const float4*)&memory[(size_t)s_oth[r]  * DIM + c4];
        sxb[r][c4 + 0] = f2bf(vs.x); sxb[r][c4 + 1] = f2bf(vs.y);
        sxb[r][c4 + 2] = f2bf(vs.z); sxb[r][c4 + 3] = f2bf(vs.w);
        sxb[r][128 + c4 + 0] = f2bf(vo.x); sxb[r][128 + c4 + 1] = f2bf(vo.y);
        sxb[r][128 + c4 + 2] = f2bf(vo.z); sxb[r][128 + c4 + 3] = f2bf(vo.w);
    }
    for (int idx = tid; idx < 16 * TDIM; idx += 256) {
        int r = idx >> 6, c = idx & 63;
        float f = s_dt[r] * w_t[c] + b_t[c];
        sxb[r][256 + c] = f2bf((c & 1) ? cosf(f) : sinf(f));
    }
    __syncthreads();

    const int w    = tid >> 6;
    const int l    = tid & 63;
    const int rowA = l & 15;        // A-frag row / B-frag n within tile
    const int kg   = l >> 4;        // k-group (8 elems each)
    const int n0   = w * 32;
    const int col  = l & 15;        // D col within tile
    const int rgrp = l >> 4;        // D row group (rows rgrp*4 .. +3)

    // ---- stage 1: h1 = relu(x @ W1^T + b1), K=320 ---------------------------
    {
        f32x4 a0 = {0.f, 0.f, 0.f, 0.f}, a1 = {0.f, 0.f, 0.f, 0.f};
        #pragma unroll
        for (int kt = 0; kt < 10; ++kt) {
            int ko = kt * 32 + kg * 8;
            bf16x8 av  = ldfrag(&sxb[rowA][ko]);
            bf16x8 b0  = ldfrag(&W1b[(size_t)(n0 + rowA) * 320 + ko]);
            bf16x8 b1v = ldfrag(&W1b[(size_t)(n0 + 16 + rowA) * 320 + ko]);
            a0 = MFMA(av, b0, a0);
            a1 = MFMA(av, b1v, a1);
        }
        float bb0 = b1[n0 + col], bb1 = b1[n0 + 16 + col];
        #pragma unroll
        for (int rgi = 0; rgi < 4; ++rgi) {
            int rr = rgrp * 4 + rgi;
            hb[rr][n0 + col]      = f2bf(fmaxf(a0[rgi] + bb0, 0.f));
            hb[rr][n0 + 16 + col] = f2bf(fmaxf(a1[rgi] + bb1, 0.f));
        }
    }
    __syncthreads();

    // ---- stage 2: msg = h1 @ W2^T + b2, K=128 -------------------------------
    {
        f32x4 m0 = {0.f, 0.f, 0.f, 0.f}, m1 = {0.f, 0.f, 0.f, 0.f};
        #pragma unroll
        for (int kt = 0; kt < 4; ++kt) {
            int ko = kt * 32 + kg * 8;
            bf16x8 av  = ldfrag(&hb[rowA][ko]);
            bf16x8 b0  = ldfrag(&W2b[(size_t)(n0 + rowA) * 128 + ko]);
            bf16x8 b1v = ldfrag(&W2b[(size_t)(n0 + 16 + rowA) * 128 + ko]);
            m0 = MFMA(av, b0, m0);
            m1 = MFMA(av, b1v, m1);
        }
        __syncthreads();   // everyone done reading h1 before overwrite
        float bb0 = b2[n0 + col], bb1 = b2[n0 + 16 + col];
        #pragma unroll
        for (int rgi = 0; rgi < 4; ++rgi) {
            int rr = rgrp * 4 + rgi;
            hb[rr][n0 + col]      = f2bf(m0[rgi] + bb0);
            hb[rr][n0 + 16 + col] = f2bf(m1[rgi] + bb1);
        }
    }
    __syncthreads();

    // ---- stage 3: GRU gates, two 16-col passes ------------------------------
    #pragma unroll
    for (int t = 0; t < 2; ++t) {
        const int db = n0 + t * 16;                 // d tile base
        f32x4 ir_ = {0.f,0.f,0.f,0.f}, iz_ = {0.f,0.f,0.f,0.f}, ig_ = {0.f,0.f,0.f,0.f};
        f32x4 hr_ = {0.f,0.f,0.f,0.f}, hz_ = {0.f,0.f,0.f,0.f}, hg_ = {0.f,0.f,0.f,0.f};
        #pragma unroll
        for (int kt = 0; kt < 4; ++kt) {
            int ko = kt * 32 + kg * 8;
            bf16x8 am = ldfrag(&hb[rowA][ko]);        // msg
            bf16x8 ah = ldfrag(&sxb[rowA][ko]);       // self (cols 0..127)
            int br = db + rowA;
            ir_ = MFMA(am, ldfrag(&Wihb[(size_t)(      br) * 128 + ko]), ir_);
            iz_ = MFMA(am, ldfrag(&Wihb[(size_t)(128 + br) * 128 + ko]), iz_);
            ig_ = MFMA(am, ldfrag(&Wihb[(size_t)(256 + br) * 128 + ko]), ig_);
            hr_ = MFMA(ah, ldfrag(&Whhb[(size_t)(      br) * 128 + ko]), hr_);
            hz_ = MFMA(ah, ldfrag(&Whhb[(size_t)(128 + br) * 128 + ko]), hz_);
            hg_ = MFMA(ah, ldfrag(&Whhb[(size_t)(256 + br) * 128 + ko]), hg_);
        }
        const int d = db + col;
        float bir = bih[d], biz = bih[128 + d], big = bih[256 + d];
        float bhr = bhh[d], bhz = bhh[128 + d], bhg = bhh[256 + d];
        #pragma unroll
        for (int rgi = 0; rgi < 4; ++rgi) {
            int rr = rgrp * 4 + rgi;
            float rv = sigmoidf_((ir_[rgi] + bir) + (hr_[rgi] + bhr));
            float zv = sigmoidf_((iz_[rgi] + biz) + (hz_[rgi] + bhz));
            float gv = tanhf((ig_[rgi] + big) + rv * (hg_[rgi] + bhg));
            float selfv = bf2f(sxb[rr][d]);
            new_mem[(size_t)(base + rr) * DIM + d] = (1.f - zv) * gv + zv * selfv;
        }
    }
}

// ---------------------------------------------------------------------------
// K2: temporal top-16-of-32 per src row.
// ---------------------------------------------------------------------------
__global__ __launch_bounds__(256) void k2_topk(
    const int* __restrict__ src, const float* __restrict__ ts,
    const int* __restrict__ nbr_ids, const float* __restrict__ nbr_ts,
    int* __restrict__ sel_id, float* __restrict__ sel_td, int* __restrict__ sel_mk)
{
    int b = blockIdx.x * 256 + threadIdx.x;
    if (b >= BATCH) return;
    int   s = src[b];
    float t = ts[b];
    const int*   ip = nbr_ids + (size_t)s * KNB;
    const float* tp = nbr_ts  + (size_t)s * KNB;
    float kt[KNB]; int kid[KNB];
    #pragma unroll
    for (int j = 0; j < KNB; ++j) {
        int id = ip[j]; float nt = tp[j];
        bool valid = (id >= 0) && (nt < t + 1e-6f);
        kt[j]  = valid ? nt : -1e30f;
        kid[j] = id;
    }
    unsigned picked = 0u;
    for (int sI = 0; sI < KSEL; ++sI) {
        float bv = -3.4e38f; int bj = 0; int bid = 0;
        #pragma unroll
        for (int j = 0; j < KNB; ++j) {
            bool avail = !((picked >> j) & 1u);
            if (avail && kt[j] > bv) { bv = kt[j]; bj = j; bid = kid[j]; }
        }
        picked |= (1u << bj);
        bool mk = bv > -1e29f;
        int id = mk ? (bid < 0 ? 0 : (bid > NNODES - 1 ? NNODES - 1 : bid)) : 0;
        sel_id[b * KSEL + sI] = id;
        sel_td[b * KSEL + sI] = mk ? (t - bv) : 0.f;
        sel_mk[b * KSEL + sI] = mk ? 1 : 0;
    }
}

// ---------------------------------------------------------------------------
// K3a: node_feat gather + Q proj + qb = Q.bk + u = Wk_h^T Q_h.
// ---------------------------------------------------------------------------
__global__ __launch_bounds__(256) void k3a_qu(
    const int* __restrict__ src,
    const float* __restrict__ memory, const float* __restrict__ new_mem,
    const int* __restrict__ winner,
    const float* __restrict__ Wq, const float* __restrict__ bq,
    const float* __restrict__ Wk, const float* __restrict__ bk,
    float* __restrict__ nf_ws, float* __restrict__ u_ws, float* __restrict__ qb_ws)
{
    __shared__ float s_nf[16][128];
    __shared__ float s_q [16][128];
    __shared__ const float* s_ptr[16];

    const int tid = threadIdx.x;
    const int base = blockIdx.x * 16;

    if (tid < 16) {
        int v = src[base + tid];
        int wv = winner[v];
        s_ptr[tid] = (wv >= 0) ? (new_mem + (size_t)wv * DIM)
                               : (memory  + (size_t)v  * DIM);
    }
    __syncthreads();

    for (int idx = tid; idx < 16 * 32; idx += 256) {
        int r = idx >> 5, c4 = (idx & 31) << 2;
        float4 v = *(const float4*)&s_ptr[r][c4];
        *(float4*)&s_nf[r][c4] = v;
        *(float4*)&nf_ws[(size_t)(base + r) * DIM + c4] = v;
    }
    __syncthreads();

    const int d  = tid & 127;
    const int rg = tid >> 7;

    {
        float acc[8];
        float bb = bq[d];
        #pragma unroll
        for (int r = 0; r < 8; ++r) acc[r] = bb;
        const float* wrow = Wq + (size_t)d * 128;
        for (int k = 0; k < 128; k += 4) {
            float4 w4 = *(const float4*)&wrow[k];
            #pragma unroll
            for (int r = 0; r < 8; ++r)
                acc[r] += dot4(w4, *(const float4*)&s_nf[rg * 8 + r][k]);
        }
        #pragma unroll
        for (int r = 0; r < 8; ++r) s_q[rg * 8 + r][d] = acc[r];
    }
    __syncthreads();

    {
        int r = tid >> 4, rem = tid & 15, h = rem >> 3, p = rem & 7;
        float part = 0.f;
        #pragma unroll
        for (int j = 0; j < 8; ++j) {
            int dd = h * 64 + p * 8 + j;
            part += s_q[r][dd] * bk[dd];
        }
        part += __shfl_xor(part, 1);
        part += __shfl_xor(part, 2);
        part += __shfl_xor(part, 4);
        if (p == 0) qb_ws[(base + r) * 2 + h] = part;
    }

    {
        const int lane_c = tid & 63;
        const int sel = tid >> 6;
        const int rg2 = sel & 1;
        const int h   = sel >> 1;
        float acc0[8], acc1[8], acc2[8];
        #pragma unroll
        for (int r = 0; r < 8; ++r) { acc0[r] = 0.f; acc1[r] = 0.f; acc2[r] = 0.f; }
        for (int dh = 0; dh < 64; ++dh) {
            float qv[8];
            #pragma unroll
            for (int r = 0; r < 8; ++r) qv[r] = s_q[rg2 * 8 + r][h * 64 + dh];
            const float* wp = Wk + (size_t)(h * 64 + dh) * 192 + lane_c;
            float w0 = wp[0], w1 = wp[64], w2 = wp[128];
            #pragma unroll
            for (int r = 0; r < 8; ++r) {
                acc0[r] += w0 * qv[r];
                acc1[r] += w1 * qv[r];
                acc2[r] += w2 * qv[r];
            }
        }
        #pragma unroll
        for (int r = 0; r < 8; ++r) {
            size_t rowb = (size_t)(base + rg2 * 8 + r) * 384 + h * 192 + lane_c;
            u_ws[rowb]       = acc0[r];
            u_ws[rowb + 64]  = acc1[r];
            u_ws[rowb + 128] = acc2[r];
        }
    }
}

// ---------------------------------------------------------------------------
// K3b: neighbor gather + scores + softmax + kvbar. One wave per row.
// ---------------------------------------------------------------------------
__global__ __launch_bounds__(256) void k3b_score(
    const float* __restrict__ memory, const float* __restrict__ new_mem,
    const int* __restrict__ winner,
    const int* __restrict__ sel_id, const float* __restrict__ sel_td,
    const int* __restrict__ sel_mk,
    const float* __restrict__ w_ta, const float* __restrict__ b_ta,
    const float* __restrict__ u_ws, const float* __restrict__ qb_ws,
    float* __restrict__ kvb_ws, float* __restrict__ satt_ws)
{
    const int lane = threadIdx.x & 63;
    const int w    = threadIdx.x >> 6;
    const int b    = blockIdx.x * 4 + w;

    __shared__ float s_kv  [4][16][196];
    __shared__ float s_u   [4][384];
    __shared__ float s_attn[4][2][16];
    __shared__ float s_td  [4][16];
    __shared__ int   s_mk  [4][16];
    __shared__ const float* s_ptr[4][16];

    if (lane < 16) {
        int id = sel_id[b * KSEL + lane];
        int wi = winner[id];
        s_ptr[w][lane] = (wi >= 0) ? (new_mem + (size_t)wi * DIM)
                                   : (memory  + (size_t)id * DIM);
        s_td[w][lane] = sel_td[b * KSEL + lane];
        s_mk[w][lane] = sel_mk[b * KSEL + lane];
    }
    #pragma unroll
    for (int i = 0; i < 6; ++i)
        s_u[w][i * 64 + lane] = u_ws[(size_t)b * 384 + i * 64 + lane];
    __syncthreads();

    {
        #pragma unroll
        for (int it = 0; it < 8; ++it) {
            int n  = it * 2 + (lane >> 5);
            int c4 = (lane & 31) << 2;
            *(float4*)&s_kv[w][n][c4] = *(const float4*)&s_ptr[w][n][c4];
        }
        float wt = w_ta[lane], bt = b_ta[lane];
        #pragma unroll
        for (int n = 0; n < 16; ++n) {
            float f = s_td[w][n] * wt + bt;
            s_kv[w][n][128 + lane] = (lane & 1) ? cosf(f) : sinf(f);
        }
    }
    __syncthreads();

    {
        int h = (lane >> 4) & 1, n = lane & 15, half = lane >> 5;
        float acc = (half == 0) ? qb_ws[b * 2 + h] : 0.f;
        const float* kvrow = &s_kv[w][n][half * 96];
        const float* urow  = &s_u[w][h * 192 + half * 96];
        #pragma unroll
        for (int k = 0; k < 96; k += 4)
            acc += dot4(*(const float4*)&kvrow[k], *(const float4*)&urow[k]);
        acc += __shfl_xor(acc, 32);
        int mk = s_mk[w][n];
        float s = mk ? acc * 0.125f : -INFINITY;
        float mx = s;
        #pragma unroll
        for (int m = 1; m < 16; m <<= 1) mx = fmaxf(mx, __shfl_xor(mx, m));
        float p = (mk && mx > -1e37f) ? expf(s - mx) : 0.f;
        float den = p;
        #pragma unroll
        for (int m = 1; m < 16; m <<= 1) den += __shfl_xor(den, m);
        float a = (den > 0.f) ? (p / den) : 0.f;
        if (lane < 32) s_attn[w][h][n] = a;
        if (lane == 0 || lane == 16) satt_ws[b * 2 + h] = (den > 0.f) ? 1.f : 0.f;
    }
    __syncthreads();

    #pragma unroll
    for (int i = 0; i < 3; ++i) {
        int c = i * 64 + lane;
        float k0 = 0.f, k1 = 0.f;
        #pragma unroll
        for (int n = 0; n < 16; ++n) {
            float v = s_kv[w][n][c];
            k0 += s_attn[w][0][n] * v;
            k1 += s_attn[w][1][n] * v;
        }
        kvb_ws[(size_t)b * 384 + c]       = k0;
        kvb_ws[(size_t)b * 384 + 192 + c] = k1;
    }
}

// ---------------------------------------------------------------------------
// K3c: dense back-end + LayerNorm. 16 rows/block, 8-row ILP.
// ---------------------------------------------------------------------------
__global__ __launch_bounds__(256) void k3c_mlp(
    const float* __restrict__ kvb_ws, const float* __restrict__ satt_ws,
    const float* __restrict__ nf_ws,
    const float* __restrict__ Wv, const float* __restrict__ bv,
    const float* __restrict__ Wo, const float* __restrict__ bo,
    const float* __restrict__ Wm1, const float* __restrict__ bm1,
    const float* __restrict__ Wm2, const float* __restrict__ bm2,
    const float* __restrict__ ln_g, const float* __restrict__ ln_b,
    float* __restrict__ out)
{
    __shared__ float s_pool[16 * 384];
    __shared__ float s_nf[16][128];
    __shared__ float s_o [16][128];
    __shared__ float s_satt[16][2];

    float (*s_kvb)[384] = (float(*)[384])s_pool;
    float (*s_ao)[128]  = (float(*)[128])s_pool;
    float (*s_h1)[128]  = (float(*)[128])(s_pool + 16 * 128);
    float (*s_h2)[128]  = (float(*)[128])(s_pool + 32 * 128);

    const int tid = threadIdx.x;
    const int base = blockIdx.x * 16;

    for (int idx = tid; idx < 16 * 96; idx += 256) {
        int r = idx / 96, j = (idx % 96) << 2;
        *(float4*)&s_kvb[r][j] = *(const float4*)&kvb_ws[(size_t)(base + r) * 384 + j];
    }
    for (int idx = tid; idx < 16 * 32; idx += 256) {
        int r = idx >> 5, j = (idx & 31) << 2;
        *(float4*)&s_nf[r][j] = *(const float4*)&nf_ws[(size_t)(base + r) * DIM + j];
    }
    if (tid < 32) s_satt[tid >> 1][tid & 1] = satt_ws[(base + (tid >> 1)) * 2 + (tid & 1)];
    __syncthreads();

    const int d  = tid & 127;
    const int rg = tid >> 7;

    {
        float acc[8];
        int h = d >> 6;
        float bb = bv[d];
        #pragma unroll
        for (int r = 0; r < 8; ++r) acc[r] = s_satt[rg * 8 + r][h] * bb;
        const float* wrow = Wv + (size_t)d * 192;
        for (int k = 0; k < 192; k += 4) {
            float4 w4 = *(const float4*)&wrow[k];
            #pragma unroll
            for (int r = 0; r < 8; ++r)
                acc[r] += dot4(w4, *(const float4*)&s_kvb[rg * 8 + r][h * 192 + k]);
        }
        __syncthreads();
        #pragma unroll
        for (int r = 0; r < 8; ++r) s_o[rg * 8 + r][d] = acc[r];
    }
    __syncthreads();

    {
        float acc[8];
        float bb = bo[d];
        #pragma unroll
        for (int r = 0; r < 8; ++r) acc[r] = bb;
        const float* wrow = Wo + (size_t)d * 128;
        for (int k = 0; k < 128; k += 4) {
            float4 w4 = *(const float4*)&wrow[k];
            #pragma unroll
            for (int r = 0; r < 8; ++r)
                acc[r] += dot4(w4, *(const float4*)&s_o[rg * 8 + r][k]);
        }
        #pragma unroll
        for (int r = 0; r < 8; ++r) s_ao[rg * 8 + r][d] = acc[r];
    }
    __syncthreads();

    {
        float acc[8];
        float bb = bm1[d];
        #pragma unroll
        for (int r = 0; r < 8; ++r) acc[r] = bb;
        const float* wrow = Wm1 + (size_t)d * 256;
        for (int k = 0; k < 128; k += 4) {
            float4 w4  = *(const float4*)&wrow[k];
            float4 w42 = *(const float4*)&wrow[128 + k];
            #pragma unroll
            for (int r = 0; r < 8; ++r) {
                acc[r] += dot4(w4,  *(const float4*)&s_ao[rg * 8 + r][k]);
                acc[r] += dot4(w42, *(const float4*)&s_nf[rg * 8 + r][k]);
            }
        }
        #pragma unroll
        for (int r = 0; r < 8; ++r) s_h1[rg * 8 + r][d] = fmaxf(acc[r], 0.f);
    }
    __syncthreads();

    {
        float acc[8];
        float bb = bm2[d];
        #pragma unroll
        for (int r = 0; r < 8; ++r) acc[r] = bb;
        const float* wrow = Wm2 + (size_t)d * 128;
        for (int k = 0; k < 128; k += 4) {
            float4 w4 = *(const float4*)&wrow[k];
            #pragma unroll
            for (int r = 0; r < 8; ++r)
                acc[r] += dot4(w4, *(const float4*)&s_h1[rg * 8 + r][k]);
        }
        #pragma unroll
        for (int r = 0; r < 8; ++r) s_h2[rg * 8 + r][d] = acc[r];
    }
    __syncthreads();

    {
        const int wv = tid >> 6, lane = tid & 63;
        float lg0 = ln_g[lane], lg1 = ln_g[64 + lane];
        float lb0 = ln_b[lane], lb1 = ln_b[64 + lane];
        #pragma unroll
        for (int rr = 0; rr < 4; ++rr) {
            int r = wv * 4 + rr;
            float v0 = s_h2[r][lane], v1 = s_h2[r][64 + lane];
            float sum = v0 + v1;
            #pragma unroll
            for (int m = 1; m < 64; m <<= 1) sum += __shfl_xor(sum, m);
            float mean = sum * (1.f / 128.f);
            float e0 = v0 - mean, e1 = v1 - mean;
            float sq = e0 * e0 + e1 * e1;
            #pragma unroll
            for (int m = 1; m < 64; m <<= 1) sq += __shfl_xor(sq, m);
            float inv = rsqrtf(sq * (1.f / 128.f) + 1e-5f);
            out[(size_t)(base + r) * DIM + lane]      = e0 * inv * lg0 + lb0;
            out[(size_t)(base + r) * DIM + 64 + lane] = e1 * inv * lg1 + lb1;
        }
    }
}

// ---------------------------------------------------------------------------
extern "C" void kernel_launch(void* const* d_in, const int* in_sizes, int n_in,
                              void* d_out, int out_size, void* d_ws, size_t ws_size,
                              hipStream_t stream) {
    const int*   src         = (const int*)  d_in[0];
    const int*   dst         = (const int*)  d_in[1];
    const float* ts          = (const float*)d_in[2];
    const int*   nbr_ids     = (const int*)  d_in[3];
    const float* nbr_ts      = (const float*)d_in[4];
    const float* memory      = (const float*)d_in[5];
    const float* last_update = (const float*)d_in[6];
    const float* w_t_msg     = (const float*)d_in[7];
    const float* b_t_msg     = (const float*)d_in[8];
    const float* W_msg1      = (const float*)d_in[9];
    const float* b_msg1      = (const float*)d_in[10];
    const float* W_msg2      = (const float*)d_in[11];
    const float* b_msg2      = (const float*)d_in[12];
    const float* W_ih        = (const float*)d_in[13];
    const float* b_ih        = (const float*)d_in[14];
    const float* W_hh        = (const float*)d_in[15];
    const float* b_hh        = (const float*)d_in[16];
    const float* w_t_att     = (const float*)d_in[17];
    const float* b_t_att     = (const float*)d_in[18];
    const float* Wq          = (const float*)d_in[19];
    const float* bq          = (const float*)d_in[20];
    const float* Wk          = (const float*)d_in[21];
    const float* bk          = (const float*)d_in[22];
    const float* Wv          = (const float*)d_in[23];
    const float* bv          = (const float*)d_in[24];
    const float* Wo          = (const float*)d_in[25];
    const float* bo          = (const float*)d_in[26];
    const float* Wm1         = (const float*)d_in[27];
    const float* bm1         = (const float*)d_in[28];
    const float* Wm2         = (const float*)d_in[29];
    const float* bm2         = (const float*)d_in[30];
    const float* ln_g        = (const float*)d_in[31];
    const float* ln_b        = (const float*)d_in[32];
    float* out = (float*)d_out;

    char* ws = (char*)d_ws;
    size_t off = 0;
    float* new_mem = (float*)(ws + off); off += (size_t)2 * BATCH * DIM * 4;
    int*   winner  = (int*)  (ws + off); off += 2097152;
    int*   sel_id  = (int*)  (ws + off); off += (size_t)BATCH * KSEL * 4;
    float* sel_td  = (float*)(ws + off); off += (size_t)BATCH * KSEL * 4;
    int*   sel_mk  = (int*)  (ws + off); off += (size_t)BATCH * KSEL * 4;
    float* nf_ws   = (float*)(ws + off); off += (size_t)BATCH * DIM * 4;
    float* u_ws    = (float*)(ws + off); off += (size_t)BATCH * 384 * 4;
    float* qb_ws   = (float*)(ws + off); off += (size_t)BATCH * 2 * 4;
    float* kvb_ws  = (float*)(ws + off); off += (size_t)BATCH * 384 * 4;
    float* satt_ws = (float*)(ws + off); off += (size_t)BATCH * 2 * 4;
    unsigned short* W1b  = (unsigned short*)(ws + off); off += 40960u * 2;
    unsigned short* W2b  = (unsigned short*)(ws + off); off += 16384u * 2;
    unsigned short* Wihb = (unsigned short*)(ws + off); off += 49152u * 2;
    unsigned short* Whhb = (unsigned short*)(ws + off); off += 49152u * 2;

    hipMemsetAsync(winner, 0xFF, NNODES * sizeof(int), stream);
    k0_cvt4<<<608, 256, 0, stream>>>(W_msg1, W_msg2, W_ih, W_hh, W1b, W2b, Wihb, Whhb);
    k_winner<<<(2 * BATCH + 255) / 256, 256, 0, stream>>>(src, dst, winner);
    k1_mfma<<<(2 * BATCH) / 16, 256, 0, stream>>>(
        src, dst, ts, memory, last_update,
        w_t_msg, b_t_msg, W1b, b_msg1, W2b, b_msg2,
        Wihb, b_ih, Whhb, b_hh, new_mem);
    k2_topk<<<(BATCH + 255) / 256, 256, 0, stream>>>(
        src, ts, nbr_ids, nbr_ts, sel_id, sel_td, sel_mk);
    k3a_qu<<<BATCH / 16, 256, 0, stream>>>(
        src, memory, new_mem, winner, Wq, bq, Wk, bk, nf_ws, u_ws, qb_ws);
    k3b_score<<<BATCH / 4, 256, 0, stream>>>(
        memory, new_mem, winner, sel_id, sel_td, sel_mk,
        w_t_att, b_t_att, u_ws, qb_ws, kvb_ws, satt_ws);
    k3c_mlp<<<BATCH / 16, 256, 0, stream>>>(
        kvb_ws, satt_ws, nf_ws, Wv, bv, Wo, bo, Wm1, bm1, Wm2, bm2,
        ln_g, ln_b, out);
}

// Round 4
// 124.401 us; speedup vs baseline: 6.2183x; 1.4269x over previous
//
#include <hip/hip_runtime.h>
#include <math.h>

#define BATCH  8192
#define NNODES 500000
#define DIM    128
#define TDIM   64
#define KNB    32
#define KSEL   16

// bf16 weight pool element offsets
#define OFF_W1   0
#define OFF_W2   40960
#define OFF_WIH  57344
#define OFF_WHH  106496
#define OFF_WQ   155648
#define OFF_WV   172032
#define OFF_WO   196608
#define OFF_WM1  212992
#define OFF_WM2  245760
#define OFF_WKT  262144
#define CVT_TOT  286720

typedef float  f32x4  __attribute__((ext_vector_type(4)));
typedef __bf16 bf16x8 __attribute__((ext_vector_type(8)));
typedef short  s16x8  __attribute__((ext_vector_type(8)));

#define MFMA(a,b,c) __builtin_amdgcn_mfma_f32_16x16x32_bf16(a,b,c,0,0,0)

__device__ __forceinline__ float sigmoidf_(float x) { return 1.f / (1.f + expf(-x)); }
__device__ __forceinline__ float dot4(float4 a, float4 b) {
    return a.x * b.x + a.y * b.y + a.z * b.z + a.w * b.w;
}
__device__ __forceinline__ unsigned short f2bf(float x) {
    unsigned u = __builtin_bit_cast(unsigned, x);
    unsigned r = (u + 0x7FFFu + ((u >> 16) & 1u)) >> 16;
    return (unsigned short)r;
}
__device__ __forceinline__ float bf2f(unsigned short u) {
    unsigned v = ((unsigned)u) << 16;
    return __builtin_bit_cast(float, v);
}
__device__ __forceinline__ bf16x8 ldfrag(const unsigned short* p) {
    s16x8 v = *(const s16x8*)p;
    return __builtin_bit_cast(bf16x8, v);
}

// ---------------------------------------------------------------------------
// K0: convert all dense weights to bf16 into one pool. WkT is transposed:
// WkT[h][c][dh] = Wk[h*64+dh][c]  (so MFMA B-frags read contiguous dh).
// ---------------------------------------------------------------------------
__global__ __launch_bounds__(256) void k0_cvt(
    const float* __restrict__ sW1, const float* __restrict__ sW2,
    const float* __restrict__ sWih, const float* __restrict__ sWhh,
    const float* __restrict__ sWq, const float* __restrict__ sWv,
    const float* __restrict__ sWo, const float* __restrict__ sWm1,
    const float* __restrict__ sWm2, const float* __restrict__ sWk,
    unsigned short* __restrict__ dst)
{
    int i = blockIdx.x * 256 + threadIdx.x;
    if (i >= CVT_TOT) return;
    float v;
    if      (i < OFF_W2)  { v = sW1 [i - OFF_W1 ]; }
    else if (i < OFF_WIH) { v = sW2 [i - OFF_W2 ]; }
    else if (i < OFF_WHH) { v = sWih[i - OFF_WIH]; }
    else if (i < OFF_WQ)  { v = sWhh[i - OFF_WHH]; }
    else if (i < OFF_WV)  { v = sWq [i - OFF_WQ ]; }
    else if (i < OFF_WO)  { v = sWv [i - OFF_WV ]; }
    else if (i < OFF_WM1) { v = sWo [i - OFF_WO ]; }
    else if (i < OFF_WM2) { v = sWm1[i - OFF_WM1]; }
    else if (i < OFF_WKT) { v = sWm2[i - OFF_WM2]; }
    else {
        int j = i - OFF_WKT;           // h*12288 + c*64 + dh
        int h = j / 12288, rem = j % 12288;
        int c = rem >> 6, dh = rem & 63;
        v = sWk[(size_t)(h * 64 + dh) * 192 + c];
    }
    dst[i] = f2bf(v);
}

// ---------------------------------------------------------------------------
// K_winner: last-write-wins scatter resolution.
// ---------------------------------------------------------------------------
__global__ __launch_bounds__(256) void k_winner(const int* __restrict__ src,
                                                const int* __restrict__ dst,
                                                int* __restrict__ winner) {
    int i = blockIdx.x * 256 + threadIdx.x;
    if (i < 2 * BATCH) {
        int v = (i < BATCH) ? src[i] : dst[i - BATCH];
        atomicMax(&winner[v], i);
    }
}

// ---------------------------------------------------------------------------
// K1 (MFMA): message MLP + GRU. 32 rows/block, 4 waves, 2 A-tiles per wave.
// Wave w owns output cols [w*32, w*32+32) of every GEMM stage.
// ---------------------------------------------------------------------------
__global__ __launch_bounds__(256) void k1_mfma(
    const int* __restrict__ src, const int* __restrict__ dst, const float* __restrict__ ts,
    const float* __restrict__ memory, const float* __restrict__ last_update,
    const float* __restrict__ w_t, const float* __restrict__ b_t,
    const unsigned short* __restrict__ Wp,
    const float* __restrict__ b1, const float* __restrict__ b2,
    const float* __restrict__ bih, const float* __restrict__ bhh,
    float* __restrict__ new_mem)
{
    __shared__ unsigned short sxb[32][328];   // [self|oth|te] bf16, pad 8
    __shared__ unsigned short hb [32][136];   // h1 then msg
    __shared__ int   s_node[32];
    __shared__ int   s_oth [32];
    __shared__ float s_dt  [32];

    const unsigned short* W1b  = Wp + OFF_W1;
    const unsigned short* W2b  = Wp + OFF_W2;
    const unsigned short* Wihb = Wp + OFF_WIH;
    const unsigned short* Whhb = Wp + OFF_WHH;

    const int tid  = threadIdx.x;
    const int base = blockIdx.x * 32;

    if (tid < 32) {
        int gi = base + tid;
        int node, oth; float t;
        if (gi < BATCH) { node = src[gi];         oth = dst[gi];         t = ts[gi]; }
        else            { node = dst[gi - BATCH]; oth = src[gi - BATCH]; t = ts[gi - BATCH]; }
        s_node[tid] = node;
        s_oth[tid]  = oth;
        s_dt[tid]   = t - last_update[node];
    }
    __syncthreads();

    for (int idx = tid; idx < 32 * 32; idx += 256) {
        int r = idx >> 5, c4 = (idx & 31) << 2;
        float4 vs = *(const float4*)&memory[(size_t)s_node[r] * DIM + c4];
        float4 vo = *(const float4*)&memory[(size_t)s_oth[r]  * DIM + c4];
        sxb[r][c4 + 0] = f2bf(vs.x); sxb[r][c4 + 1] = f2bf(vs.y);
        sxb[r][c4 + 2] = f2bf(vs.z); sxb[r][c4 + 3] = f2bf(vs.w);
        sxb[r][128 + c4 + 0] = f2bf(vo.x); sxb[r][128 + c4 + 1] = f2bf(vo.y);
        sxb[r][128 + c4 + 2] = f2bf(vo.z); sxb[r][128 + c4 + 3] = f2bf(vo.w);
    }
    for (int idx = tid; idx < 32 * TDIM; idx += 256) {
        int r = idx >> 6, c = idx & 63;
        float f = s_dt[r] * w_t[c] + b_t[c];
        sxb[r][256 + c] = f2bf((c & 1) ? cosf(f) : sinf(f));
    }
    __syncthreads();

    const int w    = tid >> 6;
    const int l    = tid & 63;
    const int rowA = l & 15;
    const int kg   = l >> 4;
    const int n0   = w * 32;
    const int col  = l & 15;
    const int rgrp = l >> 4;

    // ---- stage 1: h1 = relu(x @ W1^T + b1), K=320 ---------------------------
    {
        f32x4 a[2][2] = {{{0.f,0.f,0.f,0.f},{0.f,0.f,0.f,0.f}},
                         {{0.f,0.f,0.f,0.f},{0.f,0.f,0.f,0.f}}};
        #pragma unroll
        for (int kt = 0; kt < 10; ++kt) {
            int ko = kt * 32 + kg * 8;
            bf16x8 b0  = ldfrag(&W1b[(size_t)(n0 + rowA) * 320 + ko]);
            bf16x8 b1v = ldfrag(&W1b[(size_t)(n0 + 16 + rowA) * 320 + ko]);
            #pragma unroll
            for (int ta = 0; ta < 2; ++ta) {
                bf16x8 av = ldfrag(&sxb[ta * 16 + rowA][ko]);
                a[ta][0] = MFMA(av, b0,  a[ta][0]);
                a[ta][1] = MFMA(av, b1v, a[ta][1]);
            }
        }
        float bb0 = b1[n0 + col], bb1 = b1[n0 + 16 + col];
        #pragma unroll
        for (int ta = 0; ta < 2; ++ta)
            #pragma unroll
            for (int rgi = 0; rgi < 4; ++rgi) {
                int rr = ta * 16 + rgrp * 4 + rgi;
                hb[rr][n0 + col]      = f2bf(fmaxf(a[ta][0][rgi] + bb0, 0.f));
                hb[rr][n0 + 16 + col] = f2bf(fmaxf(a[ta][1][rgi] + bb1, 0.f));
            }
    }
    __syncthreads();

    // ---- stage 2: msg = h1 @ W2^T + b2, K=128 -------------------------------
    {
        f32x4 m[2][2] = {{{0.f,0.f,0.f,0.f},{0.f,0.f,0.f,0.f}},
                         {{0.f,0.f,0.f,0.f},{0.f,0.f,0.f,0.f}}};
        #pragma unroll
        for (int kt = 0; kt < 4; ++kt) {
            int ko = kt * 32 + kg * 8;
            bf16x8 b0  = ldfrag(&W2b[(size_t)(n0 + rowA) * 128 + ko]);
            bf16x8 b1v = ldfrag(&W2b[(size_t)(n0 + 16 + rowA) * 128 + ko]);
            #pragma unroll
            for (int ta = 0; ta < 2; ++ta) {
                bf16x8 av = ldfrag(&hb[ta * 16 + rowA][ko]);
                m[ta][0] = MFMA(av, b0,  m[ta][0]);
                m[ta][1] = MFMA(av, b1v, m[ta][1]);
            }
        }
        __syncthreads();   // all h1 reads done before overwrite
        float bb0 = b2[n0 + col], bb1 = b2[n0 + 16 + col];
        #pragma unroll
        for (int ta = 0; ta < 2; ++ta)
            #pragma unroll
            for (int rgi = 0; rgi < 4; ++rgi) {
                int rr = ta * 16 + rgrp * 4 + rgi;
                hb[rr][n0 + col]      = f2bf(m[ta][0][rgi] + bb0);
                hb[rr][n0 + 16 + col] = f2bf(m[ta][1][rgi] + bb1);
            }
    }
    __syncthreads();

    // ---- stage 3: GRU gates, two 16-col passes ------------------------------
    #pragma unroll
    for (int tp = 0; tp < 2; ++tp) {
        const int db = n0 + tp * 16;
        f32x4 g[6][2];
        #pragma unroll
        for (int gi_ = 0; gi_ < 6; ++gi_)
            #pragma unroll
            for (int ta = 0; ta < 2; ++ta) g[gi_][ta] = (f32x4){0.f,0.f,0.f,0.f};
        #pragma unroll
        for (int kt = 0; kt < 4; ++kt) {
            int ko = kt * 32 + kg * 8;
            int br = db + rowA;
            bf16x8 bir = ldfrag(&Wihb[(size_t)(      br) * 128 + ko]);
            bf16x8 biz = ldfrag(&Wihb[(size_t)(128 + br) * 128 + ko]);
            bf16x8 big = ldfrag(&Wihb[(size_t)(256 + br) * 128 + ko]);
            bf16x8 bhr = ldfrag(&Whhb[(size_t)(      br) * 128 + ko]);
            bf16x8 bhz = ldfrag(&Whhb[(size_t)(128 + br) * 128 + ko]);
            bf16x8 bhg = ldfrag(&Whhb[(size_t)(256 + br) * 128 + ko]);
            #pragma unroll
            for (int ta = 0; ta < 2; ++ta) {
                bf16x8 am = ldfrag(&hb [ta * 16 + rowA][ko]);
                bf16x8 ah = ldfrag(&sxb[ta * 16 + rowA][ko]);
                g[0][ta] = MFMA(am, bir, g[0][ta]);
                g[1][ta] = MFMA(am, biz, g[1][ta]);
                g[2][ta] = MFMA(am, big, g[2][ta]);
                g[3][ta] = MFMA(ah, bhr, g[3][ta]);
                g[4][ta] = MFMA(ah, bhz, g[4][ta]);
                g[5][ta] = MFMA(ah, bhg, g[5][ta]);
            }
        }
        const int d = db + col;
        float bir = bih[d], biz = bih[128 + d], big = bih[256 + d];
        float bhr = bhh[d], bhz = bhh[128 + d], bhg = bhh[256 + d];
        #pragma unroll
        for (int ta = 0; ta < 2; ++ta)
            #pragma unroll
            for (int rgi = 0; rgi < 4; ++rgi) {
                int rr = ta * 16 + rgrp * 4 + rgi;
                float rv = sigmoidf_((g[0][ta][rgi] + bir) + (g[3][ta][rgi] + bhr));
                float zv = sigmoidf_((g[1][ta][rgi] + biz) + (g[4][ta][rgi] + bhz));
                float gv = tanhf((g[2][ta][rgi] + big) + rv * (g[5][ta][rgi] + bhg));
                float selfv = bf2f(sxb[rr][d]);
                new_mem[(size_t)(base + rr) * DIM + d] = (1.f - zv) * gv + zv * selfv;
            }
    }
}

// ---------------------------------------------------------------------------
// K2: temporal top-16-of-32 per src row.
// ---------------------------------------------------------------------------
__global__ __launch_bounds__(256) void k2_topk(
    const int* __restrict__ src, const float* __restrict__ ts,
    const int* __restrict__ nbr_ids, const float* __restrict__ nbr_ts,
    int* __restrict__ sel_id, float* __restrict__ sel_td, int* __restrict__ sel_mk)
{
    int b = blockIdx.x * 256 + threadIdx.x;
    if (b >= BATCH) return;
    int   s = src[b];
    float t = ts[b];
    const int*   ip = nbr_ids + (size_t)s * KNB;
    const float* tp = nbr_ts  + (size_t)s * KNB;
    float kt[KNB]; int kid[KNB];
    #pragma unroll
    for (int j = 0; j < KNB; ++j) {
        int id = ip[j]; float nt = tp[j];
        bool valid = (id >= 0) && (nt < t + 1e-6f);
        kt[j]  = valid ? nt : -1e30f;
        kid[j] = id;
    }
    unsigned picked = 0u;
    for (int sI = 0; sI < KSEL; ++sI) {
        float bv = -3.4e38f; int bj = 0; int bid = 0;
        #pragma unroll
        for (int j = 0; j < KNB; ++j) {
            bool avail = !((picked >> j) & 1u);
            if (avail && kt[j] > bv) { bv = kt[j]; bj = j; bid = kid[j]; }
        }
        picked |= (1u << bj);
        bool mk = bv > -1e29f;
        int id = mk ? (bid < 0 ? 0 : (bid > NNODES - 1 ? NNODES - 1 : bid)) : 0;
        sel_id[b * KSEL + sI] = id;
        sel_td[b * KSEL + sI] = mk ? (t - bv) : 0.f;
        sel_mk[b * KSEL + sI] = mk ? 1 : 0;
    }
}

// ---------------------------------------------------------------------------
// K3a (MFMA): nf gather + Q proj + qb + u = Wk_h^T Q_h. 32 rows/block.
// ---------------------------------------------------------------------------
__global__ __launch_bounds__(256) void k3a_qu(
    const int* __restrict__ src,
    const float* __restrict__ memory, const float* __restrict__ new_mem,
    const int* __restrict__ winner,
    const unsigned short* __restrict__ Wp,
    const float* __restrict__ bq, const float* __restrict__ bk,
    float* __restrict__ nf_ws, float* __restrict__ u_ws, float* __restrict__ qb_ws)
{
    __shared__ unsigned short s_nfB[32][136];
    __shared__ float          s_q  [32][128];
    __shared__ unsigned short s_qB [32][136];
    __shared__ const float*   s_ptr[32];

    const unsigned short* Wqb  = Wp + OFF_WQ;
    const unsigned short* WkTb = Wp + OFF_WKT;

    const int tid  = threadIdx.x;
    const int base = blockIdx.x * 32;

    if (tid < 32) {
        int v = src[base + tid];
        int wv = winner[v];
        s_ptr[tid] = (wv >= 0) ? (new_mem + (size_t)wv * DIM)
                               : (memory  + (size_t)v  * DIM);
    }
    __syncthreads();

    for (int idx = tid; idx < 32 * 32; idx += 256) {
        int r = idx >> 5, c4 = (idx & 31) << 2;
        float4 v = *(const float4*)&s_ptr[r][c4];
        *(float4*)&nf_ws[(size_t)(base + r) * DIM + c4] = v;
        s_nfB[r][c4 + 0] = f2bf(v.x); s_nfB[r][c4 + 1] = f2bf(v.y);
        s_nfB[r][c4 + 2] = f2bf(v.z); s_nfB[r][c4 + 3] = f2bf(v.w);
    }
    __syncthreads();

    const int w    = tid >> 6;
    const int l    = tid & 63;
    const int rowA = l & 15;
    const int kg   = l >> 4;
    const int n0   = w * 32;
    const int col  = l & 15;
    const int rgrp = l >> 4;

    // Q = nf @ Wq^T + bq
    {
        f32x4 q[2][2] = {{{0.f,0.f,0.f,0.f},{0.f,0.f,0.f,0.f}},
                         {{0.f,0.f,0.f,0.f},{0.f,0.f,0.f,0.f}}};
        #pragma unroll
        for (int kt = 0; kt < 4; ++kt) {
            int ko = kt * 32 + kg * 8;
            bf16x8 b0  = ldfrag(&Wqb[(size_t)(n0 + rowA) * 128 + ko]);
            bf16x8 b1v = ldfrag(&Wqb[(size_t)(n0 + 16 + rowA) * 128 + ko]);
            #pragma unroll
            for (int ta = 0; ta < 2; ++ta) {
                bf16x8 av = ldfrag(&s_nfB[ta * 16 + rowA][ko]);
                q[ta][0] = MFMA(av, b0,  q[ta][0]);
                q[ta][1] = MFMA(av, b1v, q[ta][1]);
            }
        }
        float bb0 = bq[n0 + col], bb1 = bq[n0 + 16 + col];
        #pragma unroll
        for (int ta = 0; ta < 2; ++ta)
            #pragma unroll
            for (int rgi = 0; rgi < 4; ++rgi) {
                int rr = ta * 16 + rgrp * 4 + rgi;
                float v0 = q[ta][0][rgi] + bb0;
                float v1 = q[ta][1][rgi] + bb1;
                s_q [rr][n0 + col]      = v0;
                s_q [rr][n0 + 16 + col] = v1;
                s_qB[rr][n0 + col]      = f2bf(v0);
                s_qB[rr][n0 + 16 + col] = f2bf(v1);
            }
    }
    __syncthreads();

    // qb[r][h] = Q_h . bk_h   (8 threads per row: h = bit2, p = bits0..1)
    {
        int r = tid >> 3, rem = tid & 7, h = rem >> 2, p = rem & 3;
        float part = 0.f;
        #pragma unroll
        for (int j = 0; j < 16; ++j) {
            int dd = h * 64 + p * 16 + j;
            part += s_q[r][dd] * bk[dd];
        }
        part += __shfl_xor(part, 1);
        part += __shfl_xor(part, 2);
        if (p == 0) qb_ws[(base + r) * 2 + h] = part;
    }

    // u: per head h (=w>>1), wave covers 96 cols (6 tiles). K=64.
    {
        const int h  = w >> 1;
        const int cb = (w & 1) * 96;
        f32x4 u[6][2];
        #pragma unroll
        for (int ct = 0; ct < 6; ++ct)
            #pragma unroll
            for (int ta = 0; ta < 2; ++ta) u[ct][ta] = (f32x4){0.f,0.f,0.f,0.f};
        #pragma unroll
        for (int kt = 0; kt < 2; ++kt) {
            int ko = kt * 32 + kg * 8;
            bf16x8 bf[6];
            #pragma unroll
            for (int ct = 0; ct < 6; ++ct)
                bf[ct] = ldfrag(&WkTb[(size_t)h * 12288 + (size_t)(cb + ct * 16 + rowA) * 64 + ko]);
            #pragma unroll
            for (int ta = 0; ta < 2; ++ta) {
                bf16x8 av = ldfrag(&s_qB[ta * 16 + rowA][h * 64 + ko]);
                #pragma unroll
                for (int ct = 0; ct < 6; ++ct)
                    u[ct][ta] = MFMA(av, bf[ct], u[ct][ta]);
            }
        }
        #pragma unroll
        for (int ct = 0; ct < 6; ++ct)
            #pragma unroll
            for (int ta = 0; ta < 2; ++ta)
                #pragma unroll
                for (int rgi = 0; rgi < 4; ++rgi) {
                    int rr = ta * 16 + rgrp * 4 + rgi;
                    int c  = cb + ct * 16 + col;
                    u_ws[(size_t)(base + rr) * 384 + h * 192 + c] = u[ct][ta][rgi];
                }
    }
}

// ---------------------------------------------------------------------------
// K3b: neighbor gather + scores + softmax + kvbar. One wave per row. (f32)
// ---------------------------------------------------------------------------
__global__ __launch_bounds__(256) void k3b_score(
    const float* __restrict__ memory, const float* __restrict__ new_mem,
    const int* __restrict__ winner,
    const int* __restrict__ sel_id, const float* __restrict__ sel_td,
    const int* __restrict__ sel_mk,
    const float* __restrict__ w_ta, const float* __restrict__ b_ta,
    const float* __restrict__ u_ws, const float* __restrict__ qb_ws,
    float* __restrict__ kvb_ws, float* __restrict__ satt_ws)
{
    const int lane = threadIdx.x & 63;
    const int w    = threadIdx.x >> 6;
    const int b    = blockIdx.x * 4 + w;

    __shared__ float s_kv  [4][16][196];
    __shared__ float s_u   [4][384];
    __shared__ float s_attn[4][2][16];
    __shared__ float s_td  [4][16];
    __shared__ int   s_mk  [4][16];
    __shared__ const float* s_ptr[4][16];

    if (lane < 16) {
        int id = sel_id[b * KSEL + lane];
        int wi = winner[id];
        s_ptr[w][lane] = (wi >= 0) ? (new_mem + (size_t)wi * DIM)
                                   : (memory  + (size_t)id * DIM);
        s_td[w][lane] = sel_td[b * KSEL + lane];
        s_mk[w][lane] = sel_mk[b * KSEL + lane];
    }
    #pragma unroll
    for (int i = 0; i < 6; ++i)
        s_u[w][i * 64 + lane] = u_ws[(size_t)b * 384 + i * 64 + lane];
    __syncthreads();

    {
        #pragma unroll
        for (int it = 0; it < 8; ++it) {
            int n  = it * 2 + (lane >> 5);
            int c4 = (lane & 31) << 2;
            *(float4*)&s_kv[w][n][c4] = *(const float4*)&s_ptr[w][n][c4];
        }
        float wt = w_ta[lane], bt = b_ta[lane];
        #pragma unroll
        for (int n = 0; n < 16; ++n) {
            float f = s_td[w][n] * wt + bt;
            s_kv[w][n][128 + lane] = (lane & 1) ? cosf(f) : sinf(f);
        }
    }
    __syncthreads();

    {
        int h = (lane >> 4) & 1, n = lane & 15, half = lane >> 5;
        float acc = (half == 0) ? qb_ws[b * 2 + h] : 0.f;
        const float* kvrow = &s_kv[w][n][half * 96];
        const float* urow  = &s_u[w][h * 192 + half * 96];
        #pragma unroll
        for (int k = 0; k < 96; k += 4)
            acc += dot4(*(const float4*)&kvrow[k], *(const float4*)&urow[k]);
        acc += __shfl_xor(acc, 32);
        int mk = s_mk[w][n];
        float s = mk ? acc * 0.125f : -INFINITY;
        float mx = s;
        #pragma unroll
        for (int m = 1; m < 16; m <<= 1) mx = fmaxf(mx, __shfl_xor(mx, m));
        float p = (mk && mx > -1e37f) ? expf(s - mx) : 0.f;
        float den = p;
        #pragma unroll
        for (int m = 1; m < 16; m <<= 1) den += __shfl_xor(den, m);
        float a = (den > 0.f) ? (p / den) : 0.f;
        if (lane < 32) s_attn[w][h][n] = a;
        if (lane == 0 || lane == 16) satt_ws[b * 2 + h] = (den > 0.f) ? 1.f : 0.f;
    }
    __syncthreads();

    #pragma unroll
    for (int i = 0; i < 3; ++i) {
        int c = i * 64 + lane;
        float k0 = 0.f, k1 = 0.f;
        #pragma unroll
        for (int n = 0; n < 16; ++n) {
            float v = s_kv[w][n][c];
            k0 += s_attn[w][0][n] * v;
            k1 += s_attn[w][1][n] * v;
        }
        kvb_ws[(size_t)b * 384 + c]       = k0;
        kvb_ws[(size_t)b * 384 + 192 + c] = k1;
    }
}

// ---------------------------------------------------------------------------
// K3c (MFMA): Wv -> Wo -> Wm1 -> Wm2 -> LayerNorm. 32 rows/block.
// ---------------------------------------------------------------------------
__global__ __launch_bounds__(256) void k3c_mlp(
    const float* __restrict__ kvb_ws, const float* __restrict__ satt_ws,
    const float* __restrict__ nf_ws,
    const unsigned short* __restrict__ Wp,
    const float* __restrict__ bv, const float* __restrict__ bo,
    const float* __restrict__ bm1, const float* __restrict__ bm2,
    const float* __restrict__ ln_g, const float* __restrict__ ln_b,
    float* __restrict__ out)
{
    __shared__ unsigned short skvbB[32][2][200];
    __shared__ unsigned short s_cat[32][264];   // [ao 0:128 | nf 128:256]
    __shared__ unsigned short s_oB [32][136];
    __shared__ unsigned short s_h1B[32][136];
    __shared__ float          s_h2 [32][128];
    __shared__ float          s_satt[32][2];

    const unsigned short* Wvb  = Wp + OFF_WV;
    const unsigned short* Wob  = Wp + OFF_WO;
    const unsigned short* Wm1b = Wp + OFF_WM1;
    const unsigned short* Wm2b = Wp + OFF_WM2;

    const int tid  = threadIdx.x;
    const int base = blockIdx.x * 32;

    for (int idx = tid; idx < 32 * 96; idx += 256) {
        int r = idx / 96, j = (idx % 96) << 2;        // j in [0,384), mult of 4
        float4 v = *(const float4*)&kvb_ws[(size_t)(base + r) * 384 + j];
        int h = j / 192, jj = j % 192;
        skvbB[r][h][jj + 0] = f2bf(v.x); skvbB[r][h][jj + 1] = f2bf(v.y);
        skvbB[r][h][jj + 2] = f2bf(v.z); skvbB[r][h][jj + 3] = f2bf(v.w);
    }
    for (int idx = tid; idx < 32 * 32; idx += 256) {
        int r = idx >> 5, j = (idx & 31) << 2;
        float4 v = *(const float4*)&nf_ws[(size_t)(base + r) * DIM + j];
        s_cat[r][128 + j + 0] = f2bf(v.x); s_cat[r][128 + j + 1] = f2bf(v.y);
        s_cat[r][128 + j + 2] = f2bf(v.z); s_cat[r][128 + j + 3] = f2bf(v.w);
    }
    if (tid < 64) s_satt[tid >> 1][tid & 1] = satt_ws[(base + (tid >> 1)) * 2 + (tid & 1)];
    __syncthreads();

    const int w    = tid >> 6;
    const int l    = tid & 63;
    const int rowA = l & 15;
    const int kg   = l >> 4;
    const int col  = l & 15;
    const int rgrp = l >> 4;

    // ---- out = Wv_h @ kvbar_h + satt_h*bv : wave w -> head w>>1, cols (w&1)*32
    {
        const int h  = w >> 1;
        const int c0 = (w & 1) * 32;
        f32x4 o_[2][2] = {{{0.f,0.f,0.f,0.f},{0.f,0.f,0.f,0.f}},
                          {{0.f,0.f,0.f,0.f},{0.f,0.f,0.f,0.f}}};
        #pragma unroll
        for (int kt = 0; kt < 6; ++kt) {
            int ko = kt * 32 + kg * 8;
            bf16x8 b0  = ldfrag(&Wvb[(size_t)(h * 64 + c0 + rowA) * 192 + ko]);
            bf16x8 b1v = ldfrag(&Wvb[(size_t)(h * 64 + c0 + 16 + rowA) * 192 + ko]);
            #pragma unroll
            for (int ta = 0; ta < 2; ++ta) {
                bf16x8 av = ldfrag(&skvbB[ta * 16 + rowA][h][ko]);
                o_[ta][0] = MFMA(av, b0,  o_[ta][0]);
                o_[ta][1] = MFMA(av, b1v, o_[ta][1]);
            }
        }
        int d0 = h * 64 + c0 + col, d1 = d0 + 16;
        float bv0 = bv[d0], bv1 = bv[d1];
        #pragma unroll
        for (int ta = 0; ta < 2; ++ta)
            #pragma unroll
            for (int rgi = 0; rgi < 4; ++rgi) {
                int rr = ta * 16 + rgrp * 4 + rgi;
                s_oB[rr][d0] = f2bf(o_[ta][0][rgi] + s_satt[rr][h] * bv0);
                s_oB[rr][d1] = f2bf(o_[ta][1][rgi] + s_satt[rr][h] * bv1);
            }
    }
    __syncthreads();

    // ---- ao = Wo @ out + bo  -> s_cat[0:128]
    {
        const int n0 = w * 32;
        f32x4 a[2][2] = {{{0.f,0.f,0.f,0.f},{0.f,0.f,0.f,0.f}},
                         {{0.f,0.f,0.f,0.f},{0.f,0.f,0.f,0.f}}};
        #pragma unroll
        for (int kt = 0; kt < 4; ++kt) {
            int ko = kt * 32 + kg * 8;
            bf16x8 b0  = ldfrag(&Wob[(size_t)(n0 + rowA) * 128 + ko]);
            bf16x8 b1v = ldfrag(&Wob[(size_t)(n0 + 16 + rowA) * 128 + ko]);
            #pragma unroll
            for (int ta = 0; ta < 2; ++ta) {
                bf16x8 av = ldfrag(&s_oB[ta * 16 + rowA][ko]);
                a[ta][0] = MFMA(av, b0,  a[ta][0]);
                a[ta][1] = MFMA(av, b1v, a[ta][1]);
            }
        }
        float bb0 = bo[n0 + col], bb1 = bo[n0 + 16 + col];
        #pragma unroll
        for (int ta = 0; ta < 2; ++ta)
            #pragma unroll
            for (int rgi = 0; rgi < 4; ++rgi) {
                int rr = ta * 16 + rgrp * 4 + rgi;
                s_cat[rr][n0 + col]      = f2bf(a[ta][0][rgi] + bb0);
                s_cat[rr][n0 + 16 + col] = f2bf(a[ta][1][rgi] + bb1);
            }
    }
    __syncthreads();

    // ---- h1 = relu(Wm1 @ [ao|nf] + bm1), K=256
    {
        const int n0 = w * 32;
        f32x4 a[2][2] = {{{0.f,0.f,0.f,0.f},{0.f,0.f,0.f,0.f}},
                         {{0.f,0.f,0.f,0.f},{0.f,0.f,0.f,0.f}}};
        #pragma unroll
        for (int kt = 0; kt < 8; ++kt) {
            int ko = kt * 32 + kg * 8;
            bf16x8 b0  = ldfrag(&Wm1b[(size_t)(n0 + rowA) * 256 + ko]);
            bf16x8 b1v = ldfrag(&Wm1b[(size_t)(n0 + 16 + rowA) * 256 + ko]);
            #pragma unroll
            for (int ta = 0; ta < 2; ++ta) {
                bf16x8 av = ldfrag(&s_cat[ta * 16 + rowA][ko]);
                a[ta][0] = MFMA(av, b0,  a[ta][0]);
                a[ta][1] = MFMA(av, b1v, a[ta][1]);
            }
        }
        float bb0 = bm1[n0 + col], bb1 = bm1[n0 + 16 + col];
        #pragma unroll
        for (int ta = 0; ta < 2; ++ta)
            #pragma unroll
            for (int rgi = 0; rgi < 4; ++rgi) {
                int rr = ta * 16 + rgrp * 4 + rgi;
                s_h1B[rr][n0 + col]      = f2bf(fmaxf(a[ta][0][rgi] + bb0, 0.f));
                s_h1B[rr][n0 + 16 + col] = f2bf(fmaxf(a[ta][1][rgi] + bb1, 0.f));
            }
    }
    __syncthreads();

    // ---- h2 = Wm2 @ h1 + bm2 -> f32
    {
        const int n0 = w * 32;
        f32x4 a[2][2] = {{{0.f,0.f,0.f,0.f},{0.f,0.f,0.f,0.f}},
                         {{0.f,0.f,0.f,0.f},{0.f,0.f,0.f,0.f}}};
        #pragma unroll
        for (int kt = 0; kt < 4; ++kt) {
            int ko = kt * 32 + kg * 8;
            bf16x8 b0  = ldfrag(&Wm2b[(size_t)(n0 + rowA) * 128 + ko]);
            bf16x8 b1v = ldfrag(&Wm2b[(size_t)(n0 + 16 + rowA) * 128 + ko]);
            #pragma unroll
            for (int ta = 0; ta < 2; ++ta) {
                bf16x8 av = ldfrag(&s_h1B[ta * 16 + rowA][ko]);
                a[ta][0] = MFMA(av, b0,  a[ta][0]);
                a[ta][1] = MFMA(av, b1v, a[ta][1]);
            }
        }
        float bb0 = bm2[n0 + col], bb1 = bm2[n0 + 16 + col];
        #pragma unroll
        for (int ta = 0; ta < 2; ++ta)
            #pragma unroll
            for (int rgi = 0; rgi < 4; ++rgi) {
                int rr = ta * 16 + rgrp * 4 + rgi;
                s_h2[rr][n0 + col]      = a[ta][0][rgi] + bb0;
                s_h2[rr][n0 + 16 + col] = a[ta][1][rgi] + bb1;
            }
    }
    __syncthreads();

    // ---- LayerNorm: wave w -> rows w*8 .. w*8+7
    {
        float lg0 = ln_g[l], lg1 = ln_g[64 + l];
        float lb0 = ln_b[l], lb1 = ln_b[64 + l];
        #pragma unroll
        for (int i = 0; i < 8; ++i) {
            int r = w * 8 + i;
            float v0 = s_h2[r][l], v1 = s_h2[r][64 + l];
            float sum = v0 + v1;
            #pragma unroll
            for (int m = 1; m < 64; m <<= 1) sum += __shfl_xor(sum, m);
            float mean = sum * (1.f / 128.f);
            float e0 = v0 - mean, e1 = v1 - mean;
            float sq = e0 * e0 + e1 * e1;
            #pragma unroll
            for (int m = 1; m < 64; m <<= 1) sq += __shfl_xor(sq, m);
            float inv = rsqrtf(sq * (1.f / 128.f) + 1e-5f);
            out[(size_t)(base + r) * DIM + l]      = e0 * inv * lg0 + lb0;
            out[(size_t)(base + r) * DIM + 64 + l] = e1 * inv * lg1 + lb1;
        }
    }
}

// ---------------------------------------------------------------------------
extern "C" void kernel_launch(void* const* d_in, const int* in_sizes, int n_in,
                              void* d_out, int out_size, void* d_ws, size_t ws_size,
                              hipStream_t stream) {
    const int*   src         = (const int*)  d_in[0];
    const int*   dst         = (const int*)  d_in[1];
    const float* ts          = (const float*)d_in[2];
    const int*   nbr_ids     = (const int*)  d_in[3];
    const float* nbr_ts      = (const float*)d_in[4];
    const float* memory      = (const float*)d_in[5];
    const float* last_update = (const float*)d_in[6];
    const float* w_t_msg     = (const float*)d_in[7];
    const float* b_t_msg     = (const float*)d_in[8];
    const float* W_msg1      = (const float*)d_in[9];
    const float* b_msg1      = (const float*)d_in[10];
    const float* W_msg2      = (const float*)d_in[11];
    const float* b_msg2      = (const float*)d_in[12];
    const float* W_ih        = (const float*)d_in[13];
    const float* b_ih        = (const float*)d_in[14];
    const float* W_hh        = (const float*)d_in[15];
    const float* b_hh        = (const float*)d_in[16];
    const float* w_t_att     = (const float*)d_in[17];
    const float* b_t_att     = (const float*)d_in[18];
    const float* Wq          = (const float*)d_in[19];
    const float* bq          = (const float*)d_in[20];
    const float* Wk          = (const float*)d_in[21];
    const float* bk          = (const float*)d_in[22];
    const float* Wv          = (const float*)d_in[23];
    const float* bv          = (const float*)d_in[24];
    const float* Wo          = (const float*)d_in[25];
    const float* bo          = (const float*)d_in[26];
    const float* Wm1         = (const float*)d_in[27];
    const float* bm1         = (const float*)d_in[28];
    const float* Wm2         = (const float*)d_in[29];
    const float* bm2         = (const float*)d_in[30];
    const float* ln_g        = (const float*)d_in[31];
    const float* ln_b        = (const float*)d_in[32];
    float* out = (float*)d_out;

    char* ws = (char*)d_ws;
    size_t off = 0;
    float* new_mem = (float*)(ws + off); off += (size_t)2 * BATCH * DIM * 4;
    int*   winner  = (int*)  (ws + off); off += 2097152;
    int*   sel_id  = (int*)  (ws + off); off += (size_t)BATCH * KSEL * 4;
    float* sel_td  = (float*)(ws + off); off += (size_t)BATCH * KSEL * 4;
    int*   sel_mk  = (int*)  (ws + off); off += (size_t)BATCH * KSEL * 4;
    float* nf_ws   = (float*)(ws + off); off += (size_t)BATCH * DIM * 4;
    float* u_ws    = (float*)(ws + off); off += (size_t)BATCH * 384 * 4;
    float* qb_ws   = (float*)(ws + off); off += 65536;
    float* kvb_ws  = (float*)(ws + off); off += (size_t)BATCH * 384 * 4;
    float* satt_ws = (float*)(ws + off); off += 65536;
    unsigned short* Wpool = (unsigned short*)(ws + off); off += (size_t)CVT_TOT * 2;

    hipMemsetAsync(winner, 0xFF, NNODES * sizeof(int), stream);
    k0_cvt<<<(CVT_TOT + 255) / 256, 256, 0, stream>>>(
        W_msg1, W_msg2, W_ih, W_hh, Wq, Wv, Wo, Wm1, Wm2, Wk, Wpool);
    k_winner<<<(2 * BATCH + 255) / 256, 256, 0, stream>>>(src, dst, winner);
    k1_mfma<<<(2 * BATCH) / 32, 256, 0, stream>>>(
        src, dst, ts, memory, last_update,
        w_t_msg, b_t_msg, Wpool, b_msg1, b_msg2, b_ih, b_hh, new_mem);
    k2_topk<<<(BATCH + 255) / 256, 256, 0, stream>>>(
        src, ts, nbr_ids, nbr_ts, sel_id, sel_td, sel_mk);
    k3a_qu<<<BATCH / 32, 256, 0, stream>>>(
        src, memory, new_mem, winner, Wpool, bq, bk, nf_ws, u_ws, qb_ws);
    k3b_score<<<BATCH / 4, 256, 0, stream>>>(
        memory, new_mem, winner, sel_id, sel_td, sel_mk,
        w_t_att, b_t_att, u_ws, qb_ws, kvb_ws, satt_ws);
    k3c_mlp<<<BATCH / 32, 256, 0, stream>>>(
        kvb_ws, satt_ws, nf_ws, Wpool, bv, bo, bm1, bm2, ln_g, ln_b, out);
}

// Round 5
// 106.640 us; speedup vs baseline: 7.2539x; 1.1665x over previous
//
#include <hip/hip_runtime.h>
#include <math.h>

#define BATCH  8192
#define NNODES 500000
#define DIM    128
#define TDIM   64
#define KNB    32
#define KSEL   16

// bf16 weight pool element offsets
#define OFF_W1   0
#define OFF_W2   40960
#define OFF_WIH  57344
#define OFF_WHH  106496
#define OFF_WQ   155648
#define OFF_WV   172032
#define OFF_WO   196608
#define OFF_WM1  212992
#define OFF_WM2  245760
#define OFF_WKT  262144
#define CVT_TOT  286720

// prep kernel block ranges
#define NB_CVT  1120                  // CVT_TOT / 256 exactly
#define NB_WIN  (NB_CVT + 64)         // 16384 threads for winner scatter
#define NB_TOPK (NB_WIN + 32)         // 8192 threads for top-k

typedef float  f32x4  __attribute__((ext_vector_type(4)));
typedef __bf16 bf16x8 __attribute__((ext_vector_type(8)));
typedef short  s16x8  __attribute__((ext_vector_type(8)));

#define MFMA(a,b,c) __builtin_amdgcn_mfma_f32_16x16x32_bf16(a,b,c,0,0,0)

__device__ __forceinline__ float sigmoidf_(float x) { return 1.f / (1.f + expf(-x)); }
__device__ __forceinline__ unsigned short f2bf(float x) {
    unsigned u = __builtin_bit_cast(unsigned, x);
    unsigned r = (u + 0x7FFFu + ((u >> 16) & 1u)) >> 16;
    return (unsigned short)r;
}
__device__ __forceinline__ float bf2f(unsigned short u) {
    unsigned v = ((unsigned)u) << 16;
    return __builtin_bit_cast(float, v);
}
__device__ __forceinline__ bf16x8 ldfrag(const unsigned short* p) {
    s16x8 v = *(const s16x8*)p;
    return __builtin_bit_cast(bf16x8, v);
}

// ---------------------------------------------------------------------------
// K_prep: [0,NB_CVT) weight->bf16 pool | [NB_CVT,NB_WIN) winner scatter |
//         [NB_WIN,NB_TOPK) temporal top-16-of-32.
// ---------------------------------------------------------------------------
__global__ __launch_bounds__(256) void k_prep(
    const float* __restrict__ sW1, const float* __restrict__ sW2,
    const float* __restrict__ sWih, const float* __restrict__ sWhh,
    const float* __restrict__ sWq, const float* __restrict__ sWv,
    const float* __restrict__ sWo, const float* __restrict__ sWm1,
    const float* __restrict__ sWm2, const float* __restrict__ sWk,
    unsigned short* __restrict__ pool,
    const int* __restrict__ src, const int* __restrict__ dst,
    int* __restrict__ winner,
    const float* __restrict__ ts,
    const int* __restrict__ nbr_ids, const float* __restrict__ nbr_ts,
    int* __restrict__ sel_id, float* __restrict__ sel_td, int* __restrict__ sel_mk)
{
    const int bid = blockIdx.x;
    const int tid = threadIdx.x;

    if (bid < NB_CVT) {
        int i = bid * 256 + tid;
        float v;
        if      (i < OFF_W2)  { v = sW1 [i - OFF_W1 ]; }
        else if (i < OFF_WIH) { v = sW2 [i - OFF_W2 ]; }
        else if (i < OFF_WHH) { v = sWih[i - OFF_WIH]; }
        else if (i < OFF_WQ)  { v = sWhh[i - OFF_WHH]; }
        else if (i < OFF_WV)  { v = sWq [i - OFF_WQ ]; }
        else if (i < OFF_WO)  { v = sWv [i - OFF_WV ]; }
        else if (i < OFF_WM1) { v = sWo [i - OFF_WO ]; }
        else if (i < OFF_WM2) { v = sWm1[i - OFF_WM1]; }
        else if (i < OFF_WKT) { v = sWm2[i - OFF_WM2]; }
        else {
            int j = i - OFF_WKT;           // h*12288 + c*64 + dh
            int h = j / 12288, rem = j % 12288;
            int c = rem >> 6, dh = rem & 63;
            v = sWk[(size_t)(h * 64 + dh) * 192 + c];
        }
        pool[i] = f2bf(v);
        return;
    }
    if (bid < NB_WIN) {
        int i = (bid - NB_CVT) * 256 + tid;
        if (i < 2 * BATCH) {
            int v = (i < BATCH) ? src[i] : dst[i - BATCH];
            atomicMax(&winner[v], i);
        }
        return;
    }
    {
        int b = (bid - NB_WIN) * 256 + tid;
        if (b >= BATCH) return;
        int   s = src[b];
        float t = ts[b];
        const int*   ip = nbr_ids + (size_t)s * KNB;
        const float* tp = nbr_ts  + (size_t)s * KNB;
        float kt[KNB]; int kid[KNB];
        #pragma unroll
        for (int j = 0; j < KNB; ++j) {
            int id = ip[j]; float nt = tp[j];
            bool valid = (id >= 0) && (nt < t + 1e-6f);
            kt[j]  = valid ? nt : -1e30f;
            kid[j] = id;
        }
        unsigned picked = 0u;
        for (int sI = 0; sI < KSEL; ++sI) {
            float bv = -3.4e38f; int bj = 0; int bid2 = 0;
            #pragma unroll
            for (int j = 0; j < KNB; ++j) {
                bool avail = !((picked >> j) & 1u);
                if (avail && kt[j] > bv) { bv = kt[j]; bj = j; bid2 = kid[j]; }
            }
            picked |= (1u << bj);
            bool mk = bv > -1e29f;
            int id = mk ? (bid2 < 0 ? 0 : (bid2 > NNODES - 1 ? NNODES - 1 : bid2)) : 0;
            sel_id[b * KSEL + sI] = id;
            sel_td[b * KSEL + sI] = mk ? (t - bv) : 0.f;
            sel_mk[b * KSEL + sI] = mk ? 1 : 0;
        }
    }
}

// ---------------------------------------------------------------------------
// K1 (MFMA): message MLP + GRU. 32 rows/block, 8 waves (512 thr).
// Wave w owns output cols [w*16, w*16+16) of every GEMM stage.
// ---------------------------------------------------------------------------
__global__ __launch_bounds__(512) void k1_mfma(
    const int* __restrict__ src, const int* __restrict__ dst, const float* __restrict__ ts,
    const float* __restrict__ memory, const float* __restrict__ last_update,
    const float* __restrict__ w_t, const float* __restrict__ b_t,
    const unsigned short* __restrict__ Wp,
    const float* __restrict__ b1, const float* __restrict__ b2,
    const float* __restrict__ bih, const float* __restrict__ bhh,
    float* __restrict__ new_mem)
{
    __shared__ unsigned short sxb[32][328];   // [self|oth|te] bf16, pad 8
    __shared__ unsigned short hb [32][136];   // h1 then msg
    __shared__ int   s_node[32];
    __shared__ int   s_oth [32];
    __shared__ float s_dt  [32];

    const unsigned short* W1b  = Wp + OFF_W1;
    const unsigned short* W2b  = Wp + OFF_W2;
    const unsigned short* Wihb = Wp + OFF_WIH;
    const unsigned short* Whhb = Wp + OFF_WHH;

    const int tid  = threadIdx.x;
    const int base = blockIdx.x * 32;

    if (tid < 32) {
        int gi = base + tid;
        int node, oth; float t;
        if (gi < BATCH) { node = src[gi];         oth = dst[gi];         t = ts[gi]; }
        else            { node = dst[gi - BATCH]; oth = src[gi - BATCH]; t = ts[gi - BATCH]; }
        s_node[tid] = node;
        s_oth[tid]  = oth;
        s_dt[tid]   = t - last_update[node];
    }
    __syncthreads();

    for (int idx = tid; idx < 32 * 32; idx += 512) {
        int r = idx >> 5, c4 = (idx & 31) << 2;
        float4 vs = *(const float4*)&memory[(size_t)s_node[r] * DIM + c4];
        float4 vo = *(const float4*)&memory[(size_t)s_oth[r]  * DIM + c4];
        sxb[r][c4 + 0] = f2bf(vs.x); sxb[r][c4 + 1] = f2bf(vs.y);
        sxb[r][c4 + 2] = f2bf(vs.z); sxb[r][c4 + 3] = f2bf(vs.w);
        sxb[r][128 + c4 + 0] = f2bf(vo.x); sxb[r][128 + c4 + 1] = f2bf(vo.y);
        sxb[r][128 + c4 + 2] = f2bf(vo.z); sxb[r][128 + c4 + 3] = f2bf(vo.w);
    }
    for (int idx = tid; idx < 32 * TDIM; idx += 512) {
        int r = idx >> 6, c = idx & 63;
        float f = s_dt[r] * w_t[c] + b_t[c];
        sxb[r][256 + c] = f2bf((c & 1) ? cosf(f) : sinf(f));
    }
    __syncthreads();

    const int w    = tid >> 6;        // 0..7
    const int l    = tid & 63;
    const int rowA = l & 15;
    const int kg   = l >> 4;
    const int n0   = w * 16;
    const int col  = l & 15;
    const int rgrp = l >> 4;

    // ---- stage 1: h1 = relu(x @ W1^T + b1), K=320 ---------------------------
    {
        f32x4 a0 = {0.f,0.f,0.f,0.f}, a1 = {0.f,0.f,0.f,0.f};
        #pragma unroll
        for (int kt = 0; kt < 10; ++kt) {
            int ko = kt * 32 + kg * 8;
            bf16x8 bfr = ldfrag(&W1b[(size_t)(n0 + rowA) * 320 + ko]);
            a0 = MFMA(ldfrag(&sxb[rowA][ko]),      bfr, a0);
            a1 = MFMA(ldfrag(&sxb[16 + rowA][ko]), bfr, a1);
        }
        float bb = b1[n0 + col];
        #pragma unroll
        for (int rgi = 0; rgi < 4; ++rgi) {
            hb[rgrp * 4 + rgi][n0 + col]      = f2bf(fmaxf(a0[rgi] + bb, 0.f));
            hb[16 + rgrp * 4 + rgi][n0 + col] = f2bf(fmaxf(a1[rgi] + bb, 0.f));
        }
    }
    __syncthreads();

    // ---- stage 2: msg = h1 @ W2^T + b2, K=128 -------------------------------
    {
        f32x4 m0 = {0.f,0.f,0.f,0.f}, m1 = {0.f,0.f,0.f,0.f};
        #pragma unroll
        for (int kt = 0; kt < 4; ++kt) {
            int ko = kt * 32 + kg * 8;
            bf16x8 bfr = ldfrag(&W2b[(size_t)(n0 + rowA) * 128 + ko]);
            m0 = MFMA(ldfrag(&hb[rowA][ko]),      bfr, m0);
            m1 = MFMA(ldfrag(&hb[16 + rowA][ko]), bfr, m1);
        }
        __syncthreads();   // all h1 reads done before overwrite
        float bb = b2[n0 + col];
        #pragma unroll
        for (int rgi = 0; rgi < 4; ++rgi) {
            hb[rgrp * 4 + rgi][n0 + col]      = f2bf(m0[rgi] + bb);
            hb[16 + rgrp * 4 + rgi][n0 + col] = f2bf(m1[rgi] + bb);
        }
    }
    __syncthreads();

    // ---- stage 3: GRU gates, one 16-col pass per wave -----------------------
    {
        f32x4 g[6][2];
        #pragma unroll
        for (int gi_ = 0; gi_ < 6; ++gi_)
            #pragma unroll
            for (int ta = 0; ta < 2; ++ta) g[gi_][ta] = (f32x4){0.f,0.f,0.f,0.f};
        #pragma unroll
        for (int kt = 0; kt < 4; ++kt) {
            int ko = kt * 32 + kg * 8;
            int br = n0 + rowA;
            bf16x8 bir = ldfrag(&Wihb[(size_t)(      br) * 128 + ko]);
            bf16x8 biz = ldfrag(&Wihb[(size_t)(128 + br) * 128 + ko]);
            bf16x8 big = ldfrag(&Wihb[(size_t)(256 + br) * 128 + ko]);
            bf16x8 bhr = ldfrag(&Whhb[(size_t)(      br) * 128 + ko]);
            bf16x8 bhz = ldfrag(&Whhb[(size_t)(128 + br) * 128 + ko]);
            bf16x8 bhg = ldfrag(&Whhb[(size_t)(256 + br) * 128 + ko]);
            #pragma unroll
            for (int ta = 0; ta < 2; ++ta) {
                bf16x8 am = ldfrag(&hb [ta * 16 + rowA][ko]);
                bf16x8 ah = ldfrag(&sxb[ta * 16 + rowA][ko]);
                g[0][ta] = MFMA(am, bir, g[0][ta]);
                g[1][ta] = MFMA(am, biz, g[1][ta]);
                g[2][ta] = MFMA(am, big, g[2][ta]);
                g[3][ta] = MFMA(ah, bhr, g[3][ta]);
                g[4][ta] = MFMA(ah, bhz, g[4][ta]);
                g[5][ta] = MFMA(ah, bhg, g[5][ta]);
            }
        }
        const int d = n0 + col;
        float bir = bih[d], biz = bih[128 + d], big = bih[256 + d];
        float bhr = bhh[d], bhz = bhh[128 + d], bhg = bhh[256 + d];
        #pragma unroll
        for (int ta = 0; ta < 2; ++ta)
            #pragma unroll
            for (int rgi = 0; rgi < 4; ++rgi) {
                int rr = ta * 16 + rgrp * 4 + rgi;
                float rv = sigmoidf_((g[0][ta][rgi] + bir) + (g[3][ta][rgi] + bhr));
                float zv = sigmoidf_((g[1][ta][rgi] + biz) + (g[4][ta][rgi] + bhz));
                float gv = tanhf((g[2][ta][rgi] + big) + rv * (g[5][ta][rgi] + bhg));
                float selfv = bf2f(sxb[rr][d]);
                new_mem[(size_t)(base + rr) * DIM + d] = (1.f - zv) * gv + zv * selfv;
            }
    }
}

// ---------------------------------------------------------------------------
// K3a (MFMA): nf gather + Q proj + qb + u = Wk_h^T Q_h. 16 rows/block.
// ---------------------------------------------------------------------------
__global__ __launch_bounds__(256) void k3a_qu(
    const int* __restrict__ src,
    const float* __restrict__ memory, const float* __restrict__ new_mem,
    const int* __restrict__ winner,
    const unsigned short* __restrict__ Wp,
    const float* __restrict__ bq, const float* __restrict__ bk,
    unsigned short* __restrict__ nfB_ws, float* __restrict__ u_ws,
    float* __restrict__ qb_ws)
{
    __shared__ unsigned short s_nfB[16][136];
    __shared__ float          s_q  [16][128];
    __shared__ unsigned short s_qB [16][136];
    __shared__ const float*   s_ptr[16];

    const unsigned short* Wqb  = Wp + OFF_WQ;
    const unsigned short* WkTb = Wp + OFF_WKT;

    const int tid  = threadIdx.x;
    const int base = blockIdx.x * 16;

    if (tid < 16) {
        int v = src[base + tid];
        int wv = winner[v];
        s_ptr[tid] = (wv >= 0) ? (new_mem + (size_t)wv * DIM)
                               : (memory  + (size_t)v  * DIM);
    }
    __syncthreads();

    for (int idx = tid; idx < 16 * 32; idx += 256) {
        int r = idx >> 5, c4 = (idx & 31) << 2;
        float4 v = *(const float4*)&s_ptr[r][c4];
        unsigned short u0 = f2bf(v.x), u1 = f2bf(v.y), u2 = f2bf(v.z), u3 = f2bf(v.w);
        s_nfB[r][c4 + 0] = u0; s_nfB[r][c4 + 1] = u1;
        s_nfB[r][c4 + 2] = u2; s_nfB[r][c4 + 3] = u3;
        uint2 pk;
        pk.x = (unsigned)u0 | ((unsigned)u1 << 16);
        pk.y = (unsigned)u2 | ((unsigned)u3 << 16);
        *(uint2*)&nfB_ws[(size_t)(base + r) * DIM + c4] = pk;
    }
    __syncthreads();

    const int w    = tid >> 6;
    const int l    = tid & 63;
    const int rowA = l & 15;
    const int kg   = l >> 4;
    const int n0   = w * 32;
    const int col  = l & 15;
    const int rgrp = l >> 4;

    // Q = nf @ Wq^T + bq
    {
        f32x4 q0 = {0.f,0.f,0.f,0.f}, q1 = {0.f,0.f,0.f,0.f};
        #pragma unroll
        for (int kt = 0; kt < 4; ++kt) {
            int ko = kt * 32 + kg * 8;
            bf16x8 av = ldfrag(&s_nfB[rowA][ko]);
            q0 = MFMA(av, ldfrag(&Wqb[(size_t)(n0 + rowA) * 128 + ko]),      q0);
            q1 = MFMA(av, ldfrag(&Wqb[(size_t)(n0 + 16 + rowA) * 128 + ko]), q1);
        }
        float bb0 = bq[n0 + col], bb1 = bq[n0 + 16 + col];
        #pragma unroll
        for (int rgi = 0; rgi < 4; ++rgi) {
            int rr = rgrp * 4 + rgi;
            float v0 = q0[rgi] + bb0;
            float v1 = q1[rgi] + bb1;
            s_q [rr][n0 + col]      = v0;
            s_q [rr][n0 + 16 + col] = v1;
            s_qB[rr][n0 + col]      = f2bf(v0);
            s_qB[rr][n0 + 16 + col] = f2bf(v1);
        }
    }
    __syncthreads();

    // qb[r][h] = Q_h . bk_h   (8 threads per row, tid<128)
    if (tid < 128) {
        int r = tid >> 3, rem = tid & 7, h = rem >> 2, p = rem & 3;
        float part = 0.f;
        #pragma unroll
        for (int j = 0; j < 16; ++j) {
            int dd = h * 64 + p * 16 + j;
            part += s_q[r][dd] * bk[dd];
        }
        part += __shfl_xor(part, 1);
        part += __shfl_xor(part, 2);
        if (p == 0) qb_ws[(base + r) * 2 + h] = part;
    }

    // u: wave w -> head h=w>>1, cols cb=(w&1)*96 (6 tiles), K=64.
    {
        const int h  = w >> 1;
        const int cb = (w & 1) * 96;
        f32x4 u[6];
        #pragma unroll
        for (int ct = 0; ct < 6; ++ct) u[ct] = (f32x4){0.f,0.f,0.f,0.f};
        #pragma unroll
        for (int kt = 0; kt < 2; ++kt) {
            int ko = kt * 32 + kg * 8;
            bf16x8 av = ldfrag(&s_qB[rowA][h * 64 + ko]);
            #pragma unroll
            for (int ct = 0; ct < 6; ++ct) {
                bf16x8 bfr = ldfrag(&WkTb[(size_t)h * 12288 + (size_t)(cb + ct * 16 + rowA) * 64 + ko]);
                u[ct] = MFMA(av, bfr, u[ct]);
            }
        }
        #pragma unroll
        for (int ct = 0; ct < 6; ++ct)
            #pragma unroll
            for (int rgi = 0; rgi < 4; ++rgi) {
                int rr = rgrp * 4 + rgi;
                int c  = cb + ct * 16 + col;
                u_ws[(size_t)(base + rr) * 384 + h * 192 + c] = u[ct][rgi];
            }
    }
}

// ---------------------------------------------------------------------------
// K3b: neighbor gather (bf16 LDS) + scores + softmax + kvbar. One wave/row.
// ---------------------------------------------------------------------------
__global__ __launch_bounds__(256) void k3b_score(
    const float* __restrict__ memory, const float* __restrict__ new_mem,
    const int* __restrict__ winner,
    const int* __restrict__ sel_id, const float* __restrict__ sel_td,
    const int* __restrict__ sel_mk,
    const float* __restrict__ w_ta, const float* __restrict__ b_ta,
    const float* __restrict__ u_ws, const float* __restrict__ qb_ws,
    unsigned short* __restrict__ kvbB_ws, float* __restrict__ satt_ws)
{
    const int lane = threadIdx.x & 63;
    const int w    = threadIdx.x >> 6;
    const int b    = blockIdx.x * 4 + w;

    __shared__ unsigned short s_kv[4][16][200];   // bf16 kv (192 used + pad)
    __shared__ float s_u   [4][384];
    __shared__ float s_attn[4][2][16];
    __shared__ float s_td  [4][16];
    __shared__ int   s_mk  [4][16];
    __shared__ const float* s_ptr[4][16];

    if (lane < 16) {
        int id = sel_id[b * KSEL + lane];
        int wi = winner[id];
        s_ptr[w][lane] = (wi >= 0) ? (new_mem + (size_t)wi * DIM)
                                   : (memory  + (size_t)id * DIM);
        s_td[w][lane] = sel_td[b * KSEL + lane];
        s_mk[w][lane] = sel_mk[b * KSEL + lane];
    }
    #pragma unroll
    for (int i = 0; i < 6; ++i)
        s_u[w][i * 64 + lane] = u_ws[(size_t)b * 384 + i * 64 + lane];
    __syncthreads();

    {
        #pragma unroll
        for (int it = 0; it < 8; ++it) {
            int n  = it * 2 + (lane >> 5);
            int c4 = (lane & 31) << 2;
            float4 v = *(const float4*)&s_ptr[w][n][c4];
            s_kv[w][n][c4 + 0] = f2bf(v.x); s_kv[w][n][c4 + 1] = f2bf(v.y);
            s_kv[w][n][c4 + 2] = f2bf(v.z); s_kv[w][n][c4 + 3] = f2bf(v.w);
        }
        float wt = w_ta[lane], bt = b_ta[lane];
        #pragma unroll
        for (int n = 0; n < 16; ++n) {
            float f = s_td[w][n] * wt + bt;
            s_kv[w][n][128 + lane] = f2bf((lane & 1) ? cosf(f) : sinf(f));
        }
    }
    __syncthreads();

    {
        int h = (lane >> 4) & 1, n = lane & 15, half = lane >> 5;
        float acc = (half == 0) ? qb_ws[b * 2 + h] : 0.f;
        const unsigned short* kvrow = &s_kv[w][n][half * 96];
        const float* urow = &s_u[w][h * 192 + half * 96];
        #pragma unroll
        for (int k = 0; k < 96; k += 8) {
            s16x8 kv8 = *(const s16x8*)&kvrow[k];
            #pragma unroll
            for (int j = 0; j < 8; ++j)
                acc += bf2f((unsigned short)kv8[j]) * urow[k + j];
        }
        acc += __shfl_xor(acc, 32);
        int mk = s_mk[w][n];
        float s = mk ? acc * 0.125f : -INFINITY;
        float mx = s;
        #pragma unroll
        for (int m = 1; m < 16; m <<= 1) mx = fmaxf(mx, __shfl_xor(mx, m));
        float p = (mk && mx > -1e37f) ? expf(s - mx) : 0.f;
        float den = p;
        #pragma unroll
        for (int m = 1; m < 16; m <<= 1) den += __shfl_xor(den, m);
        float a = (den > 0.f) ? (p / den) : 0.f;
        if (lane < 32) s_attn[w][h][n] = a;
        if (lane == 0 || lane == 16) satt_ws[b * 2 + h] = (den > 0.f) ? 1.f : 0.f;
    }
    __syncthreads();

    #pragma unroll
    for (int i = 0; i < 3; ++i) {
        int c = i * 64 + lane;
        float k0 = 0.f, k1 = 0.f;
        #pragma unroll
        for (int n = 0; n < 16; ++n) {
            float v = bf2f(s_kv[w][n][c]);
            k0 += s_attn[w][0][n] * v;
            k1 += s_attn[w][1][n] * v;
        }
        kvbB_ws[(size_t)b * 384 + c]       = f2bf(k0);
        kvbB_ws[(size_t)b * 384 + 192 + c] = f2bf(k1);
    }
}

// ---------------------------------------------------------------------------
// K3c (MFMA): Wv -> Wo -> Wm1 -> Wm2 -> LayerNorm. 16 rows/block.
// ---------------------------------------------------------------------------
__global__ __launch_bounds__(256) void k3c_mlp(
    const unsigned short* __restrict__ kvbB_ws, const float* __restrict__ satt_ws,
    const unsigned short* __restrict__ nfB_ws,
    const unsigned short* __restrict__ Wp,
    const float* __restrict__ bv, const float* __restrict__ bo,
    const float* __restrict__ bm1, const float* __restrict__ bm2,
    const float* __restrict__ ln_g, const float* __restrict__ ln_b,
    float* __restrict__ out)
{
    __shared__ unsigned short skvbB[16][2][200];
    __shared__ unsigned short s_cat[16][264];   // [ao 0:128 | nf 128:256]
    __shared__ unsigned short s_oB [16][136];
    __shared__ unsigned short s_h1B[16][136];
    __shared__ float          s_h2 [16][128];
    __shared__ float          s_satt[16][2];

    const unsigned short* Wvb  = Wp + OFF_WV;
    const unsigned short* Wob  = Wp + OFF_WO;
    const unsigned short* Wm1b = Wp + OFF_WM1;
    const unsigned short* Wm2b = Wp + OFF_WM2;

    const int tid  = threadIdx.x;
    const int base = blockIdx.x * 16;

    for (int idx = tid; idx < 16 * 48; idx += 256) {      // 8 bf16 per idx
        int r = idx / 48, j = (idx % 48) * 8;             // j in [0,384)
        uint4 v = *(const uint4*)&kvbB_ws[(size_t)(base + r) * 384 + j];
        int h = j / 192, jj = j % 192;
        *(uint4*)&skvbB[r][h][jj] = v;
    }
    for (int idx = tid; idx < 16 * 16; idx += 256) {      // 8 bf16 per idx
        int r = idx >> 4, j = (idx & 15) * 8;
        uint4 v = *(const uint4*)&nfB_ws[(size_t)(base + r) * DIM + j];
        *(uint4*)&s_cat[r][128 + j] = v;
    }
    if (tid < 32) s_satt[tid >> 1][tid & 1] = satt_ws[(base + (tid >> 1)) * 2 + (tid & 1)];
    __syncthreads();

    const int w    = tid >> 6;
    const int l    = tid & 63;
    const int rowA = l & 15;
    const int kg   = l >> 4;
    const int col  = l & 15;
    const int rgrp = l >> 4;

    // ---- out = Wv_h @ kvbar_h + satt_h*bv : wave w -> head w>>1, cols (w&1)*32
    {
        const int h  = w >> 1;
        const int c0 = (w & 1) * 32;
        f32x4 o0 = {0.f,0.f,0.f,0.f}, o1 = {0.f,0.f,0.f,0.f};
        #pragma unroll
        for (int kt = 0; kt < 6; ++kt) {
            int ko = kt * 32 + kg * 8;
            bf16x8 av = ldfrag(&skvbB[rowA][h][ko]);
            o0 = MFMA(av, ldfrag(&Wvb[(size_t)(h * 64 + c0 + rowA) * 192 + ko]),      o0);
            o1 = MFMA(av, ldfrag(&Wvb[(size_t)(h * 64 + c0 + 16 + rowA) * 192 + ko]), o1);
        }
        int d0 = h * 64 + c0 + col, d1 = d0 + 16;
        float bv0 = bv[d0], bv1 = bv[d1];
        #pragma unroll
        for (int rgi = 0; rgi < 4; ++rgi) {
            int rr = rgrp * 4 + rgi;
            s_oB[rr][d0] = f2bf(o0[rgi] + s_satt[rr][h] * bv0);
            s_oB[rr][d1] = f2bf(o1[rgi] + s_satt[rr][h] * bv1);
        }
    }
    __syncthreads();

    // ---- ao = Wo @ out + bo  -> s_cat[0:128]
    {
        const int n0 = w * 32;
        f32x4 a0 = {0.f,0.f,0.f,0.f}, a1 = {0.f,0.f,0.f,0.f};
        #pragma unroll
        for (int kt = 0; kt < 4; ++kt) {
            int ko = kt * 32 + kg * 8;
            bf16x8 av = ldfrag(&s_oB[rowA][ko]);
            a0 = MFMA(av, ldfrag(&Wob[(size_t)(n0 + rowA) * 128 + ko]),      a0);
            a1 = MFMA(av, ldfrag(&Wob[(size_t)(n0 + 16 + rowA) * 128 + ko]), a1);
        }
        float bb0 = bo[n0 + col], bb1 = bo[n0 + 16 + col];
        #pragma unroll
        for (int rgi = 0; rgi < 4; ++rgi) {
            int rr = rgrp * 4 + rgi;
            s_cat[rr][n0 + col]      = f2bf(a0[rgi] + bb0);
            s_cat[rr][n0 + 16 + col] = f2bf(a1[rgi] + bb1);
        }
    }
    __syncthreads();

    // ---- h1 = relu(Wm1 @ [ao|nf] + bm1), K=256
    {
        const int n0 = w * 32;
        f32x4 a0 = {0.f,0.f,0.f,0.f}, a1 = {0.f,0.f,0.f,0.f};
        #pragma unroll
        for (int kt = 0; kt < 8; ++kt) {
            int ko = kt * 32 + kg * 8;
            bf16x8 av = ldfrag(&s_cat[rowA][ko]);
            a0 = MFMA(av, ldfrag(&Wm1b[(size_t)(n0 + rowA) * 256 + ko]),      a0);
            a1 = MFMA(av, ldfrag(&Wm1b[(size_t)(n0 + 16 + rowA) * 256 + ko]), a1);
        }
        float bb0 = bm1[n0 + col], bb1 = bm1[n0 + 16 + col];
        #pragma unroll
        for (int rgi = 0; rgi < 4; ++rgi) {
            int rr = rgrp * 4 + rgi;
            s_h1B[rr][n0 + col]      = f2bf(fmaxf(a0[rgi] + bb0, 0.f));
            s_h1B[rr][n0 + 16 + col] = f2bf(fmaxf(a1[rgi] + bb1, 0.f));
        }
    }
    __syncthreads();

    // ---- h2 = Wm2 @ h1 + bm2 -> f32
    {
        const int n0 = w * 32;
        f32x4 a0 = {0.f,0.f,0.f,0.f}, a1 = {0.f,0.f,0.f,0.f};
        #pragma unroll
        for (int kt = 0; kt < 4; ++kt) {
            int ko = kt * 32 + kg * 8;
            bf16x8 av = ldfrag(&s_h1B[rowA][ko]);
            a0 = MFMA(av, ldfrag(&Wm2b[(size_t)(n0 + rowA) * 128 + ko]),      a0);
            a1 = MFMA(av, ldfrag(&Wm2b[(size_t)(n0 + 16 + rowA) * 128 + ko]), a1);
        }
        float bb0 = bm2[n0 + col], bb1 = bm2[n0 + 16 + col];
        #pragma unroll
        for (int rgi = 0; rgi < 4; ++rgi) {
            int rr = rgrp * 4 + rgi;
            s_h2[rr][n0 + col]      = a0[rgi] + bb0;
            s_h2[rr][n0 + 16 + col] = a1[rgi] + bb1;
        }
    }
    __syncthreads();

    // ---- LayerNorm: wave w -> rows w*4 .. w*4+3
    {
        float lg0 = ln_g[l], lg1 = ln_g[64 + l];
        float lb0 = ln_b[l], lb1 = ln_b[64 + l];
        #pragma unroll
        for (int i = 0; i < 4; ++i) {
            int r = w * 4 + i;
            float v0 = s_h2[r][l], v1 = s_h2[r][64 + l];
            float sum = v0 + v1;
            #pragma unroll
            for (int m = 1; m < 64; m <<= 1) sum += __shfl_xor(sum, m);
            float mean = sum * (1.f / 128.f);
            float e0 = v0 - mean, e1 = v1 - mean;
            float sq = e0 * e0 + e1 * e1;
            #pragma unroll
            for (int m = 1; m < 64; m <<= 1) sq += __shfl_xor(sq, m);
            float inv = rsqrtf(sq * (1.f / 128.f) + 1e-5f);
            out[(size_t)(base + r) * DIM + l]      = e0 * inv * lg0 + lb0;
            out[(size_t)(base + r) * DIM + 64 + l] = e1 * inv * lg1 + lb1;
        }
    }
}

// ---------------------------------------------------------------------------
extern "C" void kernel_launch(void* const* d_in, const int* in_sizes, int n_in,
                              void* d_out, int out_size, void* d_ws, size_t ws_size,
                              hipStream_t stream) {
    const int*   src         = (const int*)  d_in[0];
    const int*   dst         = (const int*)  d_in[1];
    const float* ts          = (const float*)d_in[2];
    const int*   nbr_ids     = (const int*)  d_in[3];
    const float* nbr_ts      = (const float*)d_in[4];
    const float* memory      = (const float*)d_in[5];
    const float* last_update = (const float*)d_in[6];
    const float* w_t_msg     = (const float*)d_in[7];
    const float* b_t_msg     = (const float*)d_in[8];
    const float* W_msg1      = (const float*)d_in[9];
    const float* b_msg1      = (const float*)d_in[10];
    const float* W_msg2      = (const float*)d_in[11];
    const float* b_msg2      = (const float*)d_in[12];
    const float* W_ih        = (const float*)d_in[13];
    const float* b_ih        = (const float*)d_in[14];
    const float* W_hh        = (const float*)d_in[15];
    const float* b_hh        = (const float*)d_in[16];
    const float* w_t_att     = (const float*)d_in[17];
    const float* b_t_att     = (const float*)d_in[18];
    const float* Wq          = (const float*)d_in[19];
    const float* bq          = (const float*)d_in[20];
    const float* Wk          = (const float*)d_in[21];
    const float* bk          = (const float*)d_in[22];
    const float* Wv          = (const float*)d_in[23];
    const float* bv          = (const float*)d_in[24];
    const float* Wo          = (const float*)d_in[25];
    const float* bo          = (const float*)d_in[26];
    const float* Wm1         = (const float*)d_in[27];
    const float* bm1         = (const float*)d_in[28];
    const float* Wm2         = (const float*)d_in[29];
    const float* bm2         = (const float*)d_in[30];
    const float* ln_g        = (const float*)d_in[31];
    const float* ln_b        = (const float*)d_in[32];
    float* out = (float*)d_out;

    char* ws = (char*)d_ws;
    size_t off = 0;
    float* new_mem = (float*)(ws + off); off += (size_t)2 * BATCH * DIM * 4;   // 8 MiB
    int*   winner  = (int*)  (ws + off); off += 2097152;                       // 2 MiB
    int*   sel_id  = (int*)  (ws + off); off += (size_t)BATCH * KSEL * 4;
    float* sel_td  = (float*)(ws + off); off += (size_t)BATCH * KSEL * 4;
    int*   sel_mk  = (int*)  (ws + off); off += (size_t)BATCH * KSEL * 4;
    unsigned short* nfB_ws  = (unsigned short*)(ws + off); off += (size_t)BATCH * DIM * 2;
    float* u_ws    = (float*)(ws + off); off += (size_t)BATCH * 384 * 4;
    float* qb_ws   = (float*)(ws + off); off += 65536;
    unsigned short* kvbB_ws = (unsigned short*)(ws + off); off += (size_t)BATCH * 384 * 2;
    float* satt_ws = (float*)(ws + off); off += 65536;
    unsigned short* Wpool = (unsigned short*)(ws + off); off += (size_t)CVT_TOT * 2;

    hipMemsetAsync(winner, 0xFF, NNODES * sizeof(int), stream);
    k_prep<<<NB_TOPK, 256, 0, stream>>>(
        W_msg1, W_msg2, W_ih, W_hh, Wq, Wv, Wo, Wm1, Wm2, Wk, Wpool,
        src, dst, winner, ts, nbr_ids, nbr_ts, sel_id, sel_td, sel_mk);
    k1_mfma<<<(2 * BATCH) / 32, 512, 0, stream>>>(
        src, dst, ts, memory, last_update,
        w_t_msg, b_t_msg, Wpool, b_msg1, b_msg2, b_ih, b_hh, new_mem);
    k3a_qu<<<BATCH / 16, 256, 0, stream>>>(
        src, memory, new_mem, winner, Wpool, bq, bk, nfB_ws, u_ws, qb_ws);
    k3b_score<<<BATCH / 4, 256, 0, stream>>>(
        memory, new_mem, winner, sel_id, sel_td, sel_mk,
        w_t_att, b_t_att, u_ws, qb_ws, kvbB_ws, satt_ws);
    k3c_mlp<<<BATCH / 16, 256, 0, stream>>>(
        kvbB_ws, satt_ws, nfB_ws, Wpool, bv, bo, bm1, bm2, ln_g, ln_b, out);
}

// Round 6
// 100.692 us; speedup vs baseline: 7.6823x; 1.0591x over previous
//
#include <hip/hip_runtime.h>
#include <math.h>

#define BATCH  8192
#define NNODES 500000
#define DIM    128
#define TDIM   64
#define KNB    32
#define KSEL   16

// bf16 weight pool element offsets
#define OFF_W1   0
#define OFF_W2   40960
#define OFF_WIH  57344
#define OFF_WHH  106496
#define OFF_WQ   155648
#define OFF_WV   172032
#define OFF_WO   196608
#define OFF_WM1  212992
#define OFF_WM2  245760
#define OFF_WKT  262144
#define CVT_TOT  286720

// prep kernel block ranges
#define NB_CVT  1120                  // CVT_TOT / 256 exactly
#define NB_WIN  (NB_CVT + 64)         // 16384 threads for winner scatter
#define NB_TOPK (NB_WIN + 32)         // 8192 threads for top-k

typedef float  f32x4  __attribute__((ext_vector_type(4)));
typedef __bf16 bf16x8 __attribute__((ext_vector_type(8)));
typedef short  s16x8  __attribute__((ext_vector_type(8)));

#define MFMA(a,b,c) __builtin_amdgcn_mfma_f32_16x16x32_bf16(a,b,c,0,0,0)

__device__ __forceinline__ float sigmoidf_(float x) { return 1.f / (1.f + expf(-x)); }
__device__ __forceinline__ unsigned short f2bf(float x) {
    unsigned u = __builtin_bit_cast(unsigned, x);
    unsigned r = (u + 0x7FFFu + ((u >> 16) & 1u)) >> 16;
    return (unsigned short)r;
}
__device__ __forceinline__ float bf2f(unsigned short u) {
    unsigned v = ((unsigned)u) << 16;
    return __builtin_bit_cast(float, v);
}
__device__ __forceinline__ bf16x8 ldfrag(const unsigned short* p) {
    s16x8 v = *(const s16x8*)p;
    return __builtin_bit_cast(bf16x8, v);
}

// ---------------------------------------------------------------------------
// K_prep: [0,NB_CVT) weight->bf16 pool | [NB_CVT,NB_WIN) winner scatter |
//         [NB_WIN,NB_TOPK) temporal top-16-of-32.
// ---------------------------------------------------------------------------
__global__ __launch_bounds__(256) void k_prep(
    const float* __restrict__ sW1, const float* __restrict__ sW2,
    const float* __restrict__ sWih, const float* __restrict__ sWhh,
    const float* __restrict__ sWq, const float* __restrict__ sWv,
    const float* __restrict__ sWo, const float* __restrict__ sWm1,
    const float* __restrict__ sWm2, const float* __restrict__ sWk,
    unsigned short* __restrict__ pool,
    const int* __restrict__ src, const int* __restrict__ dst,
    int* __restrict__ winner,
    const float* __restrict__ ts,
    const int* __restrict__ nbr_ids, const float* __restrict__ nbr_ts,
    int* __restrict__ sel_id, float* __restrict__ sel_td, int* __restrict__ sel_mk)
{
    const int bid = blockIdx.x;
    const int tid = threadIdx.x;

    if (bid < NB_CVT) {
        int i = bid * 256 + tid;
        float v;
        if      (i < OFF_W2)  { v = sW1 [i - OFF_W1 ]; }
        else if (i < OFF_WIH) { v = sW2 [i - OFF_W2 ]; }
        else if (i < OFF_WHH) { v = sWih[i - OFF_WIH]; }
        else if (i < OFF_WQ)  { v = sWhh[i - OFF_WHH]; }
        else if (i < OFF_WV)  { v = sWq [i - OFF_WQ ]; }
        else if (i < OFF_WO)  { v = sWv [i - OFF_WV ]; }
        else if (i < OFF_WM1) { v = sWo [i - OFF_WO ]; }
        else if (i < OFF_WM2) { v = sWm1[i - OFF_WM1]; }
        else if (i < OFF_WKT) { v = sWm2[i - OFF_WM2]; }
        else {
            int j = i - OFF_WKT;           // h*12288 + c*64 + dh
            int h = j / 12288, rem = j % 12288;
            int c = rem >> 6, dh = rem & 63;
            v = sWk[(size_t)(h * 64 + dh) * 192 + c];
        }
        pool[i] = f2bf(v);
        return;
    }
    if (bid < NB_WIN) {
        int i = (bid - NB_CVT) * 256 + tid;
        if (i < 2 * BATCH) {
            int v = (i < BATCH) ? src[i] : dst[i - BATCH];
            atomicMax(&winner[v], i);
        }
        return;
    }
    {
        int b = (bid - NB_WIN) * 256 + tid;
        if (b >= BATCH) return;
        int   s = src[b];
        float t = ts[b];
        const int*   ip = nbr_ids + (size_t)s * KNB;
        const float* tp = nbr_ts  + (size_t)s * KNB;
        float kt[KNB]; int kid[KNB];
        #pragma unroll
        for (int j = 0; j < KNB; ++j) {
            int id = ip[j]; float nt = tp[j];
            bool valid = (id >= 0) && (nt < t + 1e-6f);
            kt[j]  = valid ? nt : -1e30f;
            kid[j] = id;
        }
        unsigned picked = 0u;
        for (int sI = 0; sI < KSEL; ++sI) {
            float bv = -3.4e38f; int bj = 0; int bid2 = 0;
            #pragma unroll
            for (int j = 0; j < KNB; ++j) {
                bool avail = !((picked >> j) & 1u);
                if (avail && kt[j] > bv) { bv = kt[j]; bj = j; bid2 = kid[j]; }
            }
            picked |= (1u << bj);
            bool mk = bv > -1e29f;
            int id = mk ? (bid2 < 0 ? 0 : (bid2 > NNODES - 1 ? NNODES - 1 : bid2)) : 0;
            sel_id[b * KSEL + sI] = id;
            sel_td[b * KSEL + sI] = mk ? (t - bv) : 0.f;
            sel_mk[b * KSEL + sI] = mk ? 1 : 0;
        }
    }
}

// ---------------------------------------------------------------------------
// K1 (MFMA): message MLP + GRU. 32 rows/block, 8 waves (512 thr).
// Wave w owns output cols [w*16, w*16+16) of every GEMM stage.
// ---------------------------------------------------------------------------
__global__ __launch_bounds__(512) void k1_mfma(
    const int* __restrict__ src, const int* __restrict__ dst, const float* __restrict__ ts,
    const float* __restrict__ memory, const float* __restrict__ last_update,
    const float* __restrict__ w_t, const float* __restrict__ b_t,
    const unsigned short* __restrict__ Wp,
    const float* __restrict__ b1, const float* __restrict__ b2,
    const float* __restrict__ bih, const float* __restrict__ bhh,
    float* __restrict__ new_mem)
{
    __shared__ unsigned short sxb[32][328];   // [self|oth|te] bf16, pad 8
    __shared__ unsigned short hb [32][136];   // h1 then msg
    __shared__ int   s_node[32];
    __shared__ int   s_oth [32];
    __shared__ float s_dt  [32];

    const unsigned short* W1b  = Wp + OFF_W1;
    const unsigned short* W2b  = Wp + OFF_W2;
    const unsigned short* Wihb = Wp + OFF_WIH;
    const unsigned short* Whhb = Wp + OFF_WHH;

    const int tid  = threadIdx.x;
    const int base = blockIdx.x * 32;

    if (tid < 32) {
        int gi = base + tid;
        int node, oth; float t;
        if (gi < BATCH) { node = src[gi];         oth = dst[gi];         t = ts[gi]; }
        else            { node = dst[gi - BATCH]; oth = src[gi - BATCH]; t = ts[gi - BATCH]; }
        s_node[tid] = node;
        s_oth[tid]  = oth;
        s_dt[tid]   = t - last_update[node];
    }
    __syncthreads();

    for (int idx = tid; idx < 32 * 32; idx += 512) {
        int r = idx >> 5, c4 = (idx & 31) << 2;
        float4 vs = *(const float4*)&memory[(size_t)s_node[r] * DIM + c4];
        float4 vo = *(const float4*)&memory[(size_t)s_oth[r]  * DIM + c4];
        sxb[r][c4 + 0] = f2bf(vs.x); sxb[r][c4 + 1] = f2bf(vs.y);
        sxb[r][c4 + 2] = f2bf(vs.z); sxb[r][c4 + 3] = f2bf(vs.w);
        sxb[r][128 + c4 + 0] = f2bf(vo.x); sxb[r][128 + c4 + 1] = f2bf(vo.y);
        sxb[r][128 + c4 + 2] = f2bf(vo.z); sxb[r][128 + c4 + 3] = f2bf(vo.w);
    }
    for (int idx = tid; idx < 32 * TDIM; idx += 512) {
        int r = idx >> 6, c = idx & 63;
        float f = s_dt[r] * w_t[c] + b_t[c];
        sxb[r][256 + c] = f2bf((c & 1) ? cosf(f) : sinf(f));
    }
    __syncthreads();

    const int w    = tid >> 6;        // 0..7
    const int l    = tid & 63;
    const int rowA = l & 15;
    const int kg   = l >> 4;
    const int n0   = w * 16;
    const int col  = l & 15;
    const int rgrp = l >> 4;

    // ---- stage 1: h1 = relu(x @ W1^T + b1), K=320 ---------------------------
    {
        f32x4 a0 = {0.f,0.f,0.f,0.f}, a1 = {0.f,0.f,0.f,0.f};
        #pragma unroll
        for (int kt = 0; kt < 10; ++kt) {
            int ko = kt * 32 + kg * 8;
            bf16x8 bfr = ldfrag(&W1b[(size_t)(n0 + rowA) * 320 + ko]);
            a0 = MFMA(ldfrag(&sxb[rowA][ko]),      bfr, a0);
            a1 = MFMA(ldfrag(&sxb[16 + rowA][ko]), bfr, a1);
        }
        float bb = b1[n0 + col];
        #pragma unroll
        for (int rgi = 0; rgi < 4; ++rgi) {
            hb[rgrp * 4 + rgi][n0 + col]      = f2bf(fmaxf(a0[rgi] + bb, 0.f));
            hb[16 + rgrp * 4 + rgi][n0 + col] = f2bf(fmaxf(a1[rgi] + bb, 0.f));
        }
    }
    __syncthreads();

    // ---- stage 2: msg = h1 @ W2^T + b2, K=128 -------------------------------
    {
        f32x4 m0 = {0.f,0.f,0.f,0.f}, m1 = {0.f,0.f,0.f,0.f};
        #pragma unroll
        for (int kt = 0; kt < 4; ++kt) {
            int ko = kt * 32 + kg * 8;
            bf16x8 bfr = ldfrag(&W2b[(size_t)(n0 + rowA) * 128 + ko]);
            m0 = MFMA(ldfrag(&hb[rowA][ko]),      bfr, m0);
            m1 = MFMA(ldfrag(&hb[16 + rowA][ko]), bfr, m1);
        }
        __syncthreads();   // all h1 reads done before overwrite
        float bb = b2[n0 + col];
        #pragma unroll
        for (int rgi = 0; rgi < 4; ++rgi) {
            hb[rgrp * 4 + rgi][n0 + col]      = f2bf(m0[rgi] + bb);
            hb[16 + rgrp * 4 + rgi][n0 + col] = f2bf(m1[rgi] + bb);
        }
    }
    __syncthreads();

    // ---- stage 3: GRU gates, one 16-col pass per wave -----------------------
    {
        f32x4 g[6][2];
        #pragma unroll
        for (int gi_ = 0; gi_ < 6; ++gi_)
            #pragma unroll
            for (int ta = 0; ta < 2; ++ta) g[gi_][ta] = (f32x4){0.f,0.f,0.f,0.f};
        #pragma unroll
        for (int kt = 0; kt < 4; ++kt) {
            int ko = kt * 32 + kg * 8;
            int br = n0 + rowA;
            bf16x8 bir = ldfrag(&Wihb[(size_t)(      br) * 128 + ko]);
            bf16x8 biz = ldfrag(&Wihb[(size_t)(128 + br) * 128 + ko]);
            bf16x8 big = ldfrag(&Wihb[(size_t)(256 + br) * 128 + ko]);
            bf16x8 bhr = ldfrag(&Whhb[(size_t)(      br) * 128 + ko]);
            bf16x8 bhz = ldfrag(&Whhb[(size_t)(128 + br) * 128 + ko]);
            bf16x8 bhg = ldfrag(&Whhb[(size_t)(256 + br) * 128 + ko]);
            #pragma unroll
            for (int ta = 0; ta < 2; ++ta) {
                bf16x8 am = ldfrag(&hb [ta * 16 + rowA][ko]);
                bf16x8 ah = ldfrag(&sxb[ta * 16 + rowA][ko]);
                g[0][ta] = MFMA(am, bir, g[0][ta]);
                g[1][ta] = MFMA(am, biz, g[1][ta]);
                g[2][ta] = MFMA(am, big, g[2][ta]);
                g[3][ta] = MFMA(ah, bhr, g[3][ta]);
                g[4][ta] = MFMA(ah, bhz, g[4][ta]);
                g[5][ta] = MFMA(ah, bhg, g[5][ta]);
            }
        }
        const int d = n0 + col;
        float bir = bih[d], biz = bih[128 + d], big = bih[256 + d];
        float bhr = bhh[d], bhz = bhh[128 + d], bhg = bhh[256 + d];
        #pragma unroll
        for (int ta = 0; ta < 2; ++ta)
            #pragma unroll
            for (int rgi = 0; rgi < 4; ++rgi) {
                int rr = ta * 16 + rgrp * 4 + rgi;
                float rv = sigmoidf_((g[0][ta][rgi] + bir) + (g[3][ta][rgi] + bhr));
                float zv = sigmoidf_((g[1][ta][rgi] + biz) + (g[4][ta][rgi] + bhz));
                float gv = tanhf((g[2][ta][rgi] + big) + rv * (g[5][ta][rgi] + bhg));
                float selfv = bf2f(sxb[rr][d]);
                new_mem[(size_t)(base + rr) * DIM + d] = (1.f - zv) * gv + zv * selfv;
            }
    }
}

// ---------------------------------------------------------------------------
// K3 fused: Q/u proj (MFMA) -> per-wave gather+scores+softmax+kvbar ->
//           Wv/Wo/Wm1/Wm2 MFMA back-end + LayerNorm. 16 rows/block, 4 waves.
// ---------------------------------------------------------------------------
__global__ __launch_bounds__(256) void k3_fused(
    const int* __restrict__ src,
    const float* __restrict__ memory, const float* __restrict__ new_mem,
    const int* __restrict__ winner,
    const int* __restrict__ sel_id, const float* __restrict__ sel_td,
    const int* __restrict__ sel_mk,
    const float* __restrict__ w_ta, const float* __restrict__ b_ta,
    const unsigned short* __restrict__ Wp,
    const float* __restrict__ bq, const float* __restrict__ bk,
    const float* __restrict__ bv, const float* __restrict__ bo,
    const float* __restrict__ bm1, const float* __restrict__ bm2,
    const float* __restrict__ ln_g, const float* __restrict__ ln_b,
    float* __restrict__ out)
{
    __shared__ unsigned short s_nfB[16][136];     // node features bf16
    __shared__ unsigned short s_qB [16][136];     // Q bf16
    __shared__ unsigned short s_u  [16][2][200];  // u = Wk_h^T Q_h, bf16
    __shared__ unsigned short s_kvb[16][2][200];  // kvbar bf16
    __shared__ unsigned long long s_pool64[3200]; // 25600B: kv staging / phase-B bufs
    __shared__ const float* s_nptr[16][16];
    __shared__ float s_td [16][16];
    __shared__ int   s_mk [16][16];
    __shared__ float s_qb [16][2];
    __shared__ float s_satt[16][2];
    __shared__ float s_at [4][2][16];
    __shared__ const float* s_ptr[16];

    const unsigned short* Wqb  = Wp + OFF_WQ;
    const unsigned short* WkTb = Wp + OFF_WKT;
    const unsigned short* Wvb  = Wp + OFF_WV;
    const unsigned short* Wob  = Wp + OFF_WO;
    const unsigned short* Wm1b = Wp + OFF_WM1;
    const unsigned short* Wm2b = Wp + OFF_WM2;

    const int tid  = threadIdx.x;
    const int base = blockIdx.x * 16;

    // ---- stage pointers + per-row neighbor metadata -------------------------
    if (tid < 16) {
        int v = src[base + tid];
        int wv = winner[v];
        s_ptr[tid] = (wv >= 0) ? (new_mem + (size_t)wv * DIM)
                               : (memory  + (size_t)v  * DIM);
    }
    {
        int r = tid >> 4, n = tid & 15;
        int id = sel_id[(base + r) * KSEL + n];
        int wi = winner[id];
        s_nptr[r][n] = (wi >= 0) ? (new_mem + (size_t)wi * DIM)
                                 : (memory  + (size_t)id * DIM);
        s_td[r][n] = sel_td[(base + r) * KSEL + n];
        s_mk[r][n] = sel_mk[(base + r) * KSEL + n];
    }
    __syncthreads();

    // ---- gather node features -> s_nfB --------------------------------------
    for (int idx = tid; idx < 16 * 32; idx += 256) {
        int r = idx >> 5, c4 = (idx & 31) << 2;
        float4 v = *(const float4*)&s_ptr[r][c4];
        s_nfB[r][c4 + 0] = f2bf(v.x); s_nfB[r][c4 + 1] = f2bf(v.y);
        s_nfB[r][c4 + 2] = f2bf(v.z); s_nfB[r][c4 + 3] = f2bf(v.w);
    }
    __syncthreads();

    const int w    = tid >> 6;
    const int l    = tid & 63;
    const int rowA = l & 15;
    const int kg   = l >> 4;
    const int col  = l & 15;
    const int rgrp = l >> 4;

    // ---- phase 0a: Q = nf @ Wq^T + bq (wave w: cols w*32..w*32+32) ----------
    {
        const int n0 = w * 32;
        f32x4 q0 = {0.f,0.f,0.f,0.f}, q1 = {0.f,0.f,0.f,0.f};
        #pragma unroll
        for (int kt = 0; kt < 4; ++kt) {
            int ko = kt * 32 + kg * 8;
            bf16x8 av = ldfrag(&s_nfB[rowA][ko]);
            q0 = MFMA(av, ldfrag(&Wqb[(size_t)(n0 + rowA) * 128 + ko]),      q0);
            q1 = MFMA(av, ldfrag(&Wqb[(size_t)(n0 + 16 + rowA) * 128 + ko]), q1);
        }
        float bb0 = bq[n0 + col], bb1 = bq[n0 + 16 + col];
        #pragma unroll
        for (int rgi = 0; rgi < 4; ++rgi) {
            int rr = rgrp * 4 + rgi;
            s_qB[rr][n0 + col]      = f2bf(q0[rgi] + bb0);
            s_qB[rr][n0 + 16 + col] = f2bf(q1[rgi] + bb1);
        }
    }
    __syncthreads();

    // ---- phase 0b: qb[r][h] = Q_h . bk_h  (128 threads) ---------------------
    if (tid < 128) {
        int r = tid >> 3, rem = tid & 7, h = rem >> 2, p = rem & 3;
        float part = 0.f;
        #pragma unroll
        for (int j = 0; j < 16; ++j) {
            int dd = h * 64 + p * 16 + j;
            part += bf2f(s_qB[r][dd]) * bk[dd];
        }
        part += __shfl_xor(part, 1);
        part += __shfl_xor(part, 2);
        if (p == 0) s_qb[r][h] = part;
    }

    // ---- phase 0c: u = Wk_h^T Q_h (wave w: head w>>1, cols (w&1)*96) --------
    {
        const int h  = w >> 1;
        const int cb = (w & 1) * 96;
        f32x4 u[6];
        #pragma unroll
        for (int ct = 0; ct < 6; ++ct) u[ct] = (f32x4){0.f,0.f,0.f,0.f};
        #pragma unroll
        for (int kt = 0; kt < 2; ++kt) {
            int ko = kt * 32 + kg * 8;
            bf16x8 av = ldfrag(&s_qB[rowA][h * 64 + ko]);
            #pragma unroll
            for (int ct = 0; ct < 6; ++ct) {
                bf16x8 bfr = ldfrag(&WkTb[(size_t)h * 12288 + (size_t)(cb + ct * 16 + rowA) * 64 + ko]);
                u[ct] = MFMA(av, bfr, u[ct]);
            }
        }
        #pragma unroll
        for (int ct = 0; ct < 6; ++ct)
            #pragma unroll
            for (int rgi = 0; rgi < 4; ++rgi) {
                int rr = rgrp * 4 + rgi;
                s_u[rr][h][cb + ct * 16 + col] = f2bf(u[ct][rgi]);
            }
    }
    __syncthreads();

    // ---- phase A: per-wave 4 rows: gather kv, scores, softmax, kvbar --------
    {
        unsigned short (*kvbuf)[16][200] = (unsigned short (*)[16][200])s_pool64;
        float wt = w_ta[l], bt = b_ta[l];
        for (int rr = 0; rr < 4; ++rr) {
            const int r = w * 4 + rr;            // row within block
            // gather 16 neighbor rows -> kvbuf[w] (bf16) + time encoding
            #pragma unroll
            for (int it = 0; it < 8; ++it) {
                int n  = it * 2 + (l >> 5);
                int c4 = (l & 31) << 2;
                float4 v = *(const float4*)&s_nptr[r][n][c4];
                kvbuf[w][n][c4 + 0] = f2bf(v.x); kvbuf[w][n][c4 + 1] = f2bf(v.y);
                kvbuf[w][n][c4 + 2] = f2bf(v.z); kvbuf[w][n][c4 + 3] = f2bf(v.w);
            }
            #pragma unroll
            for (int n = 0; n < 16; ++n) {
                float f = s_td[r][n] * wt + bt;
                kvbuf[w][n][128 + l] = f2bf((l & 1) ? cosf(f) : sinf(f));
            }
            __syncthreads();

            // scores + masked softmax
            {
                int h = (l >> 4) & 1, n = l & 15, half = l >> 5;
                float acc = (half == 0) ? s_qb[r][h] : 0.f;
                const unsigned short* kvrow = &kvbuf[w][n][half * 96];
                const unsigned short* urow  = &s_u[r][h][half * 96];
                #pragma unroll
                for (int k = 0; k < 96; k += 8) {
                    s16x8 kv8 = *(const s16x8*)&kvrow[k];
                    s16x8 u8  = *(const s16x8*)&urow[k];
                    #pragma unroll
                    for (int j = 0; j < 8; ++j)
                        acc += bf2f((unsigned short)kv8[j]) * bf2f((unsigned short)u8[j]);
                }
                acc += __shfl_xor(acc, 32);
                int mk = s_mk[r][n];
                float s = mk ? acc * 0.125f : -INFINITY;
                float mx = s;
                #pragma unroll
                for (int m = 1; m < 16; m <<= 1) mx = fmaxf(mx, __shfl_xor(mx, m));
                float p = (mk && mx > -1e37f) ? expf(s - mx) : 0.f;
                float den = p;
                #pragma unroll
                for (int m = 1; m < 16; m <<= 1) den += __shfl_xor(den, m);
                float a = (den > 0.f) ? (p / den) : 0.f;
                if (l < 32) s_at[w][h][n] = a;
                if (l == 0 || l == 16) s_satt[r][h] = (den > 0.f) ? 1.f : 0.f;
            }
            __syncthreads();

            // kvbar[h][c] = sum_n at[h][n] * kv[n][c]  -> s_kvb (bf16)
            #pragma unroll
            for (int i = 0; i < 3; ++i) {
                int c = i * 64 + l;
                float k0 = 0.f, k1 = 0.f;
                #pragma unroll
                for (int n = 0; n < 16; ++n) {
                    float v = bf2f(kvbuf[w][n][c]);
                    k0 += s_at[w][0][n] * v;
                    k1 += s_at[w][1][n] * v;
                }
                s_kvb[r][0][c] = f2bf(k0);
                s_kvb[r][1][c] = f2bf(k1);
            }
            __syncthreads();
        }
    }
    __syncthreads();

    // ---- phase B: MFMA back-end (pool aliased: kv staging is dead) ----------
    unsigned short (*s_aoB)[136] = (unsigned short (*)[136])s_pool64;
    unsigned short (*s_oB )[136] = (unsigned short (*)[136])((char*)s_pool64 + 4352);
    unsigned short (*s_h1B)[136] = (unsigned short (*)[136])((char*)s_pool64 + 8704);
    float          (*s_h2 )[128] = (float          (*)[128])((char*)s_pool64 + 13056);

    // out = Wv_h @ kvbar_h + satt_h*bv : wave w -> head w>>1, cols (w&1)*32
    {
        const int h  = w >> 1;
        const int c0 = (w & 1) * 32;
        f32x4 o0 = {0.f,0.f,0.f,0.f}, o1 = {0.f,0.f,0.f,0.f};
        #pragma unroll
        for (int kt = 0; kt < 6; ++kt) {
            int ko = kt * 32 + kg * 8;
            bf16x8 av = ldfrag(&s_kvb[rowA][h][ko]);
            o0 = MFMA(av, ldfrag(&Wvb[(size_t)(h * 64 + c0 + rowA) * 192 + ko]),      o0);
            o1 = MFMA(av, ldfrag(&Wvb[(size_t)(h * 64 + c0 + 16 + rowA) * 192 + ko]), o1);
        }
        int d0 = h * 64 + c0 + col, d1 = d0 + 16;
        float bv0 = bv[d0], bv1 = bv[d1];
        #pragma unroll
        for (int rgi = 0; rgi < 4; ++rgi) {
            int rr = rgrp * 4 + rgi;
            s_oB[rr][d0] = f2bf(o0[rgi] + s_satt[rr][h] * bv0);
            s_oB[rr][d1] = f2bf(o1[rgi] + s_satt[rr][h] * bv1);
        }
    }
    __syncthreads();

    // ao = Wo @ out + bo
    {
        const int n0 = w * 32;
        f32x4 a0 = {0.f,0.f,0.f,0.f}, a1 = {0.f,0.f,0.f,0.f};
        #pragma unroll
        for (int kt = 0; kt < 4; ++kt) {
            int ko = kt * 32 + kg * 8;
            bf16x8 av = ldfrag(&s_oB[rowA][ko]);
            a0 = MFMA(av, ldfrag(&Wob[(size_t)(n0 + rowA) * 128 + ko]),      a0);
            a1 = MFMA(av, ldfrag(&Wob[(size_t)(n0 + 16 + rowA) * 128 + ko]), a1);
        }
        float bb0 = bo[n0 + col], bb1 = bo[n0 + 16 + col];
        #pragma unroll
        for (int rgi = 0; rgi < 4; ++rgi) {
            int rr = rgrp * 4 + rgi;
            s_aoB[rr][n0 + col]      = f2bf(a0[rgi] + bb0);
            s_aoB[rr][n0 + 16 + col] = f2bf(a1[rgi] + bb1);
        }
    }
    __syncthreads();

    // h1 = relu(Wm1 @ [ao|nf] + bm1), K=256 (kt 0..3: ao, kt 4..7: nf)
    {
        const int n0 = w * 32;
        f32x4 a0 = {0.f,0.f,0.f,0.f}, a1 = {0.f,0.f,0.f,0.f};
        #pragma unroll
        for (int kt = 0; kt < 8; ++kt) {
            int ko = kt * 32 + kg * 8;
            bf16x8 av = (kt < 4) ? ldfrag(&s_aoB[rowA][ko])
                                 : ldfrag(&s_nfB[rowA][ko - 128]);
            a0 = MFMA(av, ldfrag(&Wm1b[(size_t)(n0 + rowA) * 256 + ko]),      a0);
            a1 = MFMA(av, ldfrag(&Wm1b[(size_t)(n0 + 16 + rowA) * 256 + ko]), a1);
        }
        float bb0 = bm1[n0 + col], bb1 = bm1[n0 + 16 + col];
        #pragma unroll
        for (int rgi = 0; rgi < 4; ++rgi) {
            int rr = rgrp * 4 + rgi;
            s_h1B[rr][n0 + col]      = f2bf(fmaxf(a0[rgi] + bb0, 0.f));
            s_h1B[rr][n0 + 16 + col] = f2bf(fmaxf(a1[rgi] + bb1, 0.f));
        }
    }
    __syncthreads();

    // h2 = Wm2 @ h1 + bm2 -> f32
    {
        const int n0 = w * 32;
        f32x4 a0 = {0.f,0.f,0.f,0.f}, a1 = {0.f,0.f,0.f,0.f};
        #pragma unroll
        for (int kt = 0; kt < 4; ++kt) {
            int ko = kt * 32 + kg * 8;
            bf16x8 av = ldfrag(&s_h1B[rowA][ko]);
            a0 = MFMA(av, ldfrag(&Wm2b[(size_t)(n0 + rowA) * 128 + ko]),      a0);
            a1 = MFMA(av, ldfrag(&Wm2b[(size_t)(n0 + 16 + rowA) * 128 + ko]), a1);
        }
        float bb0 = bm2[n0 + col], bb1 = bm2[n0 + 16 + col];
        #pragma unroll
        for (int rgi = 0; rgi < 4; ++rgi) {
            int rr = rgrp * 4 + rgi;
            s_h2[rr][n0 + col]      = a0[rgi] + bb0;
            s_h2[rr][n0 + 16 + col] = a1[rgi] + bb1;
        }
    }
    __syncthreads();

    // LayerNorm: wave w -> rows w*4 .. w*4+3
    {
        float lg0 = ln_g[l], lg1 = ln_g[64 + l];
        float lb0 = ln_b[l], lb1 = ln_b[64 + l];
        #pragma unroll
        for (int i = 0; i < 4; ++i) {
            int r = w * 4 + i;
            float v0 = s_h2[r][l], v1 = s_h2[r][64 + l];
            float sum = v0 + v1;
            #pragma unroll
            for (int m = 1; m < 64; m <<= 1) sum += __shfl_xor(sum, m);
            float mean = sum * (1.f / 128.f);
            float e0 = v0 - mean, e1 = v1 - mean;
            float sq = e0 * e0 + e1 * e1;
            #pragma unroll
            for (int m = 1; m < 64; m <<= 1) sq += __shfl_xor(sq, m);
            float inv = rsqrtf(sq * (1.f / 128.f) + 1e-5f);
            out[(size_t)(base + r) * DIM + l]      = e0 * inv * lg0 + lb0;
            out[(size_t)(base + r) * DIM + 64 + l] = e1 * inv * lg1 + lb1;
        }
    }
}

// ---------------------------------------------------------------------------
extern "C" void kernel_launch(void* const* d_in, const int* in_sizes, int n_in,
                              void* d_out, int out_size, void* d_ws, size_t ws_size,
                              hipStream_t stream) {
    const int*   src         = (const int*)  d_in[0];
    const int*   dst         = (const int*)  d_in[1];
    const float* ts          = (const float*)d_in[2];
    const int*   nbr_ids     = (const int*)  d_in[3];
    const float* nbr_ts      = (const float*)d_in[4];
    const float* memory      = (const float*)d_in[5];
    const float* last_update = (const float*)d_in[6];
    const float* w_t_msg     = (const float*)d_in[7];
    const float* b_t_msg     = (const float*)d_in[8];
    const float* W_msg1      = (const float*)d_in[9];
    const float* b_msg1      = (const float*)d_in[10];
    const float* W_msg2      = (const float*)d_in[11];
    const float* b_msg2      = (const float*)d_in[12];
    const float* W_ih        = (const float*)d_in[13];
    const float* b_ih        = (const float*)d_in[14];
    const float* W_hh        = (const float*)d_in[15];
    const float* b_hh        = (const float*)d_in[16];
    const float* w_t_att     = (const float*)d_in[17];
    const float* b_t_att     = (const float*)d_in[18];
    const float* Wq          = (const float*)d_in[19];
    const float* bq          = (const float*)d_in[20];
    const float* Wk          = (const float*)d_in[21];
    const float* bk          = (const float*)d_in[22];
    const float* Wv          = (const float*)d_in[23];
    const float* bv          = (const float*)d_in[24];
    const float* Wo          = (const float*)d_in[25];
    const float* bo          = (const float*)d_in[26];
    const float* Wm1         = (const float*)d_in[27];
    const float* bm1         = (const float*)d_in[28];
    const float* Wm2         = (const float*)d_in[29];
    const float* bm2         = (const float*)d_in[30];
    const float* ln_g        = (const float*)d_in[31];
    const float* ln_b        = (const float*)d_in[32];
    float* out = (float*)d_out;

    char* ws = (char*)d_ws;
    size_t off = 0;
    float* new_mem = (float*)(ws + off); off += (size_t)2 * BATCH * DIM * 4;   // 8 MiB
    int*   winner  = (int*)  (ws + off); off += 2097152;                       // 2 MiB
    int*   sel_id  = (int*)  (ws + off); off += (size_t)BATCH * KSEL * 4;
    float* sel_td  = (float*)(ws + off); off += (size_t)BATCH * KSEL * 4;
    int*   sel_mk  = (int*)  (ws + off); off += (size_t)BATCH * KSEL * 4;
    unsigned short* Wpool = (unsigned short*)(ws + off); off += (size_t)CVT_TOT * 2;

    hipMemsetAsync(winner, 0xFF, NNODES * sizeof(int), stream);
    k_prep<<<NB_TOPK, 256, 0, stream>>>(
        W_msg1, W_msg2, W_ih, W_hh, Wq, Wv, Wo, Wm1, Wm2, Wk, Wpool,
        src, dst, winner, ts, nbr_ids, nbr_ts, sel_id, sel_td, sel_mk);
    k1_mfma<<<(2 * BATCH) / 32, 512, 0, stream>>>(
        src, dst, ts, memory, last_update,
        w_t_msg, b_t_msg, Wpool, b_msg1, b_msg2, b_ih, b_hh, new_mem);
    k3_fused<<<BATCH / 16, 256, 0, stream>>>(
        src, memory, new_mem, winner, sel_id, sel_td, sel_mk,
        w_t_att, b_t_att, Wpool, bq, bk, bv, bo, bm1, bm2, ln_g, ln_b, out);
}

// Round 7
// 92.871 us; speedup vs baseline: 8.3294x; 1.0842x over previous
//
#include <hip/hip_runtime.h>
#include <math.h>

#define BATCH  8192
#define NNODES 500000
#define DIM    128
#define TDIM   64
#define KNB    32
#define KSEL   16

// bf16 weight pool element offsets
#define OFF_W1   0
#define OFF_W2   40960
#define OFF_WIH  57344
#define OFF_WHH  106496
#define OFF_WQ   155648
#define OFF_WV   172032
#define OFF_WO   196608
#define OFF_WM1  212992
#define OFF_WM2  245760
#define OFF_WKT  262144
#define CVT_TOT  286720

// prep kernel block ranges
#define NB_CVT  1120                  // CVT_TOT / 256 exactly
#define NB_WIN  (NB_CVT + 64)         // 16384 threads for winner scatter
#define NB_TOPK (NB_WIN + 32)         // 8192 threads for top-k

typedef float  f32x4  __attribute__((ext_vector_type(4)));
typedef __bf16 bf16x8 __attribute__((ext_vector_type(8)));
typedef short  s16x8  __attribute__((ext_vector_type(8)));

#define MFMA(a,b,c) __builtin_amdgcn_mfma_f32_16x16x32_bf16(a,b,c,0,0,0)

__device__ __forceinline__ float sigmoidf_(float x) { return 1.f / (1.f + expf(-x)); }
__device__ __forceinline__ unsigned short f2bf(float x) {
    unsigned u = __builtin_bit_cast(unsigned, x);
    unsigned r = (u + 0x7FFFu + ((u >> 16) & 1u)) >> 16;
    return (unsigned short)r;
}
__device__ __forceinline__ float bf2f(unsigned short u) {
    unsigned v = ((unsigned)u) << 16;
    return __builtin_bit_cast(float, v);
}
__device__ __forceinline__ bf16x8 ldfrag(const unsigned short* p) {
    s16x8 v = *(const s16x8*)p;
    return __builtin_bit_cast(bf16x8, v);
}
__device__ __forceinline__ uint2 pack4bf(float4 v) {
    uint2 pk;
    pk.x = (unsigned)f2bf(v.x) | ((unsigned)f2bf(v.y) << 16);
    pk.y = (unsigned)f2bf(v.z) | ((unsigned)f2bf(v.w) << 16);
    return pk;
}

// ---------------------------------------------------------------------------
// K_prep: [0,NB_CVT) weight->bf16 pool | [NB_CVT,NB_WIN) winner scatter |
//         [NB_WIN,NB_TOPK) temporal top-16-of-32.
// ---------------------------------------------------------------------------
__global__ __launch_bounds__(256) void k_prep(
    const float* __restrict__ sW1, const float* __restrict__ sW2,
    const float* __restrict__ sWih, const float* __restrict__ sWhh,
    const float* __restrict__ sWq, const float* __restrict__ sWv,
    const float* __restrict__ sWo, const float* __restrict__ sWm1,
    const float* __restrict__ sWm2, const float* __restrict__ sWk,
    unsigned short* __restrict__ pool,
    const int* __restrict__ src, const int* __restrict__ dst,
    int* __restrict__ winner,
    const float* __restrict__ ts,
    const int* __restrict__ nbr_ids, const float* __restrict__ nbr_ts,
    int* __restrict__ sel_id, float* __restrict__ sel_td, int* __restrict__ sel_mk)
{
    const int bid = blockIdx.x;
    const int tid = threadIdx.x;

    if (bid < NB_CVT) {
        int i = bid * 256 + tid;
        float v;
        if      (i < OFF_W2)  { v = sW1 [i - OFF_W1 ]; }
        else if (i < OFF_WIH) { v = sW2 [i - OFF_W2 ]; }
        else if (i < OFF_WHH) { v = sWih[i - OFF_WIH]; }
        else if (i < OFF_WQ)  { v = sWhh[i - OFF_WHH]; }
        else if (i < OFF_WV)  { v = sWq [i - OFF_WQ ]; }
        else if (i < OFF_WO)  { v = sWv [i - OFF_WV ]; }
        else if (i < OFF_WM1) { v = sWo [i - OFF_WO ]; }
        else if (i < OFF_WM2) { v = sWm1[i - OFF_WM1]; }
        else if (i < OFF_WKT) { v = sWm2[i - OFF_WM2]; }
        else {
            int j = i - OFF_WKT;           // h*12288 + c*64 + dh
            int h = j / 12288, rem = j % 12288;
            int c = rem >> 6, dh = rem & 63;
            v = sWk[(size_t)(h * 64 + dh) * 192 + c];
        }
        pool[i] = f2bf(v);
        return;
    }
    if (bid < NB_WIN) {
        int i = (bid - NB_CVT) * 256 + tid;
        if (i < 2 * BATCH) {
            int v = (i < BATCH) ? src[i] : dst[i - BATCH];
            atomicMax(&winner[v], i);
        }
        return;
    }
    {
        int b = (bid - NB_WIN) * 256 + tid;
        if (b >= BATCH) return;
        int   s = src[b];
        float t = ts[b];
        const int*   ip = nbr_ids + (size_t)s * KNB;
        const float* tp = nbr_ts  + (size_t)s * KNB;
        float kt[KNB]; int kid[KNB];
        #pragma unroll
        for (int j = 0; j < KNB; ++j) {
            int id = ip[j]; float nt = tp[j];
            bool valid = (id >= 0) && (nt < t + 1e-6f);
            kt[j]  = valid ? nt : -1e30f;
            kid[j] = id;
        }
        unsigned picked = 0u;
        for (int sI = 0; sI < KSEL; ++sI) {
            float bv = -3.4e38f; int bj = 0; int bid2 = 0;
            #pragma unroll
            for (int j = 0; j < KNB; ++j) {
                bool avail = !((picked >> j) & 1u);
                if (avail && kt[j] > bv) { bv = kt[j]; bj = j; bid2 = kid[j]; }
            }
            picked |= (1u << bj);
            bool mk = bv > -1e29f;
            int id = mk ? (bid2 < 0 ? 0 : (bid2 > NNODES - 1 ? NNODES - 1 : bid2)) : 0;
            sel_id[b * KSEL + sI] = id;
            sel_td[b * KSEL + sI] = mk ? (t - bv) : 0.f;
            sel_mk[b * KSEL + sI] = mk ? 1 : 0;
        }
    }
}

// ---------------------------------------------------------------------------
// K1 (MFMA): message MLP + GRU. 32 rows/block, 8 waves (512 thr).
// Wave w owns output cols [w*16, w*16+16) of every GEMM stage.
// ---------------------------------------------------------------------------
__global__ __launch_bounds__(512) void k1_mfma(
    const int* __restrict__ src, const int* __restrict__ dst, const float* __restrict__ ts,
    const float* __restrict__ memory, const float* __restrict__ last_update,
    const float* __restrict__ w_t, const float* __restrict__ b_t,
    const unsigned short* __restrict__ Wp,
    const float* __restrict__ b1, const float* __restrict__ b2,
    const float* __restrict__ bih, const float* __restrict__ bhh,
    float* __restrict__ new_mem)
{
    __shared__ unsigned short sxb[32][328];   // [self|oth|te] bf16, pad 8
    __shared__ unsigned short hb [32][136];   // h1 then msg
    __shared__ int   s_node[32];
    __shared__ int   s_oth [32];
    __shared__ float s_dt  [32];

    const unsigned short* W1b  = Wp + OFF_W1;
    const unsigned short* W2b  = Wp + OFF_W2;
    const unsigned short* Wihb = Wp + OFF_WIH;
    const unsigned short* Whhb = Wp + OFF_WHH;

    const int tid  = threadIdx.x;
    const int base = blockIdx.x * 32;

    if (tid < 32) {
        int gi = base + tid;
        int node, oth; float t;
        if (gi < BATCH) { node = src[gi];         oth = dst[gi];         t = ts[gi]; }
        else            { node = dst[gi - BATCH]; oth = src[gi - BATCH]; t = ts[gi - BATCH]; }
        s_node[tid] = node;
        s_oth[tid]  = oth;
        s_dt[tid]   = t - last_update[node];
    }
    __syncthreads();

    for (int idx = tid; idx < 32 * 32; idx += 512) {
        int r = idx >> 5, c4 = (idx & 31) << 2;
        float4 vs = *(const float4*)&memory[(size_t)s_node[r] * DIM + c4];
        float4 vo = *(const float4*)&memory[(size_t)s_oth[r]  * DIM + c4];
        *(uint2*)&sxb[r][c4]       = pack4bf(vs);
        *(uint2*)&sxb[r][128 + c4] = pack4bf(vo);
    }
    for (int idx = tid; idx < 32 * TDIM; idx += 512) {
        int r = idx >> 6, c = idx & 63;
        float f = s_dt[r] * w_t[c] + b_t[c];
        sxb[r][256 + c] = f2bf((c & 1) ? cosf(f) : sinf(f));
    }
    __syncthreads();

    const int w    = tid >> 6;        // 0..7
    const int l    = tid & 63;
    const int rowA = l & 15;
    const int kg   = l >> 4;
    const int n0   = w * 16;
    const int col  = l & 15;
    const int rgrp = l >> 4;

    // ---- stage 1: h1 = relu(x @ W1^T + b1), K=320 ---------------------------
    {
        f32x4 a0 = {0.f,0.f,0.f,0.f}, a1 = {0.f,0.f,0.f,0.f};
        #pragma unroll
        for (int kt = 0; kt < 10; ++kt) {
            int ko = kt * 32 + kg * 8;
            bf16x8 bfr = ldfrag(&W1b[(size_t)(n0 + rowA) * 320 + ko]);
            a0 = MFMA(ldfrag(&sxb[rowA][ko]),      bfr, a0);
            a1 = MFMA(ldfrag(&sxb[16 + rowA][ko]), bfr, a1);
        }
        float bb = b1[n0 + col];
        #pragma unroll
        for (int rgi = 0; rgi < 4; ++rgi) {
            hb[rgrp * 4 + rgi][n0 + col]      = f2bf(fmaxf(a0[rgi] + bb, 0.f));
            hb[16 + rgrp * 4 + rgi][n0 + col] = f2bf(fmaxf(a1[rgi] + bb, 0.f));
        }
    }
    __syncthreads();

    // ---- stage 2: msg = h1 @ W2^T + b2, K=128 -------------------------------
    {
        f32x4 m0 = {0.f,0.f,0.f,0.f}, m1 = {0.f,0.f,0.f,0.f};
        #pragma unroll
        for (int kt = 0; kt < 4; ++kt) {
            int ko = kt * 32 + kg * 8;
            bf16x8 bfr = ldfrag(&W2b[(size_t)(n0 + rowA) * 128 + ko]);
            m0 = MFMA(ldfrag(&hb[rowA][ko]),      bfr, m0);
            m1 = MFMA(ldfrag(&hb[16 + rowA][ko]), bfr, m1);
        }
        __syncthreads();   // all h1 reads done before overwrite
        float bb = b2[n0 + col];
        #pragma unroll
        for (int rgi = 0; rgi < 4; ++rgi) {
            hb[rgrp * 4 + rgi][n0 + col]      = f2bf(m0[rgi] + bb);
            hb[16 + rgrp * 4 + rgi][n0 + col] = f2bf(m1[rgi] + bb);
        }
    }
    __syncthreads();

    // ---- stage 3: GRU gates, one 16-col pass per wave -----------------------
    {
        f32x4 g[6][2];
        #pragma unroll
        for (int gi_ = 0; gi_ < 6; ++gi_)
            #pragma unroll
            for (int ta = 0; ta < 2; ++ta) g[gi_][ta] = (f32x4){0.f,0.f,0.f,0.f};
        #pragma unroll
        for (int kt = 0; kt < 4; ++kt) {
            int ko = kt * 32 + kg * 8;
            int br = n0 + rowA;
            bf16x8 bir = ldfrag(&Wihb[(size_t)(      br) * 128 + ko]);
            bf16x8 biz = ldfrag(&Wihb[(size_t)(128 + br) * 128 + ko]);
            bf16x8 big = ldfrag(&Wihb[(size_t)(256 + br) * 128 + ko]);
            bf16x8 bhr = ldfrag(&Whhb[(size_t)(      br) * 128 + ko]);
            bf16x8 bhz = ldfrag(&Whhb[(size_t)(128 + br) * 128 + ko]);
            bf16x8 bhg = ldfrag(&Whhb[(size_t)(256 + br) * 128 + ko]);
            #pragma unroll
            for (int ta = 0; ta < 2; ++ta) {
                bf16x8 am = ldfrag(&hb [ta * 16 + rowA][ko]);
                bf16x8 ah = ldfrag(&sxb[ta * 16 + rowA][ko]);
                g[0][ta] = MFMA(am, bir, g[0][ta]);
                g[1][ta] = MFMA(am, biz, g[1][ta]);
                g[2][ta] = MFMA(am, big, g[2][ta]);
                g[3][ta] = MFMA(ah, bhr, g[3][ta]);
                g[4][ta] = MFMA(ah, bhz, g[4][ta]);
                g[5][ta] = MFMA(ah, bhg, g[5][ta]);
            }
        }
        const int d = n0 + col;
        float bir = bih[d], biz = bih[128 + d], big = bih[256 + d];
        float bhr = bhh[d], bhz = bhh[128 + d], bhg = bhh[256 + d];
        #pragma unroll
        for (int ta = 0; ta < 2; ++ta)
            #pragma unroll
            for (int rgi = 0; rgi < 4; ++rgi) {
                int rr = ta * 16 + rgrp * 4 + rgi;
                float rv = sigmoidf_((g[0][ta][rgi] + bir) + (g[3][ta][rgi] + bhr));
                float zv = sigmoidf_((g[1][ta][rgi] + biz) + (g[4][ta][rgi] + bhz));
                float gv = tanhf((g[2][ta][rgi] + big) + rv * (g[5][ta][rgi] + bhg));
                float selfv = bf2f(sxb[rr][d]);
                new_mem[(size_t)(base + rr) * DIM + d] = (1.f - zv) * gv + zv * selfv;
            }
    }
}

// ---------------------------------------------------------------------------
// K3 fused: Q/u proj (MFMA) -> per-wave gather+scores+softmax+kvbar (NO block
// barriers in phase A: all wave-private; reg-prefetch next row's gather) ->
// Wv/Wo/Wm1/Wm2 MFMA back-end + LayerNorm. 16 rows/block, 4 waves.
// ---------------------------------------------------------------------------
__global__ __launch_bounds__(256) void k3_fused(
    const int* __restrict__ src,
    const float* __restrict__ memory, const float* __restrict__ new_mem,
    const int* __restrict__ winner,
    const int* __restrict__ sel_id, const float* __restrict__ sel_td,
    const int* __restrict__ sel_mk,
    const float* __restrict__ w_ta, const float* __restrict__ b_ta,
    const unsigned short* __restrict__ Wp,
    const float* __restrict__ bq, const float* __restrict__ bk,
    const float* __restrict__ bv, const float* __restrict__ bo,
    const float* __restrict__ bm1, const float* __restrict__ bm2,
    const float* __restrict__ ln_g, const float* __restrict__ ln_b,
    float* __restrict__ out)
{
    __shared__ unsigned short s_nfB[16][136];     // node features bf16
    __shared__ unsigned short s_qB [16][136];     // Q bf16
    __shared__ unsigned short s_u  [16][2][200];  // u = Wk_h^T Q_h, bf16
    __shared__ unsigned short s_kvb[16][2][200];  // kvbar bf16
    __shared__ unsigned long long s_pool64[3200]; // 25600B: kv staging / phase-B bufs
    __shared__ const float* s_nptr[16][16];
    __shared__ float s_td [16][16];
    __shared__ int   s_mk [16][16];
    __shared__ float s_qb [16][2];
    __shared__ float s_satt[16][2];
    __shared__ float s_at [4][2][16];
    __shared__ const float* s_ptr[16];

    const unsigned short* Wqb  = Wp + OFF_WQ;
    const unsigned short* WkTb = Wp + OFF_WKT;
    const unsigned short* Wvb  = Wp + OFF_WV;
    const unsigned short* Wob  = Wp + OFF_WO;
    const unsigned short* Wm1b = Wp + OFF_WM1;
    const unsigned short* Wm2b = Wp + OFF_WM2;

    const int tid  = threadIdx.x;
    const int base = blockIdx.x * 16;

    // ---- stage pointers + per-row neighbor metadata -------------------------
    if (tid < 16) {
        int v = src[base + tid];
        int wv = winner[v];
        s_ptr[tid] = (wv >= 0) ? (new_mem + (size_t)wv * DIM)
                               : (memory  + (size_t)v  * DIM);
    }
    {
        int r = tid >> 4, n = tid & 15;
        int id = sel_id[(base + r) * KSEL + n];
        int wi = winner[id];
        s_nptr[r][n] = (wi >= 0) ? (new_mem + (size_t)wi * DIM)
                                 : (memory  + (size_t)id * DIM);
        s_td[r][n] = sel_td[(base + r) * KSEL + n];
        s_mk[r][n] = sel_mk[(base + r) * KSEL + n];
    }
    __syncthreads();

    // ---- gather node features -> s_nfB --------------------------------------
    for (int idx = tid; idx < 16 * 32; idx += 256) {
        int r = idx >> 5, c4 = (idx & 31) << 2;
        float4 v = *(const float4*)&s_ptr[r][c4];
        *(uint2*)&s_nfB[r][c4] = pack4bf(v);
    }
    __syncthreads();

    const int w    = tid >> 6;
    const int l    = tid & 63;
    const int rowA = l & 15;
    const int kg   = l >> 4;
    const int col  = l & 15;
    const int rgrp = l >> 4;

    // ---- phase 0a: Q = nf @ Wq^T + bq (wave w: cols w*32..w*32+32) ----------
    {
        const int n0 = w * 32;
        f32x4 q0 = {0.f,0.f,0.f,0.f}, q1 = {0.f,0.f,0.f,0.f};
        #pragma unroll
        for (int kt = 0; kt < 4; ++kt) {
            int ko = kt * 32 + kg * 8;
            bf16x8 av = ldfrag(&s_nfB[rowA][ko]);
            q0 = MFMA(av, ldfrag(&Wqb[(size_t)(n0 + rowA) * 128 + ko]),      q0);
            q1 = MFMA(av, ldfrag(&Wqb[(size_t)(n0 + 16 + rowA) * 128 + ko]), q1);
        }
        float bb0 = bq[n0 + col], bb1 = bq[n0 + 16 + col];
        #pragma unroll
        for (int rgi = 0; rgi < 4; ++rgi) {
            int rr = rgrp * 4 + rgi;
            s_qB[rr][n0 + col]      = f2bf(q0[rgi] + bb0);
            s_qB[rr][n0 + 16 + col] = f2bf(q1[rgi] + bb1);
        }
    }
    __syncthreads();

    // ---- phase 0b: qb[r][h] = Q_h . bk_h  (128 threads) ---------------------
    if (tid < 128) {
        int r = tid >> 3, rem = tid & 7, h = rem >> 2, p = rem & 3;
        float part = 0.f;
        #pragma unroll
        for (int j = 0; j < 16; ++j) {
            int dd = h * 64 + p * 16 + j;
            part += bf2f(s_qB[r][dd]) * bk[dd];
        }
        part += __shfl_xor(part, 1);
        part += __shfl_xor(part, 2);
        if (p == 0) s_qb[r][h] = part;
    }

    // ---- phase 0c: u = Wk_h^T Q_h (wave w: head w>>1, cols (w&1)*96) --------
    {
        const int h  = w >> 1;
        const int cb = (w & 1) * 96;
        f32x4 u[6];
        #pragma unroll
        for (int ct = 0; ct < 6; ++ct) u[ct] = (f32x4){0.f,0.f,0.f,0.f};
        #pragma unroll
        for (int kt = 0; kt < 2; ++kt) {
            int ko = kt * 32 + kg * 8;
            bf16x8 av = ldfrag(&s_qB[rowA][h * 64 + ko]);
            #pragma unroll
            for (int ct = 0; ct < 6; ++ct) {
                bf16x8 bfr = ldfrag(&WkTb[(size_t)h * 12288 + (size_t)(cb + ct * 16 + rowA) * 64 + ko]);
                u[ct] = MFMA(av, bfr, u[ct]);
            }
        }
        #pragma unroll
        for (int ct = 0; ct < 6; ++ct)
            #pragma unroll
            for (int rgi = 0; rgi < 4; ++rgi) {
                int rr = rgrp * 4 + rgi;
                s_u[rr][h][cb + ct * 16 + col] = f2bf(u[ct][rgi]);
            }
    }
    __syncthreads();

    // ---- phase A: per-wave 4 rows, wave-private, reg-prefetched gather ------
    {
        unsigned short (*kvbuf)[16][200] = (unsigned short (*)[16][200])s_pool64;
        float wt = w_ta[l], bt = b_ta[l];
        const int pfn = l >> 5;            // this lane's neighbor parity
        const int pfc = (l & 31) << 2;     // this lane's 4-col base

        float4 pf[8];
        {
            const int r = w * 4;
            #pragma unroll
            for (int it = 0; it < 8; ++it)
                pf[it] = *(const float4*)&s_nptr[r][it * 2 + pfn][pfc];
        }

        for (int rr = 0; rr < 4; ++rr) {
            const int r = w * 4 + rr;
            // write prefetched kv rows to LDS (bf16, packed)
            #pragma unroll
            for (int it = 0; it < 8; ++it)
                *(uint2*)&kvbuf[w][it * 2 + pfn][pfc] = pack4bf(pf[it]);
            // time encoding
            #pragma unroll
            for (int n = 0; n < 16; ++n) {
                float f = s_td[r][n] * wt + bt;
                kvbuf[w][n][128 + l] = f2bf((l & 1) ? cosf(f) : sinf(f));
            }
            // issue next row's gather now; latency hides under scores/kvbar
            if (rr < 3) {
                const int rn = r + 1;
                #pragma unroll
                for (int it = 0; it < 8; ++it)
                    pf[it] = *(const float4*)&s_nptr[rn][it * 2 + pfn][pfc];
            }
            __builtin_amdgcn_wave_barrier();

            // scores + masked softmax (wave-internal)
            {
                int h = (l >> 4) & 1, n = l & 15, half = l >> 5;
                float acc = (half == 0) ? s_qb[r][h] : 0.f;
                const unsigned short* kvrow = &kvbuf[w][n][half * 96];
                const unsigned short* urow  = &s_u[r][h][half * 96];
                #pragma unroll
                for (int k = 0; k < 96; k += 8) {
                    s16x8 kv8 = *(const s16x8*)&kvrow[k];
                    s16x8 u8  = *(const s16x8*)&urow[k];
                    #pragma unroll
                    for (int j = 0; j < 8; ++j)
                        acc += bf2f((unsigned short)kv8[j]) * bf2f((unsigned short)u8[j]);
                }
                acc += __shfl_xor(acc, 32);
                int mk = s_mk[r][n];
                float s = mk ? acc * 0.125f : -INFINITY;
                float mx = s;
                #pragma unroll
                for (int m = 1; m < 16; m <<= 1) mx = fmaxf(mx, __shfl_xor(mx, m));
                float p = (mk && mx > -1e37f) ? expf(s - mx) : 0.f;
                float den = p;
                #pragma unroll
                for (int m = 1; m < 16; m <<= 1) den += __shfl_xor(den, m);
                float a = (den > 0.f) ? (p / den) : 0.f;
                if (l < 32) s_at[w][h][n] = a;
                if (l == 0 || l == 16) s_satt[r][h] = (den > 0.f) ? 1.f : 0.f;
            }
            __builtin_amdgcn_wave_barrier();

            // kvbar[h][c] = sum_n at[h][n] * kv[n][c]  -> s_kvb (bf16)
            #pragma unroll
            for (int i = 0; i < 3; ++i) {
                int c = i * 64 + l;
                float k0 = 0.f, k1 = 0.f;
                #pragma unroll
                for (int n = 0; n < 16; ++n) {
                    float v = bf2f(kvbuf[w][n][c]);
                    k0 += s_at[w][0][n] * v;
                    k1 += s_at[w][1][n] * v;
                }
                s_kvb[r][0][c] = f2bf(k0);
                s_kvb[r][1][c] = f2bf(k1);
            }
            __builtin_amdgcn_wave_barrier();
        }
    }
    __syncthreads();

    // ---- phase B: MFMA back-end (pool aliased: kv staging is dead) ----------
    unsigned short (*s_aoB)[136] = (unsigned short (*)[136])s_pool64;
    unsigned short (*s_oB )[136] = (unsigned short (*)[136])((char*)s_pool64 + 4352);
    unsigned short (*s_h1B)[136] = (unsigned short (*)[136])((char*)s_pool64 + 8704);
    float          (*s_h2 )[128] = (float          (*)[128])((char*)s_pool64 + 13056);

    // out = Wv_h @ kvbar_h + satt_h*bv : wave w -> head w>>1, cols (w&1)*32
    {
        const int h  = w >> 1;
        const int c0 = (w & 1) * 32;
        f32x4 o0 = {0.f,0.f,0.f,0.f}, o1 = {0.f,0.f,0.f,0.f};
        #pragma unroll
        for (int kt = 0; kt < 6; ++kt) {
            int ko = kt * 32 + kg * 8;
            bf16x8 av = ldfrag(&s_kvb[rowA][h][ko]);
            o0 = MFMA(av, ldfrag(&Wvb[(size_t)(h * 64 + c0 + rowA) * 192 + ko]),      o0);
            o1 = MFMA(av, ldfrag(&Wvb[(size_t)(h * 64 + c0 + 16 + rowA) * 192 + ko]), o1);
        }
        int d0 = h * 64 + c0 + col, d1 = d0 + 16;
        float bv0 = bv[d0], bv1 = bv[d1];
        #pragma unroll
        for (int rgi = 0; rgi < 4; ++rgi) {
            int rr = rgrp * 4 + rgi;
            s_oB[rr][d0] = f2bf(o0[rgi] + s_satt[rr][h] * bv0);
            s_oB[rr][d1] = f2bf(o1[rgi] + s_satt[rr][h] * bv1);
        }
    }
    __syncthreads();

    // ao = Wo @ out + bo
    {
        const int n0 = w * 32;
        f32x4 a0 = {0.f,0.f,0.f,0.f}, a1 = {0.f,0.f,0.f,0.f};
        #pragma unroll
        for (int kt = 0; kt < 4; ++kt) {
            int ko = kt * 32 + kg * 8;
            bf16x8 av = ldfrag(&s_oB[rowA][ko]);
            a0 = MFMA(av, ldfrag(&Wob[(size_t)(n0 + rowA) * 128 + ko]),      a0);
            a1 = MFMA(av, ldfrag(&Wob[(size_t)(n0 + 16 + rowA) * 128 + ko]), a1);
        }
        float bb0 = bo[n0 + col], bb1 = bo[n0 + 16 + col];
        #pragma unroll
        for (int rgi = 0; rgi < 4; ++rgi) {
            int rr = rgrp * 4 + rgi;
            s_aoB[rr][n0 + col]      = f2bf(a0[rgi] + bb0);
            s_aoB[rr][n0 + 16 + col] = f2bf(a1[rgi] + bb1);
        }
    }
    __syncthreads();

    // h1 = relu(Wm1 @ [ao|nf] + bm1), K=256 (kt 0..3: ao, kt 4..7: nf)
    {
        const int n0 = w * 32;
        f32x4 a0 = {0.f,0.f,0.f,0.f}, a1 = {0.f,0.f,0.f,0.f};
        #pragma unroll
        for (int kt = 0; kt < 8; ++kt) {
            int ko = kt * 32 + kg * 8;
            bf16x8 av = (kt < 4) ? ldfrag(&s_aoB[rowA][ko])
                                 : ldfrag(&s_nfB[rowA][ko - 128]);
            a0 = MFMA(av, ldfrag(&Wm1b[(size_t)(n0 + rowA) * 256 + ko]),      a0);
            a1 = MFMA(av, ldfrag(&Wm1b[(size_t)(n0 + 16 + rowA) * 256 + ko]), a1);
        }
        float bb0 = bm1[n0 + col], bb1 = bm1[n0 + 16 + col];
        #pragma unroll
        for (int rgi = 0; rgi < 4; ++rgi) {
            int rr = rgrp * 4 + rgi;
            s_h1B[rr][n0 + col]      = f2bf(fmaxf(a0[rgi] + bb0, 0.f));
            s_h1B[rr][n0 + 16 + col] = f2bf(fmaxf(a1[rgi] + bb1, 0.f));
        }
    }
    __syncthreads();

    // h2 = Wm2 @ h1 + bm2 -> f32
    {
        const int n0 = w * 32;
        f32x4 a0 = {0.f,0.f,0.f,0.f}, a1 = {0.f,0.f,0.f,0.f};
        #pragma unroll
        for (int kt = 0; kt < 4; ++kt) {
            int ko = kt * 32 + kg * 8;
            bf16x8 av = ldfrag(&s_h1B[rowA][ko]);
            a0 = MFMA(av, ldfrag(&Wm2b[(size_t)(n0 + rowA) * 128 + ko]),      a0);
            a1 = MFMA(av, ldfrag(&Wm2b[(size_t)(n0 + 16 + rowA) * 128 + ko]), a1);
        }
        float bb0 = bm2[n0 + col], bb1 = bm2[n0 + 16 + col];
        #pragma unroll
        for (int rgi = 0; rgi < 4; ++rgi) {
            int rr = rgrp * 4 + rgi;
            s_h2[rr][n0 + col]      = a0[rgi] + bb0;
            s_h2[rr][n0 + 16 + col] = a1[rgi] + bb1;
        }
    }
    __syncthreads();

    // LayerNorm: wave w -> rows w*4 .. w*4+3
    {
        float lg0 = ln_g[l], lg1 = ln_g[64 + l];
        float lb0 = ln_b[l], lb1 = ln_b[64 + l];
        #pragma unroll
        for (int i = 0; i < 4; ++i) {
            int r = w * 4 + i;
            float v0 = s_h2[r][l], v1 = s_h2[r][64 + l];
            float sum = v0 + v1;
            #pragma unroll
            for (int m = 1; m < 64; m <<= 1) sum += __shfl_xor(sum, m);
            float mean = sum * (1.f / 128.f);
            float e0 = v0 - mean, e1 = v1 - mean;
            float sq = e0 * e0 + e1 * e1;
            #pragma unroll
            for (int m = 1; m < 64; m <<= 1) sq += __shfl_xor(sq, m);
            float inv = rsqrtf(sq * (1.f / 128.f) + 1e-5f);
            out[(size_t)(base + r) * DIM + l]      = e0 * inv * lg0 + lb0;
            out[(size_t)(base + r) * DIM + 64 + l] = e1 * inv * lg1 + lb1;
        }
    }
}

// ---------------------------------------------------------------------------
extern "C" void kernel_launch(void* const* d_in, const int* in_sizes, int n_in,
                              void* d_out, int out_size, void* d_ws, size_t ws_size,
                              hipStream_t stream) {
    const int*   src         = (const int*)  d_in[0];
    const int*   dst         = (const int*)  d_in[1];
    const float* ts          = (const float*)d_in[2];
    const int*   nbr_ids     = (const int*)  d_in[3];
    const float* nbr_ts      = (const float*)d_in[4];
    const float* memory      = (const float*)d_in[5];
    const float* last_update = (const float*)d_in[6];
    const float* w_t_msg     = (const float*)d_in[7];
    const float* b_t_msg     = (const float*)d_in[8];
    const float* W_msg1      = (const float*)d_in[9];
    const float* b_msg1      = (const float*)d_in[10];
    const float* W_msg2      = (const float*)d_in[11];
    const float* b_msg2      = (const float*)d_in[12];
    const float* W_ih        = (const float*)d_in[13];
    const float* b_ih        = (const float*)d_in[14];
    const float* W_hh        = (const float*)d_in[15];
    const float* b_hh        = (const float*)d_in[16];
    const float* w_t_att     = (const float*)d_in[17];
    const float* b_t_att     = (const float*)d_in[18];
    const float* Wq          = (const float*)d_in[19];
    const float* bq          = (const float*)d_in[20];
    const float* Wk          = (const float*)d_in[21];
    const float* bk          = (const float*)d_in[22];
    const float* Wv          = (const float*)d_in[23];
    const float* bv          = (const float*)d_in[24];
    const float* Wo          = (const float*)d_in[25];
    const float* bo          = (const float*)d_in[26];
    const float* Wm1         = (const float*)d_in[27];
    const float* bm1         = (const float*)d_in[28];
    const float* Wm2         = (const float*)d_in[29];
    const float* bm2         = (const float*)d_in[30];
    const float* ln_g        = (const float*)d_in[31];
    const float* ln_b        = (const float*)d_in[32];
    float* out = (float*)d_out;

    char* ws = (char*)d_ws;
    size_t off = 0;
    float* new_mem = (float*)(ws + off); off += (size_t)2 * BATCH * DIM * 4;   // 8 MiB
    int*   winner  = (int*)  (ws + off); off += 2097152;                       // 2 MiB
    int*   sel_id  = (int*)  (ws + off); off += (size_t)BATCH * KSEL * 4;
    float* sel_td  = (float*)(ws + off); off += (size_t)BATCH * KSEL * 4;
    int*   sel_mk  = (int*)  (ws + off); off += (size_t)BATCH * KSEL * 4;
    unsigned short* Wpool = (unsigned short*)(ws + off); off += (size_t)CVT_TOT * 2;

    hipMemsetAsync(winner, 0xFF, NNODES * sizeof(int), stream);
    k_prep<<<NB_TOPK, 256, 0, stream>>>(
        W_msg1, W_msg2, W_ih, W_hh, Wq, Wv, Wo, Wm1, Wm2, Wk, Wpool,
        src, dst, winner, ts, nbr_ids, nbr_ts, sel_id, sel_td, sel_mk);
    k1_mfma<<<(2 * BATCH) / 32, 512, 0, stream>>>(
        src, dst, ts, memory, last_update,
        w_t_msg, b_t_msg, Wpool, b_msg1, b_msg2, b_ih, b_hh, new_mem);
    k3_fused<<<BATCH / 16, 256, 0, stream>>>(
        src, memory, new_mem, winner, sel_id, sel_td, sel_mk,
        w_t_att, b_t_att, Wpool, bq, bk, bv, bo, bm1, bm2, ln_g, ln_b, out);
}

// Round 8
// 87.835 us; speedup vs baseline: 8.8069x; 1.0573x over previous
//
#include <hip/hip_runtime.h>
#include <math.h>

#define BATCH  8192
#define NNODES 500000
#define DIM    128
#define TDIM   64
#define KNB    32
#define KSEL   16

// bf16 weight pool element offsets
#define OFF_W1   0
#define OFF_W2   40960
#define OFF_WIH  57344
#define OFF_WHH  106496
#define OFF_WQ   155648
#define OFF_WV   172032
#define OFF_WO   196608
#define OFF_WM1  212992
#define OFF_WM2  245760
#define OFF_WKT  262144
#define CVT_TOT  286720

// prep kernel block ranges
#define NB_CVT  1120                  // CVT_TOT / 256 exactly
#define NB_WIN  (NB_CVT + 64)         // 16384 threads for winner scatter
#define NB_TOPK (NB_WIN + 32)         // 8192 threads for top-k

typedef float  f32x4  __attribute__((ext_vector_type(4)));
typedef __bf16 bf16x8 __attribute__((ext_vector_type(8)));
typedef short  s16x8  __attribute__((ext_vector_type(8)));

#define MFMA(a,b,c) __builtin_amdgcn_mfma_f32_16x16x32_bf16(a,b,c,0,0,0)

__device__ __forceinline__ float sigmoidf_(float x) { return 1.f / (1.f + expf(-x)); }
__device__ __forceinline__ unsigned short f2bf(float x) {
    unsigned u = __builtin_bit_cast(unsigned, x);
    unsigned r = (u + 0x7FFFu + ((u >> 16) & 1u)) >> 16;
    return (unsigned short)r;
}
__device__ __forceinline__ float bf2f(unsigned short u) {
    unsigned v = ((unsigned)u) << 16;
    return __builtin_bit_cast(float, v);
}
__device__ __forceinline__ bf16x8 ldfrag(const unsigned short* p) {
    s16x8 v = *(const s16x8*)p;
    return __builtin_bit_cast(bf16x8, v);
}
__device__ __forceinline__ uint2 pack4bf(float4 v) {
    uint2 pk;
    pk.x = (unsigned)f2bf(v.x) | ((unsigned)f2bf(v.y) << 16);
    pk.y = (unsigned)f2bf(v.z) | ((unsigned)f2bf(v.w) << 16);
    return pk;
}

// ---------------------------------------------------------------------------
// K_prep: [0,NB_CVT) weight->bf16 pool | [NB_CVT,NB_WIN) winner scatter |
//         [NB_WIN,NB_TOPK) temporal top-16-of-32.
// ---------------------------------------------------------------------------
__global__ __launch_bounds__(256) void k_prep(
    const float* __restrict__ sW1, const float* __restrict__ sW2,
    const float* __restrict__ sWih, const float* __restrict__ sWhh,
    const float* __restrict__ sWq, const float* __restrict__ sWv,
    const float* __restrict__ sWo, const float* __restrict__ sWm1,
    const float* __restrict__ sWm2, const float* __restrict__ sWk,
    unsigned short* __restrict__ pool,
    const int* __restrict__ src, const int* __restrict__ dst,
    int* __restrict__ winner,
    const float* __restrict__ ts,
    const int* __restrict__ nbr_ids, const float* __restrict__ nbr_ts,
    int* __restrict__ sel_id, float* __restrict__ sel_td, int* __restrict__ sel_mk)
{
    const int bid = blockIdx.x;
    const int tid = threadIdx.x;

    if (bid < NB_CVT) {
        int i = bid * 256 + tid;
        float v;
        if      (i < OFF_W2)  { v = sW1 [i - OFF_W1 ]; }
        else if (i < OFF_WIH) { v = sW2 [i - OFF_W2 ]; }
        else if (i < OFF_WHH) { v = sWih[i - OFF_WIH]; }
        else if (i < OFF_WQ)  { v = sWhh[i - OFF_WHH]; }
        else if (i < OFF_WV)  { v = sWq [i - OFF_WQ ]; }
        else if (i < OFF_WO)  { v = sWv [i - OFF_WV ]; }
        else if (i < OFF_WM1) { v = sWo [i - OFF_WO ]; }
        else if (i < OFF_WM2) { v = sWm1[i - OFF_WM1]; }
        else if (i < OFF_WKT) { v = sWm2[i - OFF_WM2]; }
        else {
            int j = i - OFF_WKT;           // h*12288 + c*64 + dh
            int h = j / 12288, rem = j % 12288;
            int c = rem >> 6, dh = rem & 63;
            v = sWk[(size_t)(h * 64 + dh) * 192 + c];
        }
        pool[i] = f2bf(v);
        return;
    }
    if (bid < NB_WIN) {
        int i = (bid - NB_CVT) * 256 + tid;
        if (i < 2 * BATCH) {
            int v = (i < BATCH) ? src[i] : dst[i - BATCH];
            atomicMax(&winner[v], i);
        }
        return;
    }
    {
        int b = (bid - NB_WIN) * 256 + tid;
        if (b >= BATCH) return;
        int   s = src[b];
        float t = ts[b];
        const int*   ip = nbr_ids + (size_t)s * KNB;
        const float* tp = nbr_ts  + (size_t)s * KNB;
        float kt[KNB]; int kid[KNB];
        #pragma unroll
        for (int j = 0; j < KNB; ++j) {
            int id = ip[j]; float nt = tp[j];
            bool valid = (id >= 0) && (nt < t + 1e-6f);
            kt[j]  = valid ? nt : -1e30f;
            kid[j] = id;
        }
        unsigned picked = 0u;
        for (int sI = 0; sI < KSEL; ++sI) {
            float bv = -3.4e38f; int bj = 0; int bid2 = 0;
            #pragma unroll
            for (int j = 0; j < KNB; ++j) {
                bool avail = !((picked >> j) & 1u);
                if (avail && kt[j] > bv) { bv = kt[j]; bj = j; bid2 = kid[j]; }
            }
            picked |= (1u << bj);
            bool mk = bv > -1e29f;
            int id = mk ? (bid2 < 0 ? 0 : (bid2 > NNODES - 1 ? NNODES - 1 : bid2)) : 0;
            sel_id[b * KSEL + sI] = id;
            sel_td[b * KSEL + sI] = mk ? (t - bv) : 0.f;
            sel_mk[b * KSEL + sI] = mk ? 1 : 0;
        }
    }
}

// ---------------------------------------------------------------------------
// K1 (MFMA): message MLP + GRU. 64 rows/block, 8 waves (512 thr).
// Wave w owns output cols [w*16, w*16+16); 4 A-tiles per wave.
// ---------------------------------------------------------------------------
__global__ __launch_bounds__(512) void k1_mfma(
    const int* __restrict__ src, const int* __restrict__ dst, const float* __restrict__ ts,
    const float* __restrict__ memory, const float* __restrict__ last_update,
    const float* __restrict__ w_t, const float* __restrict__ b_t,
    const unsigned short* __restrict__ Wp,
    const float* __restrict__ b1, const float* __restrict__ b2,
    const float* __restrict__ bih, const float* __restrict__ bhh,
    float* __restrict__ new_mem)
{
    __shared__ unsigned short sxb[64][328];   // [self|oth|te] bf16, pad 8
    __shared__ unsigned short hb [64][136];   // h1 then msg
    __shared__ int   s_node[64];
    __shared__ int   s_oth [64];
    __shared__ float s_dt  [64];

    const unsigned short* W1b  = Wp + OFF_W1;
    const unsigned short* W2b  = Wp + OFF_W2;
    const unsigned short* Wihb = Wp + OFF_WIH;
    const unsigned short* Whhb = Wp + OFF_WHH;

    const int tid  = threadIdx.x;
    const int base = blockIdx.x * 64;

    if (tid < 64) {
        int gi = base + tid;
        int node, oth; float t;
        if (gi < BATCH) { node = src[gi];         oth = dst[gi];         t = ts[gi]; }
        else            { node = dst[gi - BATCH]; oth = src[gi - BATCH]; t = ts[gi - BATCH]; }
        s_node[tid] = node;
        s_oth[tid]  = oth;
        s_dt[tid]   = t - last_update[node];
    }
    __syncthreads();

    for (int idx = tid; idx < 64 * 32; idx += 512) {
        int r = idx >> 5, c4 = (idx & 31) << 2;
        float4 vs = *(const float4*)&memory[(size_t)s_node[r] * DIM + c4];
        float4 vo = *(const float4*)&memory[(size_t)s_oth[r]  * DIM + c4];
        *(uint2*)&sxb[r][c4]       = pack4bf(vs);
        *(uint2*)&sxb[r][128 + c4] = pack4bf(vo);
    }
    for (int idx = tid; idx < 64 * TDIM; idx += 512) {
        int r = idx >> 6, c = idx & 63;
        float f = s_dt[r] * w_t[c] + b_t[c];
        sxb[r][256 + c] = f2bf((c & 1) ? cosf(f) : sinf(f));
    }
    __syncthreads();

    const int w    = tid >> 6;        // 0..7
    const int l    = tid & 63;
    const int rowA = l & 15;
    const int kg   = l >> 4;
    const int n0   = w * 16;
    const int col  = l & 15;
    const int rgrp = l >> 4;

    // ---- stage 1: h1 = relu(x @ W1^T + b1), K=320 ---------------------------
    {
        f32x4 a0 = {0.f,0.f,0.f,0.f}, a1 = {0.f,0.f,0.f,0.f};
        f32x4 a2 = {0.f,0.f,0.f,0.f}, a3 = {0.f,0.f,0.f,0.f};
        #pragma unroll
        for (int kt = 0; kt < 10; ++kt) {
            int ko = kt * 32 + kg * 8;
            bf16x8 bfr = ldfrag(&W1b[(size_t)(n0 + rowA) * 320 + ko]);
            a0 = MFMA(ldfrag(&sxb[     rowA][ko]), bfr, a0);
            a1 = MFMA(ldfrag(&sxb[16 + rowA][ko]), bfr, a1);
            a2 = MFMA(ldfrag(&sxb[32 + rowA][ko]), bfr, a2);
            a3 = MFMA(ldfrag(&sxb[48 + rowA][ko]), bfr, a3);
        }
        float bb = b1[n0 + col];
        #pragma unroll
        for (int rgi = 0; rgi < 4; ++rgi) {
            int rb = rgrp * 4 + rgi;
            hb[rb     ][n0 + col] = f2bf(fmaxf(a0[rgi] + bb, 0.f));
            hb[rb + 16][n0 + col] = f2bf(fmaxf(a1[rgi] + bb, 0.f));
            hb[rb + 32][n0 + col] = f2bf(fmaxf(a2[rgi] + bb, 0.f));
            hb[rb + 48][n0 + col] = f2bf(fmaxf(a3[rgi] + bb, 0.f));
        }
    }
    __syncthreads();

    // ---- stage 2: msg = h1 @ W2^T + b2, K=128 -------------------------------
    {
        f32x4 m0 = {0.f,0.f,0.f,0.f}, m1 = {0.f,0.f,0.f,0.f};
        f32x4 m2 = {0.f,0.f,0.f,0.f}, m3 = {0.f,0.f,0.f,0.f};
        #pragma unroll
        for (int kt = 0; kt < 4; ++kt) {
            int ko = kt * 32 + kg * 8;
            bf16x8 bfr = ldfrag(&W2b[(size_t)(n0 + rowA) * 128 + ko]);
            m0 = MFMA(ldfrag(&hb[     rowA][ko]), bfr, m0);
            m1 = MFMA(ldfrag(&hb[16 + rowA][ko]), bfr, m1);
            m2 = MFMA(ldfrag(&hb[32 + rowA][ko]), bfr, m2);
            m3 = MFMA(ldfrag(&hb[48 + rowA][ko]), bfr, m3);
        }
        __syncthreads();   // all h1 reads done before overwrite
        float bb = b2[n0 + col];
        #pragma unroll
        for (int rgi = 0; rgi < 4; ++rgi) {
            int rb = rgrp * 4 + rgi;
            hb[rb     ][n0 + col] = f2bf(m0[rgi] + bb);
            hb[rb + 16][n0 + col] = f2bf(m1[rgi] + bb);
            hb[rb + 32][n0 + col] = f2bf(m2[rgi] + bb);
            hb[rb + 48][n0 + col] = f2bf(m3[rgi] + bb);
        }
    }
    __syncthreads();

    // ---- stage 3: GRU gates, one 16-col pass per wave, 4 A-tiles ------------
    {
        f32x4 g[6][4];
        #pragma unroll
        for (int gi_ = 0; gi_ < 6; ++gi_)
            #pragma unroll
            for (int ta = 0; ta < 4; ++ta) g[gi_][ta] = (f32x4){0.f,0.f,0.f,0.f};
        #pragma unroll
        for (int kt = 0; kt < 4; ++kt) {
            int ko = kt * 32 + kg * 8;
            int br = n0 + rowA;
            bf16x8 bir = ldfrag(&Wihb[(size_t)(      br) * 128 + ko]);
            bf16x8 biz = ldfrag(&Wihb[(size_t)(128 + br) * 128 + ko]);
            bf16x8 big = ldfrag(&Wihb[(size_t)(256 + br) * 128 + ko]);
            bf16x8 bhr = ldfrag(&Whhb[(size_t)(      br) * 128 + ko]);
            bf16x8 bhz = ldfrag(&Whhb[(size_t)(128 + br) * 128 + ko]);
            bf16x8 bhg = ldfrag(&Whhb[(size_t)(256 + br) * 128 + ko]);
            #pragma unroll
            for (int ta = 0; ta < 4; ++ta) {
                bf16x8 am = ldfrag(&hb [ta * 16 + rowA][ko]);
                bf16x8 ah = ldfrag(&sxb[ta * 16 + rowA][ko]);
                g[0][ta] = MFMA(am, bir, g[0][ta]);
                g[1][ta] = MFMA(am, biz, g[1][ta]);
                g[2][ta] = MFMA(am, big, g[2][ta]);
                g[3][ta] = MFMA(ah, bhr, g[3][ta]);
                g[4][ta] = MFMA(ah, bhz, g[4][ta]);
                g[5][ta] = MFMA(ah, bhg, g[5][ta]);
            }
        }
        const int d = n0 + col;
        float bir = bih[d], biz = bih[128 + d], big = bih[256 + d];
        float bhr = bhh[d], bhz = bhh[128 + d], bhg = bhh[256 + d];
        #pragma unroll
        for (int ta = 0; ta < 4; ++ta)
            #pragma unroll
            for (int rgi = 0; rgi < 4; ++rgi) {
                int rr = ta * 16 + rgrp * 4 + rgi;
                float rv = sigmoidf_((g[0][ta][rgi] + bir) + (g[3][ta][rgi] + bhr));
                float zv = sigmoidf_((g[1][ta][rgi] + biz) + (g[4][ta][rgi] + bhz));
                float gv = tanhf((g[2][ta][rgi] + big) + rv * (g[5][ta][rgi] + bhg));
                float selfv = bf2f(sxb[rr][d]);
                new_mem[(size_t)(base + rr) * DIM + d] = (1.f - zv) * gv + zv * selfv;
            }
    }
}

// ---------------------------------------------------------------------------
// K3 fused: 32 rows/block, 8 waves (512 thr). Q/u proj (MFMA) -> per-wave
// gather+scores+softmax+kvbar (wave-private, reg-prefetch) -> Wv/Wo/Wm1/Wm2
// MFMA back-end + LayerNorm.
// ---------------------------------------------------------------------------
__global__ __launch_bounds__(512) void k3_fused(
    const int* __restrict__ src,
    const float* __restrict__ memory, const float* __restrict__ new_mem,
    const int* __restrict__ winner,
    const int* __restrict__ sel_id, const float* __restrict__ sel_td,
    const int* __restrict__ sel_mk,
    const float* __restrict__ w_ta, const float* __restrict__ b_ta,
    const unsigned short* __restrict__ Wp,
    const float* __restrict__ bq, const float* __restrict__ bk,
    const float* __restrict__ bv, const float* __restrict__ bo,
    const float* __restrict__ bm1, const float* __restrict__ bm2,
    const float* __restrict__ ln_g, const float* __restrict__ ln_b,
    float* __restrict__ out)
{
    __shared__ unsigned short s_nfB[32][136];     // node features bf16
    __shared__ unsigned short s_qB [32][136];     // Q bf16
    __shared__ unsigned short s_u  [32][2][200];  // u = Wk_h^T Q_h, bf16
    __shared__ unsigned short s_kvb[32][2][200];  // kvbar bf16
    __shared__ unsigned long long s_pool64[6400]; // 51200B: kv staging / phase-B bufs
    __shared__ const float* s_nptr[32][16];
    __shared__ float s_td [32][16];
    __shared__ int   s_mk [32][16];
    __shared__ float s_qb [32][2];
    __shared__ float s_satt[32][2];
    __shared__ float s_at [8][2][16];
    __shared__ const float* s_ptr[32];

    const unsigned short* Wqb  = Wp + OFF_WQ;
    const unsigned short* WkTb = Wp + OFF_WKT;
    const unsigned short* Wvb  = Wp + OFF_WV;
    const unsigned short* Wob  = Wp + OFF_WO;
    const unsigned short* Wm1b = Wp + OFF_WM1;
    const unsigned short* Wm2b = Wp + OFF_WM2;

    const int tid  = threadIdx.x;
    const int base = blockIdx.x * 32;

    // ---- stage pointers + per-row neighbor metadata -------------------------
    if (tid < 32) {
        int v = src[base + tid];
        int wv = winner[v];
        s_ptr[tid] = (wv >= 0) ? (new_mem + (size_t)wv * DIM)
                               : (memory  + (size_t)v  * DIM);
    }
    {
        int r = tid >> 4, n = tid & 15;        // 512 threads = 32 rows x 16
        int id = sel_id[(base + r) * KSEL + n];
        int wi = winner[id];
        s_nptr[r][n] = (wi >= 0) ? (new_mem + (size_t)wi * DIM)
                                 : (memory  + (size_t)id * DIM);
        s_td[r][n] = sel_td[(base + r) * KSEL + n];
        s_mk[r][n] = sel_mk[(base + r) * KSEL + n];
    }
    __syncthreads();

    // ---- gather node features -> s_nfB --------------------------------------
    for (int idx = tid; idx < 32 * 32; idx += 512) {
        int r = idx >> 5, c4 = (idx & 31) << 2;
        float4 v = *(const float4*)&s_ptr[r][c4];
        *(uint2*)&s_nfB[r][c4] = pack4bf(v);
    }
    __syncthreads();

    const int w    = tid >> 6;        // 0..7
    const int l    = tid & 63;
    const int rowA = l & 15;
    const int kg   = l >> 4;
    const int col  = l & 15;
    const int rgrp = l >> 4;

    // ---- phase 0a: Q = nf @ Wq^T + bq (wave w: cols w*16..w*16+16) ----------
    {
        const int n0 = w * 16;
        f32x4 q0 = {0.f,0.f,0.f,0.f}, q1 = {0.f,0.f,0.f,0.f};
        #pragma unroll
        for (int kt = 0; kt < 4; ++kt) {
            int ko = kt * 32 + kg * 8;
            bf16x8 bfr = ldfrag(&Wqb[(size_t)(n0 + rowA) * 128 + ko]);
            q0 = MFMA(ldfrag(&s_nfB[     rowA][ko]), bfr, q0);
            q1 = MFMA(ldfrag(&s_nfB[16 + rowA][ko]), bfr, q1);
        }
        float bb = bq[n0 + col];
        #pragma unroll
        for (int rgi = 0; rgi < 4; ++rgi) {
            int rb = rgrp * 4 + rgi;
            s_qB[rb     ][n0 + col] = f2bf(q0[rgi] + bb);
            s_qB[rb + 16][n0 + col] = f2bf(q1[rgi] + bb);
        }
    }
    __syncthreads();

    // ---- phase 0b: qb[r][h] = Q_h . bk_h  (256 threads) ---------------------
    if (tid < 256) {
        int r = tid >> 3, rem = tid & 7, h = rem >> 2, p = rem & 3;
        float part = 0.f;
        #pragma unroll
        for (int j = 0; j < 16; ++j) {
            int dd = h * 64 + p * 16 + j;
            part += bf2f(s_qB[r][dd]) * bk[dd];
        }
        part += __shfl_xor(part, 1);
        part += __shfl_xor(part, 2);
        if (p == 0) s_qb[r][h] = part;
    }

    // ---- phase 0c: u = Wk_h^T Q_h (wave w: head w>>2, cols (w&3)*48) --------
    {
        const int h  = w >> 2;
        const int cb = (w & 3) * 48;
        f32x4 u[3][2];
        #pragma unroll
        for (int ct = 0; ct < 3; ++ct)
            #pragma unroll
            for (int ta = 0; ta < 2; ++ta) u[ct][ta] = (f32x4){0.f,0.f,0.f,0.f};
        #pragma unroll
        for (int kt = 0; kt < 2; ++kt) {
            int ko = kt * 32 + kg * 8;
            bf16x8 bfr[3];
            #pragma unroll
            for (int ct = 0; ct < 3; ++ct)
                bfr[ct] = ldfrag(&WkTb[(size_t)h * 12288 + (size_t)(cb + ct * 16 + rowA) * 64 + ko]);
            #pragma unroll
            for (int ta = 0; ta < 2; ++ta) {
                bf16x8 av = ldfrag(&s_qB[ta * 16 + rowA][h * 64 + ko]);
                #pragma unroll
                for (int ct = 0; ct < 3; ++ct)
                    u[ct][ta] = MFMA(av, bfr[ct], u[ct][ta]);
            }
        }
        #pragma unroll
        for (int ct = 0; ct < 3; ++ct)
            #pragma unroll
            for (int ta = 0; ta < 2; ++ta)
                #pragma unroll
                for (int rgi = 0; rgi < 4; ++rgi) {
                    int rr = ta * 16 + rgrp * 4 + rgi;
                    s_u[rr][h][cb + ct * 16 + col] = f2bf(u[ct][ta][rgi]);
                }
    }
    __syncthreads();

    // ---- phase A: per-wave 4 rows, wave-private, reg-prefetched gather ------
    {
        unsigned short (*kvbuf)[16][200] = (unsigned short (*)[16][200])s_pool64;
        float wt = w_ta[l], bt = b_ta[l];
        const int pfn = l >> 5;            // this lane's neighbor parity
        const int pfc = (l & 31) << 2;     // this lane's 4-col base

        float4 pf[8];
        {
            const int r = w * 4;
            #pragma unroll
            for (int it = 0; it < 8; ++it)
                pf[it] = *(const float4*)&s_nptr[r][it * 2 + pfn][pfc];
        }

        for (int rr = 0; rr < 4; ++rr) {
            const int r = w * 4 + rr;
            // write prefetched kv rows to LDS (bf16, packed)
            #pragma unroll
            for (int it = 0; it < 8; ++it)
                *(uint2*)&kvbuf[w][it * 2 + pfn][pfc] = pack4bf(pf[it]);
            // time encoding
            #pragma unroll
            for (int n = 0; n < 16; ++n) {
                float f = s_td[r][n] * wt + bt;
                kvbuf[w][n][128 + l] = f2bf((l & 1) ? cosf(f) : sinf(f));
            }
            // issue next row's gather now; latency hides under scores/kvbar
            if (rr < 3) {
                const int rn = r + 1;
                #pragma unroll
                for (int it = 0; it < 8; ++it)
                    pf[it] = *(const float4*)&s_nptr[rn][it * 2 + pfn][pfc];
            }
            __builtin_amdgcn_wave_barrier();

            // scores + masked softmax (wave-internal)
            {
                int h = (l >> 4) & 1, n = l & 15, half = l >> 5;
                float acc = (half == 0) ? s_qb[r][h] : 0.f;
                const unsigned short* kvrow = &kvbuf[w][n][half * 96];
                const unsigned short* urow  = &s_u[r][h][half * 96];
                #pragma unroll
                for (int k = 0; k < 96; k += 8) {
                    s16x8 kv8 = *(const s16x8*)&kvrow[k];
                    s16x8 u8  = *(const s16x8*)&urow[k];
                    #pragma unroll
                    for (int j = 0; j < 8; ++j)
                        acc += bf2f((unsigned short)kv8[j]) * bf2f((unsigned short)u8[j]);
                }
                acc += __shfl_xor(acc, 32);
                int mk = s_mk[r][n];
                float s = mk ? acc * 0.125f : -INFINITY;
                float mx = s;
                #pragma unroll
                for (int m = 1; m < 16; m <<= 1) mx = fmaxf(mx, __shfl_xor(mx, m));
                float p = (mk && mx > -1e37f) ? expf(s - mx) : 0.f;
                float den = p;
                #pragma unroll
                for (int m = 1; m < 16; m <<= 1) den += __shfl_xor(den, m);
                float a = (den > 0.f) ? (p / den) : 0.f;
                if (l < 32) s_at[w][h][n] = a;
                if (l == 0 || l == 16) s_satt[r][h] = (den > 0.f) ? 1.f : 0.f;
            }
            __builtin_amdgcn_wave_barrier();

            // kvbar[h][c] = sum_n at[h][n] * kv[n][c]  -> s_kvb (bf16)
            #pragma unroll
            for (int i = 0; i < 3; ++i) {
                int c = i * 64 + l;
                float k0 = 0.f, k1 = 0.f;
                #pragma unroll
                for (int n = 0; n < 16; ++n) {
                    float v = bf2f(kvbuf[w][n][c]);
                    k0 += s_at[w][0][n] * v;
                    k1 += s_at[w][1][n] * v;
                }
                s_kvb[r][0][c] = f2bf(k0);
                s_kvb[r][1][c] = f2bf(k1);
            }
            __builtin_amdgcn_wave_barrier();
        }
    }
    __syncthreads();

    // ---- phase B: MFMA back-end (pool aliased: kv staging is dead) ----------
    unsigned short (*s_aoB)[136] = (unsigned short (*)[136])s_pool64;
    unsigned short (*s_oB )[136] = (unsigned short (*)[136])((char*)s_pool64 + 8704);
    unsigned short (*s_h1B)[136] = (unsigned short (*)[136])((char*)s_pool64 + 17408);
    float          (*s_h2 )[128] = (float          (*)[128])((char*)s_pool64 + 26112);

    // out = Wv_h @ kvbar_h + satt_h*bv : wave w -> head w>>2, cols (w&3)*16
    {
        const int h  = w >> 2;
        const int c0 = (w & 3) * 16;
        f32x4 o0 = {0.f,0.f,0.f,0.f}, o1 = {0.f,0.f,0.f,0.f};
        #pragma unroll
        for (int kt = 0; kt < 6; ++kt) {
            int ko = kt * 32 + kg * 8;
            bf16x8 bfr = ldfrag(&Wvb[(size_t)(h * 64 + c0 + rowA) * 192 + ko]);
            o0 = MFMA(ldfrag(&s_kvb[     rowA][h][ko]), bfr, o0);
            o1 = MFMA(ldfrag(&s_kvb[16 + rowA][h][ko]), bfr, o1);
        }
        int d0 = h * 64 + c0 + col;
        float bv0 = bv[d0];
        #pragma unroll
        for (int rgi = 0; rgi < 4; ++rgi) {
            int rb = rgrp * 4 + rgi;
            s_oB[rb     ][d0] = f2bf(o0[rgi] + s_satt[rb     ][h] * bv0);
            s_oB[rb + 16][d0] = f2bf(o1[rgi] + s_satt[rb + 16][h] * bv0);
        }
    }
    __syncthreads();

    // ao = Wo @ out + bo
    {
        const int n0 = w * 16;
        f32x4 a0 = {0.f,0.f,0.f,0.f}, a1 = {0.f,0.f,0.f,0.f};
        #pragma unroll
        for (int kt = 0; kt < 4; ++kt) {
            int ko = kt * 32 + kg * 8;
            bf16x8 bfr = ldfrag(&Wob[(size_t)(n0 + rowA) * 128 + ko]);
            a0 = MFMA(ldfrag(&s_oB[     rowA][ko]), bfr, a0);
            a1 = MFMA(ldfrag(&s_oB[16 + rowA][ko]), bfr, a1);
        }
        float bb = bo[n0 + col];
        #pragma unroll
        for (int rgi = 0; rgi < 4; ++rgi) {
            int rb = rgrp * 4 + rgi;
            s_aoB[rb     ][n0 + col] = f2bf(a0[rgi] + bb);
            s_aoB[rb + 16][n0 + col] = f2bf(a1[rgi] + bb);
        }
    }
    __syncthreads();

    // h1 = relu(Wm1 @ [ao|nf] + bm1), K=256 (kt 0..3: ao, kt 4..7: nf)
    {
        const int n0 = w * 16;
        f32x4 a0 = {0.f,0.f,0.f,0.f}, a1 = {0.f,0.f,0.f,0.f};
        #pragma unroll
        for (int kt = 0; kt < 8; ++kt) {
            int ko = kt * 32 + kg * 8;
            bf16x8 av0 = (kt < 4) ? ldfrag(&s_aoB[     rowA][ko])
                                  : ldfrag(&s_nfB[     rowA][ko - 128]);
            bf16x8 av1 = (kt < 4) ? ldfrag(&s_aoB[16 + rowA][ko])
                                  : ldfrag(&s_nfB[16 + rowA][ko - 128]);
            bf16x8 bfr = ldfrag(&Wm1b[(size_t)(n0 + rowA) * 256 + ko]);
            a0 = MFMA(av0, bfr, a0);
            a1 = MFMA(av1, bfr, a1);
        }
        float bb = bm1[n0 + col];
        #pragma unroll
        for (int rgi = 0; rgi < 4; ++rgi) {
            int rb = rgrp * 4 + rgi;
            s_h1B[rb     ][n0 + col] = f2bf(fmaxf(a0[rgi] + bb, 0.f));
            s_h1B[rb + 16][n0 + col] = f2bf(fmaxf(a1[rgi] + bb, 0.f));
        }
    }
    __syncthreads();

    // h2 = Wm2 @ h1 + bm2 -> f32
    {
        const int n0 = w * 16;
        f32x4 a0 = {0.f,0.f,0.f,0.f}, a1 = {0.f,0.f,0.f,0.f};
        #pragma unroll
        for (int kt = 0; kt < 4; ++kt) {
            int ko = kt * 32 + kg * 8;
            bf16x8 bfr = ldfrag(&Wm2b[(size_t)(n0 + rowA) * 128 + ko]);
            a0 = MFMA(ldfrag(&s_h1B[     rowA][ko]), bfr, a0);
            a1 = MFMA(ldfrag(&s_h1B[16 + rowA][ko]), bfr, a1);
        }
        float bb = bm2[n0 + col];
        #pragma unroll
        for (int rgi = 0; rgi < 4; ++rgi) {
            int rb = rgrp * 4 + rgi;
            s_h2[rb     ][n0 + col] = a0[rgi] + bb;
            s_h2[rb + 16][n0 + col] = a1[rgi] + bb;
        }
    }
    __syncthreads();

    // LayerNorm: wave w -> rows w*4 .. w*4+3
    {
        float lg0 = ln_g[l], lg1 = ln_g[64 + l];
        float lb0 = ln_b[l], lb1 = ln_b[64 + l];
        #pragma unroll
        for (int i = 0; i < 4; ++i) {
            int r = w * 4 + i;
            float v0 = s_h2[r][l], v1 = s_h2[r][64 + l];
            float sum = v0 + v1;
            #pragma unroll
            for (int m = 1; m < 64; m <<= 1) sum += __shfl_xor(sum, m);
            float mean = sum * (1.f / 128.f);
            float e0 = v0 - mean, e1 = v1 - mean;
            float sq = e0 * e0 + e1 * e1;
            #pragma unroll
            for (int m = 1; m < 64; m <<= 1) sq += __shfl_xor(sq, m);
            float inv = rsqrtf(sq * (1.f / 128.f) + 1e-5f);
            out[(size_t)(base + r) * DIM + l]      = e0 * inv * lg0 + lb0;
            out[(size_t)(base + r) * DIM + 64 + l] = e1 * inv * lg1 + lb1;
        }
    }
}

// ---------------------------------------------------------------------------
extern "C" void kernel_launch(void* const* d_in, const int* in_sizes, int n_in,
                              void* d_out, int out_size, void* d_ws, size_t ws_size,
                              hipStream_t stream) {
    const int*   src         = (const int*)  d_in[0];
    const int*   dst         = (const int*)  d_in[1];
    const float* ts          = (const float*)d_in[2];
    const int*   nbr_ids     = (const int*)  d_in[3];
    const float* nbr_ts      = (const float*)d_in[4];
    const float* memory      = (const float*)d_in[5];
    const float* last_update = (const float*)d_in[6];
    const float* w_t_msg     = (const float*)d_in[7];
    const float* b_t_msg     = (const float*)d_in[8];
    const float* W_msg1      = (const float*)d_in[9];
    const float* b_msg1      = (const float*)d_in[10];
    const float* W_msg2      = (const float*)d_in[11];
    const float* b_msg2      = (const float*)d_in[12];
    const float* W_ih        = (const float*)d_in[13];
    const float* b_ih        = (const float*)d_in[14];
    const float* W_hh        = (const float*)d_in[15];
    const float* b_hh        = (const float*)d_in[16];
    const float* w_t_att     = (const float*)d_in[17];
    const float* b_t_att     = (const float*)d_in[18];
    const float* Wq          = (const float*)d_in[19];
    const float* bq          = (const float*)d_in[20];
    const float* Wk          = (const float*)d_in[21];
    const float* bk          = (const float*)d_in[22];
    const float* Wv          = (const float*)d_in[23];
    const float* bv          = (const float*)d_in[24];
    const float* Wo          = (const float*)d_in[25];
    const float* bo          = (const float*)d_in[26];
    const float* Wm1         = (const float*)d_in[27];
    const float* bm1         = (const float*)d_in[28];
    const float* Wm2         = (const float*)d_in[29];
    const float* bm2         = (const float*)d_in[30];
    const float* ln_g        = (const float*)d_in[31];
    const float* ln_b        = (const float*)d_in[32];
    float* out = (float*)d_out;

    char* ws = (char*)d_ws;
    size_t off = 0;
    float* new_mem = (float*)(ws + off); off += (size_t)2 * BATCH * DIM * 4;   // 8 MiB
    int*   winner  = (int*)  (ws + off); off += 2097152;                       // 2 MiB
    int*   sel_id  = (int*)  (ws + off); off += (size_t)BATCH * KSEL * 4;
    float* sel_td  = (float*)(ws + off); off += (size_t)BATCH * KSEL * 4;
    int*   sel_mk  = (int*)  (ws + off); off += (size_t)BATCH * KSEL * 4;
    unsigned short* Wpool = (unsigned short*)(ws + off); off += (size_t)CVT_TOT * 2;

    hipMemsetAsync(winner, 0xFF, NNODES * sizeof(int), stream);
    k_prep<<<NB_TOPK, 256, 0, stream>>>(
        W_msg1, W_msg2, W_ih, W_hh, Wq, Wv, Wo, Wm1, Wm2, Wk, Wpool,
        src, dst, winner, ts, nbr_ids, nbr_ts, sel_id, sel_td, sel_mk);
    k1_mfma<<<(2 * BATCH) / 64, 512, 0, stream>>>(
        src, dst, ts, memory, last_update,
        w_t_msg, b_t_msg, Wpool, b_msg1, b_msg2, b_ih, b_hh, new_mem);
    k3_fused<<<BATCH / 32, 512, 0, stream>>>(
        src, memory, new_mem, winner, sel_id, sel_td, sel_mk,
        w_t_att, b_t_att, Wpool, bq, bk, bv, bo, bm1, bm2, ln_g, ln_b, out);
}